// Round 13
// baseline (525.152 us; speedup 1.0000x reference)
//
#include <hip/hip_runtime.h>
#include <cstdint>
#include <cstddef>

typedef short short8 __attribute__((ext_vector_type(8)));
typedef short short4v __attribute__((ext_vector_type(4)));
typedef float f32x4 __attribute__((ext_vector_type(4)));
typedef __bf16 bf16x8 __attribute__((ext_vector_type(8)));

__device__ __forceinline__ unsigned short f2bu(float f) {
  union { float f; unsigned u; } v; v.f = f;
  unsigned r = v.u + 0x7FFFu + ((v.u >> 16) & 1u);
  return (unsigned short)(r >> 16);
}
__device__ __forceinline__ float b2f(unsigned short h) {
  union { unsigned u; float f; } v; v.u = ((unsigned)h) << 16;
  return v.f;
}

__device__ __forceinline__ f32x4 mfma16(short8 a, short8 b, f32x4 c) {
  return __builtin_amdgcn_mfma_f32_16x16x32_bf16(
      __builtin_bit_cast(bf16x8, a), __builtin_bit_cast(bf16x8, b), c, 0, 0, 0);
}

// ---------------- f32 -> bf16 table convert (8/thread) ----------------
__global__ void k_cvt(const float* __restrict__ in, short* __restrict__ o, int ntot) {
  int i = (blockIdx.x * 256 + threadIdx.x) * 8;
  if (i >= ntot) return;
  float4 a = *(const float4*)(in + i);
  float4 b = *(const float4*)(in + i + 4);
  short8 v;
  v[0] = (short)f2bu(a.x); v[1] = (short)f2bu(a.y);
  v[2] = (short)f2bu(a.z); v[3] = (short)f2bu(a.w);
  v[4] = (short)f2bu(b.x); v[5] = (short)f2bu(b.y);
  v[6] = (short)f2bu(b.z); v[7] = (short)f2bu(b.w);
  *(short8*)(o + i) = v;
}

// ---------------- gather + convert referenced rows ------------------------
__global__ void k_cvt_rows(const float* __restrict__ tab, const int* __restrict__ pairs,
                           short* __restrict__ o, int nrows) {
  int t = blockIdx.x * 256 + threadIdx.x;
  if (t >= nrows * 32) return;
  int row = t >> 5;
  int c8 = (t & 31) << 3;
  int id = pairs[2 * row];
  const float* s = tab + (size_t)id * 256 + c8;
  float4 a = *(const float4*)(s);
  float4 b = *(const float4*)(s + 4);
  short8 v;
  v[0] = (short)f2bu(a.x); v[1] = (short)f2bu(a.y);
  v[2] = (short)f2bu(a.z); v[3] = (short)f2bu(a.w);
  v[4] = (short)f2bu(b.x); v[5] = (short)f2bu(b.y);
  v[6] = (short)f2bu(b.z); v[7] = (short)f2bu(b.w);
  *(short8*)(o + (size_t)row * 256 + c8) = v;
}

// ---------------- merged weight prep ------------------------------------
// mode 0 = slab-swizzle (N=256), 1 = transpose->bf16, 2 = cvt
struct Prep {
  const float* src[16];
  short* dst[16];
  int K[16], N[16], mode[16];
  int boff[17];
};
__global__ void k_prep(Prep p) {
  int b = blockIdx.x, e = 0;
#pragma unroll
  for (int i = 1; i < 16; ++i) if (b >= p.boff[i]) e = i;
  int t = (b - p.boff[e]) * 256 + threadIdx.x;
  const int K = p.K[e], N = p.N[e];
  if (t >= K * N) return;
  const float* w = p.src[e];
  const int m = p.mode[e];
  if (m == 2) { p.dst[e][t] = (short)f2bu(w[t]); return; }
  if (m == 0) {
    int ks = t >> 13, rem = t & 8191;
    int P = rem >> 3, j = rem & 7;
    int n = P >> 2;
    int kq = ((P & 3) - (n >> 1)) & 3;
    int k = (ks << 5) + (kq << 3) + j;
    p.dst[e][t] = (short)f2bu(w[(size_t)k * 256 + n]);
    return;
  }
  int n = t / K, k = t - n * K;
  p.dst[e][t] = (short)f2bu(w[(size_t)k * N + n]);
}

// ---------------- RC[6][256]: rate contribution of g_u layer 1 (f32) ------
__global__ void k_rc(const float* __restrict__ rate, const float* __restrict__ w1,
                     float* __restrict__ RC) {
  const int j = blockIdx.x;
  const int n = threadIdx.x;
  float s = 0.f;
  const float* rr = rate + j * 256;
  for (int k = 0; k < 256; ++k)
    s += rr[k] * w1[(size_t)(256 + k) * 256 + n];
  RC[j * 256 + n] = s;
}

// ---------------- QC[G][256]: per-group q contribution of attn layer 1 ----
__global__ __launch_bounds__(256, 4) void k_qc(
    const int* __restrict__ qid, const short* __restrict__ itembf,
    const short* __restrict__ aw1, float* __restrict__ QC)
{
  const int tid = threadIdx.x;
  const int lane = tid & 63;
  const int wave = tid >> 6;
  const int m0 = (int)blockIdx.x << 6;
  const int l15 = lane & 15;
  const int lq = lane >> 4;
  const int nb = wave << 6;

  int pBg[4];
  const short* qp[4];
#pragma unroll
  for (int i = 0; i < 4; ++i) {
    int n = nb + i * 16 + l15;
    pBg[i] = (n * 4 + ((lq + (n >> 1)) & 3)) * 8;
    qp[i] = itembf + (size_t)qid[m0 + i * 16 + l15] * 256 + lq * 8;
  }

  const f32x4 fz = {0.f, 0.f, 0.f, 0.f};
  f32x4 acc[4][4];
#pragma unroll
  for (int ni = 0; ni < 4; ++ni)
#pragma unroll
    for (int mi = 0; mi < 4; ++mi) acc[ni][mi] = fz;

  for (int ks = 0; ks < 8; ++ks) {
    short8 wf[4], qf[4];
#pragma unroll
    for (int i = 0; i < 4; ++i) {
      wf[i] = *(const short8*)(aw1 + (8 + ks) * 8192 + pBg[i]);
      qf[i] = *(const short8*)(qp[i] + ks * 32);
    }
#pragma unroll
    for (int ni = 0; ni < 4; ++ni)
#pragma unroll
      for (int mi = 0; mi < 4; ++mi)
        acc[ni][mi] = mfma16(wf[ni], qf[mi], acc[ni][mi]);
  }
#pragma unroll
  for (int ni = 0; ni < 4; ++ni) {
    const int nbase = nb + ni * 16 + lq * 4;
#pragma unroll
    for (int mi = 0; mi < 4; ++mi) {
      const int m = mi * 16 + l15;
      *(f32x4*)(QC + (size_t)(m0 + m) * 256 + nbase) = acc[ni][mi];
    }
  }
}

// ---------------- 48-row group-aligned mega-fusion -------------------------
// Block = 48 rows = 4 groups. Full chain in one block:
// g_u L1 (+RC) -> L2 -> f_jt (sH swz + sF plain) -> attn L1 (+QC) -> scores
// -> per-wave head MLP + softmax -> weighted sum over sF -> HPRE[group].
template <bool IDENT>
__global__ __launch_bounds__(256, 3) void k_fused2(
    const int* __restrict__ idx_pairs,
    const short* __restrict__ tab0,
    const float* __restrict__ RC,
    const float* __restrict__ QC,
    const short* __restrict__ ws1, const float* __restrict__ b1,
    const short* __restrict__ ws2, const float* __restrict__ b2,
    const short* __restrict__ aw1, const float* __restrict__ ab1,
    const short* __restrict__ aw2t, const float* __restrict__ ab2,
    const short* __restrict__ h1t, const float* __restrict__ hb1,
    const short* __restrict__ h2t, const float* __restrict__ hb2,
    short* __restrict__ HPRE)
{
  __shared__ __align__(16) short smem[26112];   // 52224 B
  short* sA = smem;            // 1536 shorts (48x32 A tile), later aliased:
  short* sS = smem;            //   scores 48x16 bf16 = 768 shorts
  short* h1d = smem + 768;     //   head hidden 4x96 bf16 = 384 shorts
  float* wgt = (float*)(smem + 1152); // 4x12 f32
  short* sH = smem + 1536;     // 48x256 swizzled (hidden / f_jt / attn-hidden)
  short* sF = smem + 13824;    // 48x256 plain f_jt

  const int tid = threadIdx.x;
  const int lane = tid & 63;
  const int wave = tid >> 6;
  const int m0 = (int)blockIdx.x * 48;
  const int l15 = lane & 15;
  const int lq = lane >> 4;
  const int nb = wave << 6;
  const int swz = (l15 & 7) << 3;

  // A staging: thread t (<192) fills quantum t
  const int an = (tid < 192) ? (tid >> 2) : 0;
  const int kqA = ((tid & 3) - (an >> 1)) & 3;
  const int rA0 = m0 + an;
  const int i0s = idx_pairs[2 * rA0];
  const short* a0 = (IDENT ? (tab0 + (size_t)rA0 * 256) : (tab0 + (size_t)i0s * 256)) + kqA * 8;

  int pBg[4], pA[3];
#pragma unroll
  for (int i = 0; i < 4; ++i) {
    int n = nb + i * 16 + l15;
    pBg[i] = (n * 4 + ((lq + (n >> 1)) & 3)) * 8;
  }
#pragma unroll
  for (int i = 0; i < 3; ++i) {
    int m = i * 16 + l15;
    pA[i] = (m * 4 + ((lq + (m >> 1)) & 3)) * 8;
  }
  const int hOff = lq * 8;

  const f32x4 fz = {0.f, 0.f, 0.f, 0.f};
  f32x4 acc[4][3];
#pragma unroll
  for (int ni = 0; ni < 4; ++ni)
#pragma unroll
    for (int mi = 0; mi < 3; ++mi) acc[ni][mi] = fz;

  short8 wfb[3][4];
  short8 rAr;

  // per-lane row metadata (3 rows per lane)
  int i1v[3], mskv[3], grpv[3];
#pragma unroll
  for (int mi = 0; mi < 3; ++mi) {
    const int row = m0 + mi * 16 + l15;
    i1v[mi]  = idx_pairs[2 * row + 1];
    mskv[mi] = idx_pairs[2 * row];
    grpv[mi] = row / 12;
  }

  // ================= g_u layer 1 (K=256, 8 ksteps, single-buf A) =========
  rAr = *(const short8*)a0;
  if (tid < 192) *(short8*)(sA + tid * 8) = rAr;
  rAr = *(const short8*)(a0 + 32);
#pragma unroll
  for (int i = 0; i < 4; ++i) wfb[0][i] = *(const short8*)(ws1 + pBg[i]);
#pragma unroll
  for (int i = 0; i < 4; ++i) wfb[1][i] = *(const short8*)(ws1 + 8192 + pBg[i]);
  __syncthreads();
#pragma unroll
  for (int ks = 0; ks < 8; ++ks) {
    if (ks < 6) {
      const short* s = ws1 + (ks + 2) * 8192;
#pragma unroll
      for (int i = 0; i < 4; ++i) wfb[(ks + 2) % 3][i] = *(const short8*)(s + pBg[i]);
    }
    short8 xf[3];
#pragma unroll
    for (int i = 0; i < 3; ++i) xf[i] = *(short8*)(sA + pA[i]);
#pragma unroll
    for (int ni = 0; ni < 4; ++ni)
#pragma unroll
      for (int mi = 0; mi < 3; ++mi)
        acc[ni][mi] = mfma16(wfb[ks % 3][ni], xf[mi], acc[ni][mi]);
    if (ks < 7) {
      __syncthreads();                         // all done reading sA
      if (tid < 192) *(short8*)(sA + tid * 8) = rAr;
      if (ks < 6) rAr = *(const short8*)(a0 + (ks + 2) * 32);
      __syncthreads();                         // sA ready
    }
  }
  // hidden = relu(acc + RC[i1] + b1) -> sH (swizzled)
#pragma unroll
  for (int ni = 0; ni < 4; ++ni) {
    const int nbase = nb + ni * 16 + lq * 4;
    float4 bb = *(const float4*)(b1 + nbase);
#pragma unroll
    for (int mi = 0; mi < 3; ++mi) {
      const int m = mi * 16 + l15;
      float4 rc = *(const float4*)(RC + i1v[mi] * 256 + nbase);
      short4v hv;
      hv[0] = (short)f2bu(fmaxf(acc[ni][mi][0] + rc.x + bb.x, 0.f));
      hv[1] = (short)f2bu(fmaxf(acc[ni][mi][1] + rc.y + bb.y, 0.f));
      hv[2] = (short)f2bu(fmaxf(acc[ni][mi][2] + rc.z + bb.z, 0.f));
      hv[3] = (short)f2bu(fmaxf(acc[ni][mi][3] + rc.w + bb.w, 0.f));
      *(short4v*)(sH + m * 256 + (nbase ^ swz)) = hv;
    }
  }
  __syncthreads();   // publish hidden

  // ================= g_u layer 2 (K=256, barrier-free) =================
#pragma unroll
  for (int ni = 0; ni < 4; ++ni)
#pragma unroll
    for (int mi = 0; mi < 3; ++mi) acc[ni][mi] = fz;
#pragma unroll
  for (int i = 0; i < 4; ++i) wfb[0][i] = *(const short8*)(ws2 + pBg[i]);
#pragma unroll
  for (int i = 0; i < 4; ++i) wfb[1][i] = *(const short8*)(ws2 + 8192 + pBg[i]);
#pragma unroll
  for (int ks = 0; ks < 8; ++ks) {
    if (ks < 6) {
      const short* s = ws2 + (ks + 2) * 8192;
#pragma unroll
      for (int i = 0; i < 4; ++i) wfb[(ks + 2) % 3][i] = *(const short8*)(s + pBg[i]);
    }
    short8 hf[3];
#pragma unroll
    for (int i = 0; i < 3; ++i)
      hf[i] = *(short8*)(sH + (i * 16 + l15) * 256 + ((ks * 32 + hOff) ^ swz));
#pragma unroll
    for (int ni = 0; ni < 4; ++ni)
#pragma unroll
      for (int mi = 0; mi < 3; ++mi)
        acc[ni][mi] = mfma16(wfb[ks % 3][ni], hf[mi], acc[ni][mi]);
  }
  __syncthreads();   // all done reading sH(hidden)

  // f_jt = acc + b2 -> sH (swizzled, for attn L1) + sF (plain, for wsum)
#pragma unroll
  for (int ni = 0; ni < 4; ++ni) {
    const int nbase = nb + ni * 16 + lq * 4;
    float4 bb = *(const float4*)(b2 + nbase);
#pragma unroll
    for (int mi = 0; mi < 3; ++mi) {
      const int m = mi * 16 + l15;
      short4v hv;
      hv[0] = (short)f2bu(acc[ni][mi][0] + bb.x);
      hv[1] = (short)f2bu(acc[ni][mi][1] + bb.y);
      hv[2] = (short)f2bu(acc[ni][mi][2] + bb.z);
      hv[3] = (short)f2bu(acc[ni][mi][3] + bb.w);
      *(short4v*)(sH + m * 256 + (nbase ^ swz)) = hv;
      *(short4v*)(sF + m * 256 + nbase) = hv;
    }
  }
  __syncthreads();   // publish f_jt

  // ================= attn layer 1 (K=256, barrier-free) =================
#pragma unroll
  for (int ni = 0; ni < 4; ++ni)
#pragma unroll
    for (int mi = 0; mi < 3; ++mi) acc[ni][mi] = fz;
#pragma unroll
  for (int i = 0; i < 4; ++i) wfb[0][i] = *(const short8*)(aw1 + pBg[i]);
#pragma unroll
  for (int i = 0; i < 4; ++i) wfb[1][i] = *(const short8*)(aw1 + 8192 + pBg[i]);
#pragma unroll
  for (int ks = 0; ks < 8; ++ks) {
    if (ks < 6) {
      const short* s = aw1 + (ks + 2) * 8192;
#pragma unroll
      for (int i = 0; i < 4; ++i) wfb[(ks + 2) % 3][i] = *(const short8*)(s + pBg[i]);
    }
    short8 xf[3];
#pragma unroll
    for (int i = 0; i < 3; ++i)
      xf[i] = *(short8*)(sH + (i * 16 + l15) * 256 + ((ks * 32 + hOff) ^ swz));
#pragma unroll
    for (int ni = 0; ni < 4; ++ni)
#pragma unroll
      for (int mi = 0; mi < 3; ++mi)
        acc[ni][mi] = mfma16(wfb[ks % 3][ni], xf[mi], acc[ni][mi]);
  }
  __syncthreads();   // all done reading sH(f_jt)

  // attn hidden = relu(acc + mask*QC[grp] + ab1) -> sH (overwrite)
#pragma unroll
  for (int ni = 0; ni < 4; ++ni) {
    const int nbase = nb + ni * 16 + lq * 4;
    float4 bb = *(const float4*)(ab1 + nbase);
#pragma unroll
    for (int mi = 0; mi < 3; ++mi) {
      const int m = mi * 16 + l15;
      float4 qv;
      if (mskv[mi] > 0) qv = *(const float4*)(QC + (size_t)grpv[mi] * 256 + nbase);
      else { qv.x = 0.f; qv.y = 0.f; qv.z = 0.f; qv.w = 0.f; }
      short4v hv;
      hv[0] = (short)f2bu(fmaxf(acc[ni][mi][0] + qv.x + bb.x, 0.f));
      hv[1] = (short)f2bu(fmaxf(acc[ni][mi][1] + qv.y + bb.y, 0.f));
      hv[2] = (short)f2bu(fmaxf(acc[ni][mi][2] + qv.z + bb.z, 0.f));
      hv[3] = (short)f2bu(fmaxf(acc[ni][mi][3] + qv.w + bb.w, 0.f));
      *(short4v*)(sH + m * 256 + (nbase ^ swz)) = hv;
    }
  }
  __syncthreads();

  // ================= attn layer 2 (256 -> 16) -> sS (waves 0..2) =========
  if (wave < 3) {
    f32x4 a2 = fz;
#pragma unroll
    for (int ks = 0; ks < 8; ++ks) {
      short8 af = *(short8*)(sH + (wave * 16 + l15) * 256 + ((ks * 32 + hOff) ^ swz));
      short8 bv = *(const short8*)(aw2t + l15 * 256 + ks * 32 + hOff);
      a2 = mfma16(af, bv, a2);
    }
    const float bias = ab2[l15];
#pragma unroll
    for (int j = 0; j < 4; ++j)
      sS[(wave * 16 + lq * 4 + j) * 16 + l15] = (short)f2bu(a2[j] + bias);
  }
  __syncthreads();   // publish scores

  // ================= head MLP + softmax (wave g = group g) ===============
  const int gi = m0 / 12 + wave;
#pragma unroll
  for (int jj = 0; jj < 2; ++jj) {
    const int j = lane + jj * 64;
    if (j < 96) {
      float s = hb1[j];
      const short* wr = h1t + j * 192;
      const short* sv = sS + wave * 192;
#pragma unroll
      for (int k = 0; k < 192; k += 8) {
        short8 wv = *(const short8*)(wr + k);
        short8 xv = *(const short8*)(sv + k);
#pragma unroll
        for (int q = 0; q < 8; ++q)
          s += b2f((unsigned short)xv[q]) * b2f((unsigned short)wv[q]);
      }
      h1d[wave * 96 + j] = (short)f2bu(fmaxf(s, 0.f));
    }
  }
  if (lane < 12) {
    float z = hb2[lane];
    const short* hr = h1d + wave * 96;
    const short* wr = h2t + lane * 96;
#pragma unroll
    for (int k = 0; k < 96; k += 8) {
      short8 hv = *(const short8*)(hr + k);
      short8 wv = *(const short8*)(wr + k);
#pragma unroll
      for (int q = 0; q < 8; ++q)
        z += b2f((unsigned short)hv[q]) * b2f((unsigned short)wv[q]);
    }
    const int msk = idx_pairs[2 * (gi * 12 + lane)];
    wgt[wave * 12 + lane] = (msk > 0) ? expf(z) : 0.f;
  }
  if (lane < 12) {
    float tot = 1e-10f;
#pragma unroll
    for (int m = 0; m < 12; ++m) tot += wgt[wave * 12 + m];
    wgt[wave * 12 + lane] = wgt[wave * 12 + lane] / tot;
  }

  // ================= weighted sum over sF -> HPRE[group] =================
  {
    float o0 = 0.f, o1 = 0.f, o2 = 0.f, o3 = 0.f;
    const int c0 = lane * 4;
#pragma unroll
    for (int m = 0; m < 12; ++m) {
      const float wm = wgt[wave * 12 + m];
      short4v x = *(short4v*)(sF + (wave * 12 + m) * 256 + c0);
      o0 += wm * b2f((unsigned short)x[0]);
      o1 += wm * b2f((unsigned short)x[1]);
      o2 += wm * b2f((unsigned short)x[2]);
      o3 += wm * b2f((unsigned short)x[3]);
    }
    short4v ov;
    ov[0] = (short)f2bu(o0); ov[1] = (short)f2bu(o1);
    ov[2] = (short)f2bu(o2); ov[3] = (short)f2bu(o3);
    *(short4v*)(HPRE + (size_t)gi * 256 + c0) = ov;
  }
}

// ---------------- kappa scores (bf16 out) ---------------------------------
__global__ __launch_bounds__(256, 3) void k_attonly(
    const short* __restrict__ first,
    const short* __restrict__ itembf,
    const int* __restrict__ iidx,
    const short* __restrict__ aw1, const float* __restrict__ ab1,
    const short* __restrict__ aw2t, const float* __restrict__ ab2,
    short* __restrict__ out)
{
  __shared__ __align__(16) short sH[16896];

  const int tid = threadIdx.x;
  const int lane = tid & 63;
  const int wave = tid >> 6;
  const int m0 = (int)blockIdx.x << 6;
  const int l15 = lane & 15;
  const int lq = lane >> 4;
  const int nb = wave << 6;
  const int hOff = lq * 8;

  const short* fp[4];
  const short* qp[4];
  int pBg[4];
#pragma unroll
  for (int i = 0; i < 4; ++i) {
    int mrow = m0 + i * 16 + l15;
    fp[i] = first + (size_t)mrow * 256 + hOff;
    qp[i] = itembf + (size_t)iidx[mrow] * 256 + hOff;
    int n = nb + i * 16 + l15;
    pBg[i] = (n * 4 + ((lq + (n >> 1)) & 3)) * 8;
  }

  const f32x4 fz = {0.f, 0.f, 0.f, 0.f};
  f32x4 acc[4][4];
#pragma unroll
  for (int ni = 0; ni < 4; ++ni)
#pragma unroll
    for (int mi = 0; mi < 4; ++mi) acc[ni][mi] = fz;

  short8 wfc[4], wfn[4], xfc[4], xfn[4];
#pragma unroll
  for (int i = 0; i < 4; ++i) {
    wfc[i] = *(const short8*)(aw1 + pBg[i]);
    xfc[i] = *(const short8*)(fp[i]);
  }
  for (int ks = 0; ks < 16; ++ks) {
    if (ks < 15) {
      const int c = ks + 1;
      const short* s = aw1 + c * 8192;
#pragma unroll
      for (int i = 0; i < 4; ++i) {
        wfn[i] = *(const short8*)(s + pBg[i]);
        xfn[i] = *(const short8*)((c < 8) ? (fp[i] + c * 32) : (qp[i] + (c - 8) * 32));
      }
    }
#pragma unroll
    for (int ni = 0; ni < 4; ++ni)
#pragma unroll
      for (int mi = 0; mi < 4; ++mi)
        acc[ni][mi] = mfma16(wfc[ni], xfc[mi], acc[ni][mi]);
    if (ks < 15) {
#pragma unroll
      for (int i = 0; i < 4; ++i) { wfc[i] = wfn[i]; xfc[i] = xfn[i]; }
    }
  }
#pragma unroll
  for (int ni = 0; ni < 4; ++ni) {
    const int nbase = nb + ni * 16 + lq * 4;
    float4 bb = *(const float4*)(ab1 + nbase);
#pragma unroll
    for (int mi = 0; mi < 4; ++mi) {
      const int m = mi * 16 + l15;
      short4v hv;
      hv[0] = (short)f2bu(fmaxf(acc[ni][mi][0] + bb.x, 0.f));
      hv[1] = (short)f2bu(fmaxf(acc[ni][mi][1] + bb.y, 0.f));
      hv[2] = (short)f2bu(fmaxf(acc[ni][mi][2] + bb.z, 0.f));
      hv[3] = (short)f2bu(fmaxf(acc[ni][mi][3] + bb.w, 0.f));
      *(short4v*)(sH + m * 264 + nbase) = hv;
    }
  }
  __syncthreads();
  f32x4 a2 = fz;
#pragma unroll
  for (int ks = 0; ks < 8; ++ks) {
    short8 af = *(short8*)(sH + (wave * 16 + l15) * 264 + ks * 32 + hOff);
    short8 bv = *(const short8*)(aw2t + l15 * 256 + ks * 32 + hOff);
    a2 = mfma16(af, bv, a2);
  }
  const float bias = ab2[l15];
#pragma unroll
  for (int j = 0; j < 4; ++j)
    out[(size_t)(m0 + wave * 16 + lq * 4 + j) * 16 + l15] = (short)f2bu(a2[j] + bias);
}

// ---------------- single-layer GEMM 256->256 + bias + relu (no LDS) -------
__global__ __launch_bounds__(256, 3) void k_gemm1(
    const short* __restrict__ Abf, const short* __restrict__ wt,
    const float* __restrict__ bias, short* __restrict__ out)
{
  const int tid  = threadIdx.x;
  const int lane = tid & 63;
  const int wave = tid >> 6;
  const int m0   = blockIdx.x << 6;
  const int l15  = lane & 15;
  const int lq   = lane >> 4;
  const int rq   = lq << 2;
  const int nb   = wave << 6;
  const int hOff = lq * 8;

  const f32x4 fz = {0.f, 0.f, 0.f, 0.f};
  f32x4 acc[4][4];
#pragma unroll
  for (int mi = 0; mi < 4; ++mi)
#pragma unroll
    for (int ni = 0; ni < 4; ++ni) acc[mi][ni] = fz;

  for (int ks = 0; ks < 8; ++ks) {
    short8 af[4], bv[4];
#pragma unroll
    for (int i = 0; i < 4; ++i) {
      af[i] = *(const short8*)(Abf + (size_t)(m0 + i * 16 + l15) * 256 + ks * 32 + hOff);
      bv[i] = *(const short8*)(wt + (size_t)(nb + i * 16 + l15) * 256 + ks * 32 + hOff);
    }
#pragma unroll
    for (int mi = 0; mi < 4; ++mi)
#pragma unroll
      for (int ni = 0; ni < 4; ++ni)
        acc[mi][ni] = mfma16(af[mi], bv[ni], acc[mi][ni]);
  }

#pragma unroll
  for (int ni = 0; ni < 4; ++ni) {
    const int col = nb + ni * 16 + l15;
    const float b = bias[col];
#pragma unroll
    for (int mi = 0; mi < 4; ++mi)
#pragma unroll
      for (int j = 0; j < 4; ++j) {
        const int row = mi * 16 + rq + j;
        out[(size_t)(m0 + row) * 256 + col] = (short)f2bu(fmaxf(acc[mi][ni][j] + b, 0.f));
      }
  }
}

// ---------------- fused 3-layer comb MLP --------------------------------
__global__ __launch_bounds__(256, 2) void k_comb(
    const short* __restrict__ hju, const short* __restrict__ hjv,
    const short* __restrict__ w1t, const float* __restrict__ b1,
    const short* __restrict__ w2t, const float* __restrict__ b2,
    const short* __restrict__ w3t, const float* __restrict__ b3,
    float* __restrict__ out)
{
  __shared__ __align__(16) short smem[29696];
  short (*A)[40]   = (short(*)[40])smem;
  short (*Bt)[40]  = (short(*)[40])(smem + 2560);
  short (*Hh)[264] = (short(*)[264])(smem + 12800);

  const int tid  = threadIdx.x;
  const int lane = tid & 63;
  const int wave = tid >> 6;
  const int m0   = blockIdx.x << 6;
  const int arow = tid >> 2;
  const int acol8 = (tid & 3) << 3;
  const int lrow = lane & 15;
  const int lk8  = (lane >> 4) << 3;
  const int rq   = (lane >> 4) << 2;
  const int nb   = wave << 6;
  const int r = m0 + arow;

  const f32x4 fz = {0.f, 0.f, 0.f, 0.f};
  f32x4 acc[4][4];
#pragma unroll
  for (int mi = 0; mi < 4; ++mi)
#pragma unroll
    for (int ni = 0; ni < 4; ++ni) acc[mi][ni] = fz;

  for (int ks = 0; ks < 16; ++ks) {
    const int kg = (ks << 5) + acol8;
    short8 av = (kg < 256) ? *(const short8*)(hju + (size_t)r * 256 + kg)
                           : *(const short8*)(hjv + (size_t)r * 256 + (kg - 256));
    *(short8*)&A[arow][acol8] = av;
    const short* wsrc = w1t + tid * 512 + (ks << 5);
    *(short8*)&Bt[tid][0]  = *(const short8*)(wsrc);
    *(short8*)&Bt[tid][8]  = *(const short8*)(wsrc + 8);
    *(short8*)&Bt[tid][16] = *(const short8*)(wsrc + 16);
    *(short8*)&Bt[tid][24] = *(const short8*)(wsrc + 24);
    __syncthreads();
    short8 af[4], bv[4];
#pragma unroll
    for (int mi = 0; mi < 4; ++mi) af[mi] = *(short8*)&A[mi * 16 + lrow][lk8];
#pragma unroll
    for (int ni = 0; ni < 4; ++ni) bv[ni] = *(short8*)&Bt[nb + ni * 16 + lrow][lk8];
#pragma unroll
    for (int mi = 0; mi < 4; ++mi)
#pragma unroll
      for (int ni = 0; ni < 4; ++ni)
        acc[mi][ni] = mfma16(af[mi], bv[ni], acc[mi][ni]);
    __syncthreads();
  }
#pragma unroll
  for (int ni = 0; ni < 4; ++ni) {
    const int col = nb + ni * 16 + lrow;
    const float bias = b1[col];
#pragma unroll
    for (int mi = 0; mi < 4; ++mi)
#pragma unroll
      for (int j = 0; j < 4; ++j)
        Hh[mi * 16 + rq + j][col] = (short)f2bu(fmaxf(acc[mi][ni][j] + bias, 0.f));
  }

#pragma unroll
  for (int mi = 0; mi < 4; ++mi)
#pragma unroll
    for (int ni = 0; ni < 4; ++ni) acc[mi][ni] = fz;
  for (int ks = 0; ks < 8; ++ks) {
    const short* wsrc = w2t + tid * 256 + (ks << 5);
    *(short8*)&Bt[tid][0]  = *(const short8*)(wsrc);
    *(short8*)&Bt[tid][8]  = *(const short8*)(wsrc + 8);
    *(short8*)&Bt[tid][16] = *(const short8*)(wsrc + 16);
    *(short8*)&Bt[tid][24] = *(const short8*)(wsrc + 24);
    __syncthreads();
    short8 af[4], bv[4];
#pragma unroll
    for (int mi = 0; mi < 4; ++mi) af[mi] = *(short8*)&Hh[mi * 16 + lrow][(ks << 5) + lk8];
#pragma unroll
    for (int ni = 0; ni < 4; ++ni) bv[ni] = *(short8*)&Bt[nb + ni * 16 + lrow][lk8];
#pragma unroll
    for (int mi = 0; mi < 4; ++mi)
#pragma unroll
      for (int ni = 0; ni < 4; ++ni)
        acc[mi][ni] = mfma16(af[mi], bv[ni], acc[mi][ni]);
    __syncthreads();
  }
#pragma unroll
  for (int ni = 0; ni < 4; ++ni) {
    const int col = nb + ni * 16 + lrow;
    const float bias = b2[col];
#pragma unroll
    for (int mi = 0; mi < 4; ++mi)
#pragma unroll
      for (int j = 0; j < 4; ++j)
        Hh[mi * 16 + rq + j][col] = (short)f2bu(fmaxf(acc[mi][ni][j] + bias, 0.f));
  }
  __syncthreads();

#pragma unroll
  for (int mi = 0; mi < 4; ++mi)
#pragma unroll
    for (int ni = 0; ni < 4; ++ni) acc[mi][ni] = fz;
  for (int ks = 0; ks < 8; ++ks) {
    const short* wsrc = w3t + tid * 256 + (ks << 5);
    *(short8*)&Bt[tid][0]  = *(const short8*)(wsrc);
    *(short8*)&Bt[tid][8]  = *(const short8*)(wsrc + 8);
    *(short8*)&Bt[tid][16] = *(const short8*)(wsrc + 16);
    *(short8*)&Bt[tid][24] = *(const short8*)(wsrc + 24);
    __syncthreads();
    short8 af[4], bv[4];
#pragma unroll
    for (int mi = 0; mi < 4; ++mi) af[mi] = *(short8*)&Hh[mi * 16 + lrow][(ks << 5) + lk8];
#pragma unroll
    for (int ni = 0; ni < 4; ++ni) bv[ni] = *(short8*)&Bt[nb + ni * 16 + lrow][lk8];
#pragma unroll
    for (int mi = 0; mi < 4; ++mi)
#pragma unroll
      for (int ni = 0; ni < 4; ++ni)
        acc[mi][ni] = mfma16(af[mi], bv[ni], acc[mi][ni]);
    __syncthreads();
  }
#pragma unroll
  for (int ni = 0; ni < 4; ++ni) {
    const int col = nb + ni * 16 + lrow;
    const float bias = b3[col];
#pragma unroll
    for (int mi = 0; mi < 4; ++mi)
#pragma unroll
      for (int j = 0; j < 4; ++j) {
        const int row = mi * 16 + rq + j;
        out[(size_t)(m0 + row) * 256 + col] = fmaxf(acc[mi][ni][j] + bias, 0.f);
      }
  }
}

// ---------------- head MLP1 as MFMA GEMM (kappa chain) --------------------
__global__ __launch_bounds__(256, 4) void k_h1(
    const short* __restrict__ A, const short* __restrict__ w1t,
    const float* __restrict__ b1, short* __restrict__ h1)
{
  const int tid = threadIdx.x;
  const int lane = tid & 63;
  const int wave = tid >> 6;
  const int m0 = (int)blockIdx.x << 6;
  const int l15 = lane & 15;
  const int lq = lane >> 4;
  const int ntc = (wave < 2) ? 2 : 1;
  const int nta = wave;
  const int ntb = wave + 4;

  const f32x4 fz = {0.f, 0.f, 0.f, 0.f};
  f32x4 acc[4][2];
#pragma unroll
  for (int i = 0; i < 4; ++i) { acc[i][0] = fz; acc[i][1] = fz; }

  for (int ks = 0; ks < 6; ++ks) {
    short8 af[4], bv[2];
#pragma unroll
    for (int i = 0; i < 4; ++i)
      af[i] = *(const short8*)(A + (size_t)(m0 + i * 16 + l15) * 192 + ks * 32 + lq * 8);
    bv[0] = *(const short8*)(w1t + (nta * 16 + l15) * 192 + ks * 32 + lq * 8);
    if (ntc == 2)
      bv[1] = *(const short8*)(w1t + (ntb * 16 + l15) * 192 + ks * 32 + lq * 8);
#pragma unroll
    for (int j = 0; j < 2; ++j)
      if (j < ntc)
#pragma unroll
        for (int i = 0; i < 4; ++i)
          acc[i][j] = mfma16(bv[j], af[i], acc[i][j]);
  }
#pragma unroll
  for (int j = 0; j < 2; ++j) {
    if (j >= ntc) continue;
    const int nbase = (j == 0 ? nta : ntb) * 16 + lq * 4;
    float4 bb = *(const float4*)(b1 + nbase);
#pragma unroll
    for (int i = 0; i < 4; ++i) {
      const int row = m0 + i * 16 + l15;
      short4v hv;
      hv[0] = (short)f2bu(fmaxf(acc[i][j][0] + bb.x, 0.f));
      hv[1] = (short)f2bu(fmaxf(acc[i][j][1] + bb.y, 0.f));
      hv[2] = (short)f2bu(fmaxf(acc[i][j][2] + bb.z, 0.f));
      hv[3] = (short)f2bu(fmaxf(acc[i][j][3] + bb.w, 0.f));
      *(short4v*)(h1 + (size_t)row * 96 + nbase) = hv;
    }
  }
}

// ---------------- head MLP2 + masked softmax -> weights -------------------
__global__ __launch_bounds__(256) void k_h2(
    const short* __restrict__ h1, const short* __restrict__ w2t,
    const float* __restrict__ b2,
    const int* __restrict__ mask_src, const int mstride,
    float* __restrict__ W)
{
  __shared__ float wgt[16][12];
  const int tid = threadIdx.x;
  const int gg = tid >> 4, sl = tid & 15;
  const int g = blockIdx.x * 16 + gg;
  if (sl < 12) {
    float s = b2[sl];
    const short* hr = h1 + (size_t)g * 96;
    const short* wr = w2t + sl * 96;
#pragma unroll
    for (int kk = 0; kk < 12; ++kk) {
      short8 hv = *(const short8*)(hr + kk * 8);
      short8 wv = *(const short8*)(wr + kk * 8);
#pragma unroll
      for (int j = 0; j < 8; ++j)
        s += b2f((unsigned short)hv[j]) * b2f((unsigned short)wv[j]);
    }
    const int mi = mask_src[(g * 12 + sl) * mstride];
    wgt[gg][sl] = (mi > 0) ? expf(s) : 0.f;
  }
  __syncthreads();
  if (sl < 12) {
    float tot = 1e-10f;
#pragma unroll
    for (int m = 0; m < 12; ++m) tot += wgt[gg][m];
    W[(size_t)g * 12 + sl] = wgt[gg][sl] / tot;
  }
}

// ---------------- weighted sum over global X ------------------------------
__global__ __launch_bounds__(256) void k_wsum(
    const float* __restrict__ W, const short* __restrict__ X,
    short* __restrict__ out)
{
  const int tid = threadIdx.x;
  const int g = blockIdx.x * 8 + (tid >> 5);
  const int d0 = (tid & 31) * 8;
  const float* wg = W + (size_t)g * 12;
  float w[12];
#pragma unroll
  for (int m = 0; m < 12; ++m) w[m] = wg[m];
  const short* xp = X + (size_t)g * 12 * 256 + d0;
  float o[8];
#pragma unroll
  for (int j = 0; j < 8; ++j) o[j] = 0.f;
#pragma unroll
  for (int m = 0; m < 12; ++m) {
    short8 x = *(const short8*)(xp + m * 256);
#pragma unroll
    for (int j = 0; j < 8; ++j) o[j] += w[m] * b2f((unsigned short)x[j]);
  }
  short8 v;
#pragma unroll
  for (int j = 0; j < 8; ++j) v[j] = (short)f2bu(o[j]);
  *(short8*)(out + (size_t)g * 256 + d0) = v;
}

// =====================================================================
extern "C" void kernel_launch(void* const* d_in, const int* in_sizes, int n_in,
                              void* d_out, int out_size, void* d_ws, size_t ws_size,
                              hipStream_t stream)
{
  (void)in_sizes; (void)n_in; (void)out_size; (void)ws_size;

  const int*   iids = (const int*)d_in[0];
  const int*   iup  = (const int*)d_in[1];
  const int*   iip  = (const int*)d_in[2];
  const int*   iiup = (const int*)d_in[3];
  const float* user_table = (const float*)d_in[4];
  const float* item_table = (const float*)d_in[5];
  const float* rate_table = (const float*)d_in[6];
  const float* g_u_w1 = (const float*)d_in[7];   const float* g_u_b1 = (const float*)d_in[8];
  const float* g_u_w2 = (const float*)d_in[9];   const float* g_u_b2 = (const float*)d_in[10];
  const float* attu_w1 = (const float*)d_in[11]; const float* attu_b1 = (const float*)d_in[12];
  const float* attu_w2 = (const float*)d_in[13]; const float* attu_b2 = (const float*)d_in[14];
  const float* headu_w1 = (const float*)d_in[15]; const float* headu_b1 = (const float*)d_in[16];
  const float* headu_w2 = (const float*)d_in[17]; const float* headu_b2 = (const float*)d_in[18];
  const float* aggi_w = (const float*)d_in[19];  const float* aggi_b = (const float*)d_in[20];
  const float* attii_w1 = (const float*)d_in[21]; const float* attii_b1 = (const float*)d_in[22];
  const float* attii_w2 = (const float*)d_in[23]; const float* attii_b2 = (const float*)d_in[24];
  const float* headii_w1 = (const float*)d_in[25]; const float* headii_b1 = (const float*)d_in[26];
  const float* headii_w2 = (const float*)d_in[27]; const float* headii_b2 = (const float*)d_in[28];
  const float* aggii_w = (const float*)d_in[29]; const float* aggii_b = (const float*)d_in[30];
  const float* comb_w1 = (const float*)d_in[31]; const float* comb_b1 = (const float*)d_in[32];
  const float* comb_w2 = (const float*)d_in[33]; const float* comb_b2 = (const float*)d_in[34];
  const float* comb_w3 = (const float*)d_in[35]; const float* comb_b3 = (const float*)d_in[36];

  const int NIe = 100000 * 256;
  const int M2 = 2048 * 12 * 12;
  const int M1 = 2048 * 12;
  const int G2 = M1;
  const int G1 = 2048;

  char* wsp = (char*)d_ws;
  size_t off = 0;
  auto alloc = [&](size_t bytes) -> void* {
    void* p = wsp + off;
    off += (bytes + 255) & ~(size_t)255;
    return p;
  };
  short* item_bf = (short*)alloc((size_t)NIe * 2);
  short* urows   = (short*)alloc((size_t)M1 * 256 * 2);
  short* sl_gu1   = (short*)alloc((size_t)512 * 256 * 2);
  short* sl_gu2   = (short*)alloc((size_t)256 * 256 * 2);
  short* sl_attu1 = (short*)alloc((size_t)512 * 256 * 2);
  short* sl_attii1= (short*)alloc((size_t)512 * 256 * 2);
  short* wt_attu2 = (short*)alloc((size_t)256 * 16 * 2);
  short* wt_attii2= (short*)alloc((size_t)256 * 16 * 2);
  short* wt_aggi   = (short*)alloc((size_t)256 * 256 * 2);
  short* wt_aggii  = (short*)alloc((size_t)256 * 256 * 2);
  short* wt_comb1  = (short*)alloc((size_t)512 * 256 * 2);
  short* wt_comb2  = (short*)alloc((size_t)256 * 256 * 2);
  short* wt_comb3  = (short*)alloc((size_t)256 * 256 * 2);
  short* hu1t  = (short*)alloc((size_t)96 * 192 * 2);
  short* hu2t  = (short*)alloc((size_t)12 * 96 * 2);
  short* hii1t = (short*)alloc((size_t)96 * 192 * 2);
  short* hii2t = (short*)alloc((size_t)12 * 96 * 2);
  float* RC    = (float*)alloc((size_t)6 * 256 * 4);
  float* QC2   = (float*)alloc((size_t)G2 * 256 * 4);
  float* QC1   = (float*)alloc((size_t)G1 * 256 * 4);

  short* KAP    = (short*)alloc((size_t)M1 * 16 * 2);
  short* H1K    = (short*)alloc((size_t)G1 * 96 * 2);
  float* WK     = (float*)alloc((size_t)G1 * 12 * 4);
  short* HPRE2  = (short*)alloc((size_t)G2 * 256 * 2);
  short* HOU    = (short*)alloc((size_t)M1 * 256 * 2);
  short* HPREJV = (short*)alloc((size_t)2048 * 256 * 2);
  short* HPRE1  = (short*)alloc((size_t)2048 * 256 * 2);
  short* HJU    = (short*)alloc((size_t)2048 * 256 * 2);
  short* HJV    = (short*)alloc((size_t)2048 * 256 * 2);

  k_cvt<<<NIe / 8 / 256, 256, 0, stream>>>(item_table, item_bf, NIe);
  k_cvt_rows<<<(M1 * 32) / 256, 256, 0, stream>>>(user_table, iup, urows, M1);
  k_rc<<<6, 256, 0, stream>>>(rate_table, g_u_w1, RC);

  Prep pp;
  int nbk = 0, ei = 0;
  auto addw = [&](const float* s, short* d, int K, int N, int mode) {
    pp.src[ei] = s; pp.dst[ei] = d; pp.K[ei] = K; pp.N[ei] = N; pp.mode[ei] = mode;
    pp.boff[ei] = nbk; nbk += (K * N + 255) / 256; ++ei;
  };
  addw(g_u_w1,   sl_gu1,    512, 256, 0);
  addw(g_u_w2,   sl_gu2,    256, 256, 0);
  addw(attu_w1,  sl_attu1,  512, 256, 0);
  addw(attii_w1, sl_attii1, 512, 256, 0);
  addw(attu_w2,  wt_attu2,  256, 16, 1);
  addw(attii_w2, wt_attii2, 256, 16, 1);
  addw(aggi_w,   wt_aggi,   256, 256, 1);
  addw(aggii_w,  wt_aggii,  256, 256, 1);
  addw(comb_w1,  wt_comb1,  512, 256, 1);
  addw(comb_w2,  wt_comb2,  256, 256, 1);
  addw(comb_w3,  wt_comb3,  256, 256, 1);
  addw(headu_w1,  hu1t,  192, 96, 1);
  addw(headu_w2,  hu2t,  96, 12, 1);
  addw(headii_w1, hii1t, 192, 96, 1);
  addw(headii_w2, hii2t, 96, 12, 1);
  pp.boff[15] = nbk;
  pp.boff[16] = nbk;
  k_prep<<<nbk, 256, 0, stream>>>(pp);

  // per-group attn q contributions
  k_qc<<<G2 / 64, 256, 0, stream>>>(iip, item_bf, sl_attu1, QC2);
  k_qc<<<G1 / 64, 256, 0, stream>>>(iids, item_bf, sl_attu1, QC1);

  // mega-fused: g_u + attn + head + softmax + weighted-sum
  k_fused2<false><<<M2 / 48, 256, 0, stream>>>(iiup, item_bf, RC, QC2,
                                               sl_gu1, g_u_b1, sl_gu2, g_u_b2,
                                               sl_attu1, attu_b1, wt_attu2, attu_b2,
                                               hu1t, headu_b1, hu2t, headu_b2,
                                               HPRE2);
  k_fused2<true><<<M1 / 48, 256, 0, stream>>>(iup, urows, RC, QC1,
                                              sl_gu1, g_u_b1, sl_gu2, g_u_b2,
                                              sl_attu1, attu_b1, wt_attu2, attu_b2,
                                              hu1t, headu_b1, hu2t, headu_b2,
                                              HPRE1);

  k_gemm1<<<M1 / 64, 256, 0, stream>>>(HPRE2, wt_aggi, aggi_b, HOU);
  k_attonly<<<M1 / 64, 256, 0, stream>>>(HOU, item_bf, iip,
                                         sl_attii1, attii_b1, wt_attii2, attii_b2, KAP);

  // kappa head chain (unchanged)
  k_h1<<<G1 / 64, 256, 0, stream>>>(KAP, hii1t, headii_b1, H1K);
  k_h2<<<G1 / 16, 256, 0, stream>>>(H1K, hii2t, headii_b2, iip, 1, WK);
  k_wsum<<<G1 / 8, 256, 0, stream>>>(WK, HOU, HPREJV);

  k_gemm1<<<2048 / 64, 256, 0, stream>>>(HPRE1, wt_aggi, aggi_b, HJU);
  k_gemm1<<<2048 / 64, 256, 0, stream>>>(HPREJV, wt_aggii, aggii_b, HJV);
  k_comb<<<2048 / 64, 256, 0, stream>>>(HJU, HJV, wt_comb1, comb_b1,
                                        wt_comb2, comb_b2, wt_comb3, comb_b3,
                                        (float*)d_out);
}

// Round 14
// 487.369 us; speedup vs baseline: 1.0775x; 1.0775x over previous
//
#include <hip/hip_runtime.h>
#include <cstdint>
#include <cstddef>

typedef short short8 __attribute__((ext_vector_type(8)));
typedef short short4v __attribute__((ext_vector_type(4)));
typedef float f32x4 __attribute__((ext_vector_type(4)));
typedef __bf16 bf16x8 __attribute__((ext_vector_type(8)));

__device__ __forceinline__ unsigned short f2bu(float f) {
  union { float f; unsigned u; } v; v.f = f;
  unsigned r = v.u + 0x7FFFu + ((v.u >> 16) & 1u);
  return (unsigned short)(r >> 16);
}
__device__ __forceinline__ float b2f(unsigned short h) {
  union { unsigned u; float f; } v; v.u = ((unsigned)h) << 16;
  return v.f;
}

__device__ __forceinline__ f32x4 mfma16(short8 a, short8 b, f32x4 c) {
  return __builtin_amdgcn_mfma_f32_16x16x32_bf16(
      __builtin_bit_cast(bf16x8, a), __builtin_bit_cast(bf16x8, b), c, 0, 0, 0);
}

// ---------------- f32 -> bf16 table convert (8/thread) ----------------
__global__ void k_cvt(const float* __restrict__ in, short* __restrict__ o, int ntot) {
  int i = (blockIdx.x * 256 + threadIdx.x) * 8;
  if (i >= ntot) return;
  float4 a = *(const float4*)(in + i);
  float4 b = *(const float4*)(in + i + 4);
  short8 v;
  v[0] = (short)f2bu(a.x); v[1] = (short)f2bu(a.y);
  v[2] = (short)f2bu(a.z); v[3] = (short)f2bu(a.w);
  v[4] = (short)f2bu(b.x); v[5] = (short)f2bu(b.y);
  v[6] = (short)f2bu(b.z); v[7] = (short)f2bu(b.w);
  *(short8*)(o + i) = v;
}

// ---------------- gather + convert referenced rows ------------------------
__global__ void k_cvt_rows(const float* __restrict__ tab, const int* __restrict__ pairs,
                           short* __restrict__ o, int nrows) {
  int t = blockIdx.x * 256 + threadIdx.x;
  if (t >= nrows * 32) return;
  int row = t >> 5;
  int c8 = (t & 31) << 3;
  int id = pairs[2 * row];
  const float* s = tab + (size_t)id * 256 + c8;
  float4 a = *(const float4*)(s);
  float4 b = *(const float4*)(s + 4);
  short8 v;
  v[0] = (short)f2bu(a.x); v[1] = (short)f2bu(a.y);
  v[2] = (short)f2bu(a.z); v[3] = (short)f2bu(a.w);
  v[4] = (short)f2bu(b.x); v[5] = (short)f2bu(b.y);
  v[6] = (short)f2bu(b.z); v[7] = (short)f2bu(b.w);
  *(short8*)(o + (size_t)row * 256 + c8) = v;
}

// ---------------- merged weight prep ------------------------------------
// mode 0 = slab-swizzle (N=256), 1 = transpose->bf16, 2 = cvt
struct Prep {
  const float* src[16];
  short* dst[16];
  int K[16], N[16], mode[16];
  int boff[17];
};
__global__ void k_prep(Prep p) {
  int b = blockIdx.x, e = 0;
#pragma unroll
  for (int i = 1; i < 16; ++i) if (b >= p.boff[i]) e = i;
  int t = (b - p.boff[e]) * 256 + threadIdx.x;
  const int K = p.K[e], N = p.N[e];
  if (t >= K * N) return;
  const float* w = p.src[e];
  const int m = p.mode[e];
  if (m == 2) { p.dst[e][t] = (short)f2bu(w[t]); return; }
  if (m == 0) {
    int ks = t >> 13, rem = t & 8191;
    int P = rem >> 3, j = rem & 7;
    int n = P >> 2;
    int kq = ((P & 3) - (n >> 1)) & 3;
    int k = (ks << 5) + (kq << 3) + j;
    p.dst[e][t] = (short)f2bu(w[(size_t)k * 256 + n]);
    return;
  }
  int n = t / K, k = t - n * K;
  p.dst[e][t] = (short)f2bu(w[(size_t)k * N + n]);
}

// ---------------- RC[6][256]: rate contribution of g_u layer 1 (f32) ------
__global__ void k_rc(const float* __restrict__ rate, const float* __restrict__ w1,
                     float* __restrict__ RC) {
  const int j = blockIdx.x;
  const int n = threadIdx.x;
  float s = 0.f;
  const float* rr = rate + j * 256;
  for (int k = 0; k < 256; ++k)
    s += rr[k] * w1[(size_t)(256 + k) * 256 + n];
  RC[j * 256 + n] = s;
}

// ---------------- QC[G][256]: per-group q contribution of attn layer 1 ----
__global__ __launch_bounds__(256, 4) void k_qc(
    const int* __restrict__ qid, const short* __restrict__ itembf,
    const short* __restrict__ aw1, float* __restrict__ QC)
{
  const int tid = threadIdx.x;
  const int lane = tid & 63;
  const int wave = tid >> 6;
  const int m0 = (int)blockIdx.x << 6;
  const int l15 = lane & 15;
  const int lq = lane >> 4;
  const int nb = wave << 6;

  int pBg[4];
  const short* qp[4];
#pragma unroll
  for (int i = 0; i < 4; ++i) {
    int n = nb + i * 16 + l15;
    pBg[i] = (n * 4 + ((lq + (n >> 1)) & 3)) * 8;
    qp[i] = itembf + (size_t)qid[m0 + i * 16 + l15] * 256 + lq * 8;
  }

  const f32x4 fz = {0.f, 0.f, 0.f, 0.f};
  f32x4 acc[4][4];
#pragma unroll
  for (int ni = 0; ni < 4; ++ni)
#pragma unroll
    for (int mi = 0; mi < 4; ++mi) acc[ni][mi] = fz;

  for (int ks = 0; ks < 8; ++ks) {
    short8 wf[4], qf[4];
#pragma unroll
    for (int i = 0; i < 4; ++i) {
      wf[i] = *(const short8*)(aw1 + (8 + ks) * 8192 + pBg[i]);
      qf[i] = *(const short8*)(qp[i] + ks * 32);
    }
#pragma unroll
    for (int ni = 0; ni < 4; ++ni)
#pragma unroll
      for (int mi = 0; mi < 4; ++mi)
        acc[ni][mi] = mfma16(wf[ni], qf[mi], acc[ni][mi]);
  }
#pragma unroll
  for (int ni = 0; ni < 4; ++ni) {
    const int nbase = nb + ni * 16 + lq * 4;
#pragma unroll
    for (int mi = 0; mi < 4; ++mi) {
      const int m = mi * 16 + l15;
      *(f32x4*)(QC + (size_t)(m0 + m) * 256 + nbase) = acc[ni][mi];
    }
  }
}

// ---------------- fused g_u(item-half) + attu(fjt-half) -------------------
// sH: XOR-swizzled unpadded [64][256] -> LDS 40960 B. X written via
// coalesced copy pass from sH (fixes 8x write amplification).
template <bool IDENT>
__global__ __launch_bounds__(256, 3) void k_fused(
    const int* __restrict__ idx_pairs,
    const short* __restrict__ tab0,
    const float* __restrict__ RC,
    const float* __restrict__ QC,
    const short* __restrict__ ws1, const float* __restrict__ b1,
    const short* __restrict__ ws2, const float* __restrict__ b2,
    const short* __restrict__ aw1, const float* __restrict__ ab1,
    const short* __restrict__ aw2t, const float* __restrict__ ab2,
    short* __restrict__ Xout, short* __restrict__ miu_out)
{
  __shared__ __align__(16) short smem[20480];   // 40960 B total
  short* sA0 = smem;
  short* sA1 = smem + 2048;
  short* sH  = smem + 4096;                     // 16384 shorts, swizzled

  const int tid = threadIdx.x;
  const int lane = tid & 63;
  const int wave = tid >> 6;
  const int m0 = (int)blockIdx.x << 6;
  const int l15 = lane & 15;
  const int lq = lane >> 4;
  const int nb = wave << 6;
  const int swz = (l15 & 7) << 3;               // per-lane sH swizzle

  const int an = tid >> 2;
  const int kqA = ((tid & 3) - (an >> 1)) & 3;
  const int r = m0 + an;
  const int i0 = idx_pairs[2 * r];
  const short* a0 = (IDENT ? (tab0 + (size_t)r * 256) : (tab0 + (size_t)i0 * 256)) + kqA * 8;

  int pBg[4], pA[4];
#pragma unroll
  for (int i = 0; i < 4; ++i) {
    int n = nb + i * 16 + l15;
    pBg[i] = (n * 4 + ((lq + (n >> 1)) & 3)) * 8;
    int m = i * 16 + l15;
    pA[i] = (m * 4 + ((lq + (m >> 1)) & 3)) * 8;
  }
  const int hOff = lq * 8;

  const f32x4 fz = {0.f, 0.f, 0.f, 0.f};
  f32x4 acc[4][4];
#pragma unroll
  for (int ni = 0; ni < 4; ++ni)
#pragma unroll
    for (int mi = 0; mi < 4; ++mi) acc[ni][mi] = fz;

  short8 wfb[3][4];
  short8 ar0, ar1;

  // per-lane row metadata (4 rows per lane: mi*16+l15)
  int i1v[4], mskv[4], grpv[4];
#pragma unroll
  for (int mi = 0; mi < 4; ++mi) {
    const int row = m0 + mi * 16 + l15;
    i1v[mi]  = idx_pairs[2 * row + 1];
    mskv[mi] = idx_pairs[2 * row];
    grpv[mi] = row / 12;
  }

  // ================= g_u layer 1 (K=256 item half, 8 ksteps) =========
  {
    short8 t = *(const short8*)a0;
    *(short8*)(sA0 + tid * 8) = t;
  }
  ar1 = *(const short8*)(a0 + 32);
#pragma unroll
  for (int i = 0; i < 4; ++i) wfb[0][i] = *(const short8*)(ws1 + pBg[i]);
#pragma unroll
  for (int i = 0; i < 4; ++i) wfb[1][i] = *(const short8*)(ws1 + 8192 + pBg[i]);
  __syncthreads();
#pragma unroll
  for (int ks = 0; ks < 8; ++ks) {
    short* sAc = (ks & 1) ? sA1 : sA0;
    short* sAn = (ks & 1) ? sA0 : sA1;
    if (ks < 6) {
      const int c = ks + 2;
      short8 t = *(const short8*)(a0 + c * 32);
      if ((ks & 1) == 0) ar0 = t; else ar1 = t;
      const short* s = ws1 + c * 8192;
#pragma unroll
      for (int i = 0; i < 4; ++i) wfb[c % 3][i] = *(const short8*)(s + pBg[i]);
    }
    short8 xf[4];
#pragma unroll
    for (int i = 0; i < 4; ++i) xf[i] = *(short8*)(sAc + pA[i]);
#pragma unroll
    for (int ni = 0; ni < 4; ++ni)
#pragma unroll
      for (int mi = 0; mi < 4; ++mi)
        acc[ni][mi] = mfma16(wfb[ks % 3][ni], xf[mi], acc[ni][mi]);
    if (ks < 7) {
      short8 w = (((ks + 1) & 1) == 0) ? ar0 : ar1;
      *(short8*)(sAn + tid * 8) = w;
      __syncthreads();
    }
  }
  // hidden = relu(acc + RC[i1] + b1) -> sH (swizzled)
#pragma unroll
  for (int ni = 0; ni < 4; ++ni) {
    const int nbase = nb + ni * 16 + lq * 4;
    float4 bb = *(const float4*)(b1 + nbase);
#pragma unroll
    for (int mi = 0; mi < 4; ++mi) {
      const int m = mi * 16 + l15;
      float4 rc = *(const float4*)(RC + i1v[mi] * 256 + nbase);
      short4v hv;
      hv[0] = (short)f2bu(fmaxf(acc[ni][mi][0] + rc.x + bb.x, 0.f));
      hv[1] = (short)f2bu(fmaxf(acc[ni][mi][1] + rc.y + bb.y, 0.f));
      hv[2] = (short)f2bu(fmaxf(acc[ni][mi][2] + rc.z + bb.z, 0.f));
      hv[3] = (short)f2bu(fmaxf(acc[ni][mi][3] + rc.w + bb.w, 0.f));
      *(short4v*)(sH + m * 256 + (nbase ^ swz)) = hv;
    }
  }
  __syncthreads();   // publish hidden

  // ================= g_u layer 2 (K=256, barrier-free) =================
#pragma unroll
  for (int ni = 0; ni < 4; ++ni)
#pragma unroll
    for (int mi = 0; mi < 4; ++mi) acc[ni][mi] = fz;
#pragma unroll
  for (int i = 0; i < 4; ++i) wfb[0][i] = *(const short8*)(ws2 + pBg[i]);
#pragma unroll
  for (int i = 0; i < 4; ++i) wfb[1][i] = *(const short8*)(ws2 + 8192 + pBg[i]);
#pragma unroll
  for (int ks = 0; ks < 8; ++ks) {
    if (ks < 6) {
      const short* s = ws2 + (ks + 2) * 8192;
#pragma unroll
      for (int i = 0; i < 4; ++i) wfb[(ks + 2) % 3][i] = *(const short8*)(s + pBg[i]);
    }
    short8 hf[4];
#pragma unroll
    for (int i = 0; i < 4; ++i)
      hf[i] = *(short8*)(sH + (i * 16 + l15) * 256 + ((ks * 32 + hOff) ^ swz));
#pragma unroll
    for (int ni = 0; ni < 4; ++ni)
#pragma unroll
      for (int mi = 0; mi < 4; ++mi)
        acc[ni][mi] = mfma16(wfb[ks % 3][ni], hf[mi], acc[ni][mi]);
  }
  __syncthreads();   // all done reading sH(hidden)

  // f_jt = acc + b2 -> sH (swizzled only; X written by copy pass below)
#pragma unroll
  for (int ni = 0; ni < 4; ++ni) {
    const int nbase = nb + ni * 16 + lq * 4;
    float4 bb = *(const float4*)(b2 + nbase);
#pragma unroll
    for (int mi = 0; mi < 4; ++mi) {
      const int m = mi * 16 + l15;
      short4v hv;
      hv[0] = (short)f2bu(acc[ni][mi][0] + bb.x);
      hv[1] = (short)f2bu(acc[ni][mi][1] + bb.y);
      hv[2] = (short)f2bu(acc[ni][mi][2] + bb.z);
      hv[3] = (short)f2bu(acc[ni][mi][3] + bb.w);
      *(short4v*)(sH + m * 256 + (nbase ^ swz)) = hv;
    }
  }
  __syncthreads();   // publish f_jt

  // coalesced X write: 32 lanes cover one 512B row segment contiguously
#pragma unroll
  for (int p = 0; p < 8; ++p) {
    const int rr = (tid >> 5) + p * 8;
    const int c8 = (tid & 31) * 8;
    short8 v = *(short8*)(sH + rr * 256 + (c8 ^ ((rr & 7) << 3)));
    *(short8*)(Xout + (size_t)(m0 + rr) * 256 + c8) = v;
  }

  // ================= attn layer 1 (K=256 f_jt half, barrier-free) ========
#pragma unroll
  for (int ni = 0; ni < 4; ++ni)
#pragma unroll
    for (int mi = 0; mi < 4; ++mi) acc[ni][mi] = fz;
#pragma unroll
  for (int i = 0; i < 4; ++i) wfb[0][i] = *(const short8*)(aw1 + pBg[i]);
#pragma unroll
  for (int i = 0; i < 4; ++i) wfb[1][i] = *(const short8*)(aw1 + 8192 + pBg[i]);
#pragma unroll
  for (int ks = 0; ks < 8; ++ks) {
    if (ks < 6) {
      const short* s = aw1 + (ks + 2) * 8192;
#pragma unroll
      for (int i = 0; i < 4; ++i) wfb[(ks + 2) % 3][i] = *(const short8*)(s + pBg[i]);
    }
    short8 xf[4];
#pragma unroll
    for (int i = 0; i < 4; ++i)
      xf[i] = *(short8*)(sH + (i * 16 + l15) * 256 + ((ks * 32 + hOff) ^ swz));
#pragma unroll
    for (int ni = 0; ni < 4; ++ni)
#pragma unroll
      for (int mi = 0; mi < 4; ++mi)
        acc[ni][mi] = mfma16(wfb[ks % 3][ni], xf[mi], acc[ni][mi]);
  }
  __syncthreads();   // all done reading sH(f_jt)

  // attn hidden = relu(acc + mask*QC[grp] + ab1) -> sH (overwrite)
#pragma unroll
  for (int ni = 0; ni < 4; ++ni) {
    const int nbase = nb + ni * 16 + lq * 4;
    float4 bb = *(const float4*)(ab1 + nbase);
#pragma unroll
    for (int mi = 0; mi < 4; ++mi) {
      const int m = mi * 16 + l15;
      float4 qv;
      if (mskv[mi] > 0) qv = *(const float4*)(QC + (size_t)grpv[mi] * 256 + nbase);
      else { qv.x = 0.f; qv.y = 0.f; qv.z = 0.f; qv.w = 0.f; }
      short4v hv;
      hv[0] = (short)f2bu(fmaxf(acc[ni][mi][0] + qv.x + bb.x, 0.f));
      hv[1] = (short)f2bu(fmaxf(acc[ni][mi][1] + qv.y + bb.y, 0.f));
      hv[2] = (short)f2bu(fmaxf(acc[ni][mi][2] + qv.z + bb.z, 0.f));
      hv[3] = (short)f2bu(fmaxf(acc[ni][mi][3] + qv.w + bb.w, 0.f));
      *(short4v*)(sH + m * 256 + (nbase ^ swz)) = hv;
    }
  }
  __syncthreads();

  // ================= attn layer 2 (256 -> 16), W2 direct ==========
  f32x4 a2 = fz;
#pragma unroll
  for (int ks = 0; ks < 8; ++ks) {
    short8 af = *(short8*)(sH + (wave * 16 + l15) * 256 + ((ks * 32 + hOff) ^ swz));
    short8 bv = *(const short8*)(aw2t + l15 * 256 + ks * 32 + hOff);
    a2 = mfma16(af, bv, a2);
  }
  const float bias = ab2[l15];
#pragma unroll
  for (int j = 0; j < 4; ++j)
    miu_out[(size_t)(m0 + wave * 16 + lq * 4 + j) * 16 + l15] = (short)f2bu(a2[j] + bias);
}

// ---------------- kappa scores (bf16 out) ---------------------------------
__global__ __launch_bounds__(256, 3) void k_attonly(
    const short* __restrict__ first,
    const short* __restrict__ itembf,
    const int* __restrict__ iidx,
    const short* __restrict__ aw1, const float* __restrict__ ab1,
    const short* __restrict__ aw2t, const float* __restrict__ ab2,
    short* __restrict__ out)
{
  __shared__ __align__(16) short sH[16896];

  const int tid = threadIdx.x;
  const int lane = tid & 63;
  const int wave = tid >> 6;
  const int m0 = (int)blockIdx.x << 6;
  const int l15 = lane & 15;
  const int lq = lane >> 4;
  const int nb = wave << 6;
  const int hOff = lq * 8;

  const short* fp[4];
  const short* qp[4];
  int pBg[4];
#pragma unroll
  for (int i = 0; i < 4; ++i) {
    int mrow = m0 + i * 16 + l15;
    fp[i] = first + (size_t)mrow * 256 + hOff;
    qp[i] = itembf + (size_t)iidx[mrow] * 256 + hOff;
    int n = nb + i * 16 + l15;
    pBg[i] = (n * 4 + ((lq + (n >> 1)) & 3)) * 8;
  }

  const f32x4 fz = {0.f, 0.f, 0.f, 0.f};
  f32x4 acc[4][4];
#pragma unroll
  for (int ni = 0; ni < 4; ++ni)
#pragma unroll
    for (int mi = 0; mi < 4; ++mi) acc[ni][mi] = fz;

  short8 wfc[4], wfn[4], xfc[4], xfn[4];
#pragma unroll
  for (int i = 0; i < 4; ++i) {
    wfc[i] = *(const short8*)(aw1 + pBg[i]);
    xfc[i] = *(const short8*)(fp[i]);
  }
  for (int ks = 0; ks < 16; ++ks) {
    if (ks < 15) {
      const int c = ks + 1;
      const short* s = aw1 + c * 8192;
#pragma unroll
      for (int i = 0; i < 4; ++i) {
        wfn[i] = *(const short8*)(s + pBg[i]);
        xfn[i] = *(const short8*)((c < 8) ? (fp[i] + c * 32) : (qp[i] + (c - 8) * 32));
      }
    }
#pragma unroll
    for (int ni = 0; ni < 4; ++ni)
#pragma unroll
      for (int mi = 0; mi < 4; ++mi)
        acc[ni][mi] = mfma16(wfc[ni], xfc[mi], acc[ni][mi]);
    if (ks < 15) {
#pragma unroll
      for (int i = 0; i < 4; ++i) { wfc[i] = wfn[i]; xfc[i] = xfn[i]; }
    }
  }
#pragma unroll
  for (int ni = 0; ni < 4; ++ni) {
    const int nbase = nb + ni * 16 + lq * 4;
    float4 bb = *(const float4*)(ab1 + nbase);
#pragma unroll
    for (int mi = 0; mi < 4; ++mi) {
      const int m = mi * 16 + l15;
      short4v hv;
      hv[0] = (short)f2bu(fmaxf(acc[ni][mi][0] + bb.x, 0.f));
      hv[1] = (short)f2bu(fmaxf(acc[ni][mi][1] + bb.y, 0.f));
      hv[2] = (short)f2bu(fmaxf(acc[ni][mi][2] + bb.z, 0.f));
      hv[3] = (short)f2bu(fmaxf(acc[ni][mi][3] + bb.w, 0.f));
      *(short4v*)(sH + m * 264 + nbase) = hv;
    }
  }
  __syncthreads();
  f32x4 a2 = fz;
#pragma unroll
  for (int ks = 0; ks < 8; ++ks) {
    short8 af = *(short8*)(sH + (wave * 16 + l15) * 264 + ks * 32 + hOff);
    short8 bv = *(const short8*)(aw2t + l15 * 256 + ks * 32 + hOff);
    a2 = mfma16(af, bv, a2);
  }
  const float bias = ab2[l15];
#pragma unroll
  for (int j = 0; j < 4; ++j)
    out[(size_t)(m0 + wave * 16 + lq * 4 + j) * 16 + l15] = (short)f2bu(a2[j] + bias);
}

// ---------------- single-layer GEMM 256->256 + bias + relu (no LDS) -------
__global__ __launch_bounds__(256, 3) void k_gemm1(
    const short* __restrict__ Abf, const short* __restrict__ wt,
    const float* __restrict__ bias, short* __restrict__ out)
{
  const int tid  = threadIdx.x;
  const int lane = tid & 63;
  const int wave = tid >> 6;
  const int m0   = blockIdx.x << 6;
  const int l15  = lane & 15;
  const int lq   = lane >> 4;
  const int rq   = lq << 2;
  const int nb   = wave << 6;
  const int hOff = lq * 8;

  const f32x4 fz = {0.f, 0.f, 0.f, 0.f};
  f32x4 acc[4][4];
#pragma unroll
  for (int mi = 0; mi < 4; ++mi)
#pragma unroll
    for (int ni = 0; ni < 4; ++ni) acc[mi][ni] = fz;

  for (int ks = 0; ks < 8; ++ks) {
    short8 af[4], bv[4];
#pragma unroll
    for (int i = 0; i < 4; ++i) {
      af[i] = *(const short8*)(Abf + (size_t)(m0 + i * 16 + l15) * 256 + ks * 32 + hOff);
      bv[i] = *(const short8*)(wt + (size_t)(nb + i * 16 + l15) * 256 + ks * 32 + hOff);
    }
#pragma unroll
    for (int mi = 0; mi < 4; ++mi)
#pragma unroll
      for (int ni = 0; ni < 4; ++ni)
        acc[mi][ni] = mfma16(af[mi], bv[ni], acc[mi][ni]);
  }

#pragma unroll
  for (int ni = 0; ni < 4; ++ni) {
    const int col = nb + ni * 16 + l15;
    const float b = bias[col];
#pragma unroll
    for (int mi = 0; mi < 4; ++mi)
#pragma unroll
      for (int j = 0; j < 4; ++j) {
        const int row = mi * 16 + rq + j;
        out[(size_t)(m0 + row) * 256 + col] = (short)f2bu(fmaxf(acc[mi][ni][j] + b, 0.f));
      }
  }
}

// ---------------- fused 3-layer comb MLP --------------------------------
__global__ __launch_bounds__(256, 2) void k_comb(
    const short* __restrict__ hju, const short* __restrict__ hjv,
    const short* __restrict__ w1t, const float* __restrict__ b1,
    const short* __restrict__ w2t, const float* __restrict__ b2,
    const short* __restrict__ w3t, const float* __restrict__ b3,
    float* __restrict__ out)
{
  __shared__ __align__(16) short smem[29696];
  short (*A)[40]   = (short(*)[40])smem;
  short (*Bt)[40]  = (short(*)[40])(smem + 2560);
  short (*Hh)[264] = (short(*)[264])(smem + 12800);

  const int tid  = threadIdx.x;
  const int lane = tid & 63;
  const int wave = tid >> 6;
  const int m0   = blockIdx.x << 6;
  const int arow = tid >> 2;
  const int acol8 = (tid & 3) << 3;
  const int lrow = lane & 15;
  const int lk8  = (lane >> 4) << 3;
  const int rq   = (lane >> 4) << 2;
  const int nb   = wave << 6;
  const int r = m0 + arow;

  const f32x4 fz = {0.f, 0.f, 0.f, 0.f};
  f32x4 acc[4][4];
#pragma unroll
  for (int mi = 0; mi < 4; ++mi)
#pragma unroll
    for (int ni = 0; ni < 4; ++ni) acc[mi][ni] = fz;

  for (int ks = 0; ks < 16; ++ks) {
    const int kg = (ks << 5) + acol8;
    short8 av = (kg < 256) ? *(const short8*)(hju + (size_t)r * 256 + kg)
                           : *(const short8*)(hjv + (size_t)r * 256 + (kg - 256));
    *(short8*)&A[arow][acol8] = av;
    const short* wsrc = w1t + tid * 512 + (ks << 5);
    *(short8*)&Bt[tid][0]  = *(const short8*)(wsrc);
    *(short8*)&Bt[tid][8]  = *(const short8*)(wsrc + 8);
    *(short8*)&Bt[tid][16] = *(const short8*)(wsrc + 16);
    *(short8*)&Bt[tid][24] = *(const short8*)(wsrc + 24);
    __syncthreads();
    short8 af[4], bv[4];
#pragma unroll
    for (int mi = 0; mi < 4; ++mi) af[mi] = *(short8*)&A[mi * 16 + lrow][lk8];
#pragma unroll
    for (int ni = 0; ni < 4; ++ni) bv[ni] = *(short8*)&Bt[nb + ni * 16 + lrow][lk8];
#pragma unroll
    for (int mi = 0; mi < 4; ++mi)
#pragma unroll
      for (int ni = 0; ni < 4; ++ni)
        acc[mi][ni] = mfma16(af[mi], bv[ni], acc[mi][ni]);
    __syncthreads();
  }
#pragma unroll
  for (int ni = 0; ni < 4; ++ni) {
    const int col = nb + ni * 16 + lrow;
    const float bias = b1[col];
#pragma unroll
    for (int mi = 0; mi < 4; ++mi)
#pragma unroll
      for (int j = 0; j < 4; ++j)
        Hh[mi * 16 + rq + j][col] = (short)f2bu(fmaxf(acc[mi][ni][j] + bias, 0.f));
  }

#pragma unroll
  for (int mi = 0; mi < 4; ++mi)
#pragma unroll
    for (int ni = 0; ni < 4; ++ni) acc[mi][ni] = fz;
  for (int ks = 0; ks < 8; ++ks) {
    const short* wsrc = w2t + tid * 256 + (ks << 5);
    *(short8*)&Bt[tid][0]  = *(const short8*)(wsrc);
    *(short8*)&Bt[tid][8]  = *(const short8*)(wsrc + 8);
    *(short8*)&Bt[tid][16] = *(const short8*)(wsrc + 16);
    *(short8*)&Bt[tid][24] = *(const short8*)(wsrc + 24);
    __syncthreads();
    short8 af[4], bv[4];
#pragma unroll
    for (int mi = 0; mi < 4; ++mi) af[mi] = *(short8*)&Hh[mi * 16 + lrow][(ks << 5) + lk8];
#pragma unroll
    for (int ni = 0; ni < 4; ++ni) bv[ni] = *(short8*)&Bt[nb + ni * 16 + lrow][lk8];
#pragma unroll
    for (int mi = 0; mi < 4; ++mi)
#pragma unroll
      for (int ni = 0; ni < 4; ++ni)
        acc[mi][ni] = mfma16(af[mi], bv[ni], acc[mi][ni]);
    __syncthreads();
  }
#pragma unroll
  for (int ni = 0; ni < 4; ++ni) {
    const int col = nb + ni * 16 + lrow;
    const float bias = b2[col];
#pragma unroll
    for (int mi = 0; mi < 4; ++mi)
#pragma unroll
      for (int j = 0; j < 4; ++j)
        Hh[mi * 16 + rq + j][col] = (short)f2bu(fmaxf(acc[mi][ni][j] + bias, 0.f));
  }
  __syncthreads();

#pragma unroll
  for (int mi = 0; mi < 4; ++mi)
#pragma unroll
    for (int ni = 0; ni < 4; ++ni) acc[mi][ni] = fz;
  for (int ks = 0; ks < 8; ++ks) {
    const short* wsrc = w3t + tid * 256 + (ks << 5);
    *(short8*)&Bt[tid][0]  = *(const short8*)(wsrc);
    *(short8*)&Bt[tid][8]  = *(const short8*)(wsrc + 8);
    *(short8*)&Bt[tid][16] = *(const short8*)(wsrc + 16);
    *(short8*)&Bt[tid][24] = *(const short8*)(wsrc + 24);
    __syncthreads();
    short8 af[4], bv[4];
#pragma unroll
    for (int mi = 0; mi < 4; ++mi) af[mi] = *(short8*)&Hh[mi * 16 + lrow][(ks << 5) + lk8];
#pragma unroll
    for (int ni = 0; ni < 4; ++ni) bv[ni] = *(short8*)&Bt[nb + ni * 16 + lrow][lk8];
#pragma unroll
    for (int mi = 0; mi < 4; ++mi)
#pragma unroll
      for (int ni = 0; ni < 4; ++ni)
        acc[mi][ni] = mfma16(af[mi], bv[ni], acc[mi][ni]);
    __syncthreads();
  }
#pragma unroll
  for (int ni = 0; ni < 4; ++ni) {
    const int col = nb + ni * 16 + lrow;
    const float bias = b3[col];
#pragma unroll
    for (int mi = 0; mi < 4; ++mi)
#pragma unroll
      for (int j = 0; j < 4; ++j) {
        const int row = mi * 16 + rq + j;
        out[(size_t)(m0 + row) * 256 + col] = fmaxf(acc[mi][ni][j] + bias, 0.f);
      }
  }
}

// ---------------- head MLP1 as MFMA GEMM: [G][192] -> [G][96], relu ------
__global__ __launch_bounds__(256, 4) void k_h1(
    const short* __restrict__ A, const short* __restrict__ w1t,
    const float* __restrict__ b1, short* __restrict__ h1)
{
  const int tid = threadIdx.x;
  const int lane = tid & 63;
  const int wave = tid >> 6;
  const int m0 = (int)blockIdx.x << 6;
  const int l15 = lane & 15;
  const int lq = lane >> 4;
  const int ntc = (wave < 2) ? 2 : 1;
  const int nta = wave;
  const int ntb = wave + 4;

  const f32x4 fz = {0.f, 0.f, 0.f, 0.f};
  f32x4 acc[4][2];
#pragma unroll
  for (int i = 0; i < 4; ++i) { acc[i][0] = fz; acc[i][1] = fz; }

  for (int ks = 0; ks < 6; ++ks) {
    short8 af[4], bv[2];
#pragma unroll
    for (int i = 0; i < 4; ++i)
      af[i] = *(const short8*)(A + (size_t)(m0 + i * 16 + l15) * 192 + ks * 32 + lq * 8);
    bv[0] = *(const short8*)(w1t + (nta * 16 + l15) * 192 + ks * 32 + lq * 8);
    if (ntc == 2)
      bv[1] = *(const short8*)(w1t + (ntb * 16 + l15) * 192 + ks * 32 + lq * 8);
#pragma unroll
    for (int j = 0; j < 2; ++j)
      if (j < ntc)
#pragma unroll
        for (int i = 0; i < 4; ++i)
          acc[i][j] = mfma16(bv[j], af[i], acc[i][j]);
  }
#pragma unroll
  for (int j = 0; j < 2; ++j) {
    if (j >= ntc) continue;
    const int nbase = (j == 0 ? nta : ntb) * 16 + lq * 4;
    float4 bb = *(const float4*)(b1 + nbase);
#pragma unroll
    for (int i = 0; i < 4; ++i) {
      const int row = m0 + i * 16 + l15;
      short4v hv;
      hv[0] = (short)f2bu(fmaxf(acc[i][j][0] + bb.x, 0.f));
      hv[1] = (short)f2bu(fmaxf(acc[i][j][1] + bb.y, 0.f));
      hv[2] = (short)f2bu(fmaxf(acc[i][j][2] + bb.z, 0.f));
      hv[3] = (short)f2bu(fmaxf(acc[i][j][3] + bb.w, 0.f));
      *(short4v*)(h1 + (size_t)row * 96 + nbase) = hv;
    }
  }
}

// ---------------- head MLP2 + masked softmax -> weights [G][12] f32 -------
__global__ __launch_bounds__(256) void k_h2(
    const short* __restrict__ h1, const short* __restrict__ w2t,
    const float* __restrict__ b2,
    const int* __restrict__ mask_src, const int mstride,
    float* __restrict__ W)
{
  __shared__ float wgt[16][12];
  const int tid = threadIdx.x;
  const int gg = tid >> 4, sl = tid & 15;
  const int g = blockIdx.x * 16 + gg;
  if (sl < 12) {
    float s = b2[sl];
    const short* hr = h1 + (size_t)g * 96;
    const short* wr = w2t + sl * 96;
#pragma unroll
    for (int kk = 0; kk < 12; ++kk) {
      short8 hv = *(const short8*)(hr + kk * 8);
      short8 wv = *(const short8*)(wr + kk * 8);
#pragma unroll
      for (int j = 0; j < 8; ++j)
        s += b2f((unsigned short)hv[j]) * b2f((unsigned short)wv[j]);
    }
    const int mi = mask_src[(g * 12 + sl) * mstride];
    wgt[gg][sl] = (mi > 0) ? expf(s) : 0.f;
  }
  __syncthreads();
  if (sl < 12) {
    float tot = 1e-10f;
#pragma unroll
    for (int m = 0; m < 12; ++m) tot += wgt[gg][m];
    W[(size_t)g * 12 + sl] = wgt[gg][sl] / tot;
  }
}

// ---------------- weighted sum: out[g] = sum_m W[g][m] * X[g*12+m] --------
__global__ __launch_bounds__(256) void k_wsum(
    const float* __restrict__ W, const short* __restrict__ X,
    short* __restrict__ out)
{
  const int tid = threadIdx.x;
  const int g = blockIdx.x * 8 + (tid >> 5);
  const int d0 = (tid & 31) * 8;
  const float* wg = W + (size_t)g * 12;
  float w[12];
#pragma unroll
  for (int m = 0; m < 12; ++m) w[m] = wg[m];
  const short* xp = X + (size_t)g * 12 * 256 + d0;
  float o[8];
#pragma unroll
  for (int j = 0; j < 8; ++j) o[j] = 0.f;
#pragma unroll
  for (int m = 0; m < 12; ++m) {
    short8 x = *(const short8*)(xp + m * 256);
#pragma unroll
    for (int j = 0; j < 8; ++j) o[j] += w[m] * b2f((unsigned short)x[j]);
  }
  short8 v;
#pragma unroll
  for (int j = 0; j < 8; ++j) v[j] = (short)f2bu(o[j]);
  *(short8*)(out + (size_t)g * 256 + d0) = v;
}

// =====================================================================
extern "C" void kernel_launch(void* const* d_in, const int* in_sizes, int n_in,
                              void* d_out, int out_size, void* d_ws, size_t ws_size,
                              hipStream_t stream)
{
  (void)in_sizes; (void)n_in; (void)out_size; (void)ws_size;

  const int*   iids = (const int*)d_in[0];
  const int*   iup  = (const int*)d_in[1];
  const int*   iip  = (const int*)d_in[2];
  const int*   iiup = (const int*)d_in[3];
  const float* user_table = (const float*)d_in[4];
  const float* item_table = (const float*)d_in[5];
  const float* rate_table = (const float*)d_in[6];
  const float* g_u_w1 = (const float*)d_in[7];   const float* g_u_b1 = (const float*)d_in[8];
  const float* g_u_w2 = (const float*)d_in[9];   const float* g_u_b2 = (const float*)d_in[10];
  const float* attu_w1 = (const float*)d_in[11]; const float* attu_b1 = (const float*)d_in[12];
  const float* attu_w2 = (const float*)d_in[13]; const float* attu_b2 = (const float*)d_in[14];
  const float* headu_w1 = (const float*)d_in[15]; const float* headu_b1 = (const float*)d_in[16];
  const float* headu_w2 = (const float*)d_in[17]; const float* headu_b2 = (const float*)d_in[18];
  const float* aggi_w = (const float*)d_in[19];  const float* aggi_b = (const float*)d_in[20];
  const float* attii_w1 = (const float*)d_in[21]; const float* attii_b1 = (const float*)d_in[22];
  const float* attii_w2 = (const float*)d_in[23]; const float* attii_b2 = (const float*)d_in[24];
  const float* headii_w1 = (const float*)d_in[25]; const float* headii_b1 = (const float*)d_in[26];
  const float* headii_w2 = (const float*)d_in[27]; const float* headii_b2 = (const float*)d_in[28];
  const float* aggii_w = (const float*)d_in[29]; const float* aggii_b = (const float*)d_in[30];
  const float* comb_w1 = (const float*)d_in[31]; const float* comb_b1 = (const float*)d_in[32];
  const float* comb_w2 = (const float*)d_in[33]; const float* comb_b2 = (const float*)d_in[34];
  const float* comb_w3 = (const float*)d_in[35]; const float* comb_b3 = (const float*)d_in[36];

  const int NIe = 100000 * 256;
  const int M2 = 2048 * 12 * 12;
  const int M1 = 2048 * 12;
  const int G2 = M1;
  const int G1 = 2048;

  char* wsp = (char*)d_ws;
  size_t off = 0;
  auto alloc = [&](size_t bytes) -> void* {
    void* p = wsp + off;
    off += (bytes + 255) & ~(size_t)255;
    return p;
  };
  short* item_bf = (short*)alloc((size_t)NIe * 2);
  short* urows   = (short*)alloc((size_t)M1 * 256 * 2);
  short* sl_gu1   = (short*)alloc((size_t)512 * 256 * 2);
  short* sl_gu2   = (short*)alloc((size_t)256 * 256 * 2);
  short* sl_attu1 = (short*)alloc((size_t)512 * 256 * 2);
  short* sl_attii1= (short*)alloc((size_t)512 * 256 * 2);
  short* wt_attu2 = (short*)alloc((size_t)256 * 16 * 2);
  short* wt_attii2= (short*)alloc((size_t)256 * 16 * 2);
  short* wt_aggi   = (short*)alloc((size_t)256 * 256 * 2);
  short* wt_aggii  = (short*)alloc((size_t)256 * 256 * 2);
  short* wt_comb1  = (short*)alloc((size_t)512 * 256 * 2);
  short* wt_comb2  = (short*)alloc((size_t)256 * 256 * 2);
  short* wt_comb3  = (short*)alloc((size_t)256 * 256 * 2);
  short* hu1t  = (short*)alloc((size_t)96 * 192 * 2);
  short* hu2t  = (short*)alloc((size_t)12 * 96 * 2);
  short* hii1t = (short*)alloc((size_t)96 * 192 * 2);
  short* hii2t = (short*)alloc((size_t)12 * 96 * 2);
  float* RC    = (float*)alloc((size_t)6 * 256 * 4);
  float* QC2   = (float*)alloc((size_t)G2 * 256 * 4);
  float* QC1   = (float*)alloc((size_t)G1 * 256 * 4);

  short* X      = (short*)alloc((size_t)M2 * 256 * 2);
  short* FJT    = (short*)alloc((size_t)M1 * 256 * 2);
  short* MIU2   = (short*)alloc((size_t)M2 * 16 * 2);
  short* MIU1   = (short*)alloc((size_t)M1 * 16 * 2);
  short* KAP    = (short*)alloc((size_t)M1 * 16 * 2);
  short* H1A    = (short*)alloc((size_t)G2 * 96 * 2);
  short* H1K    = (short*)alloc((size_t)G1 * 96 * 2);
  short* H1M    = (short*)alloc((size_t)G1 * 96 * 2);
  float* WA     = (float*)alloc((size_t)G2 * 12 * 4);
  float* WK     = (float*)alloc((size_t)G1 * 12 * 4);
  float* WM     = (float*)alloc((size_t)G1 * 12 * 4);
  short* HPRE2  = (short*)alloc((size_t)M1 * 256 * 2);
  short* HOU    = (short*)alloc((size_t)M1 * 256 * 2);
  short* HPREJV = (short*)alloc((size_t)2048 * 256 * 2);
  short* HPRE1  = (short*)alloc((size_t)2048 * 256 * 2);
  short* HJU    = (short*)alloc((size_t)2048 * 256 * 2);
  short* HJV    = (short*)alloc((size_t)2048 * 256 * 2);

  k_cvt<<<NIe / 8 / 256, 256, 0, stream>>>(item_table, item_bf, NIe);
  k_cvt_rows<<<(M1 * 32) / 256, 256, 0, stream>>>(user_table, iup, urows, M1);
  k_rc<<<6, 256, 0, stream>>>(rate_table, g_u_w1, RC);

  Prep pp;
  int nbk = 0, ei = 0;
  auto addw = [&](const float* s, short* d, int K, int N, int mode) {
    pp.src[ei] = s; pp.dst[ei] = d; pp.K[ei] = K; pp.N[ei] = N; pp.mode[ei] = mode;
    pp.boff[ei] = nbk; nbk += (K * N + 255) / 256; ++ei;
  };
  addw(g_u_w1,   sl_gu1,    512, 256, 0);
  addw(g_u_w2,   sl_gu2,    256, 256, 0);
  addw(attu_w1,  sl_attu1,  512, 256, 0);
  addw(attii_w1, sl_attii1, 512, 256, 0);
  addw(attu_w2,  wt_attu2,  256, 16, 1);
  addw(attii_w2, wt_attii2, 256, 16, 1);
  addw(aggi_w,   wt_aggi,   256, 256, 1);
  addw(aggii_w,  wt_aggii,  256, 256, 1);
  addw(comb_w1,  wt_comb1,  512, 256, 1);
  addw(comb_w2,  wt_comb2,  256, 256, 1);
  addw(comb_w3,  wt_comb3,  256, 256, 1);
  addw(headu_w1,  hu1t,  192, 96, 1);
  addw(headu_w2,  hu2t,  96, 12, 1);
  addw(headii_w1, hii1t, 192, 96, 1);
  addw(headii_w2, hii2t, 96, 12, 1);
  pp.boff[15] = nbk;
  pp.boff[16] = nbk;
  k_prep<<<nbk, 256, 0, stream>>>(pp);

  // per-group attn q contributions
  k_qc<<<G2 / 64, 256, 0, stream>>>(iip, item_bf, sl_attu1, QC2);
  k_qc<<<G1 / 64, 256, 0, stream>>>(iids, item_bf, sl_attu1, QC1);

  // fused g_u + attu
  k_fused<false><<<M2 / 64, 256, 0, stream>>>(iiup, item_bf, RC, QC2,
                                              sl_gu1, g_u_b1, sl_gu2, g_u_b2,
                                              sl_attu1, attu_b1, wt_attu2, attu_b2,
                                              X, MIU2);
  k_fused<true><<<M1 / 64, 256, 0, stream>>>(iup, urows, RC, QC1,
                                             sl_gu1, g_u_b1, sl_gu2, g_u_b2,
                                             sl_attu1, attu_b1, wt_attu2, attu_b2,
                                             FJT, MIU1);

  // head chain (part-2 inner): MIU2 -> W -> HPRE2
  k_h1<<<G2 / 64, 256, 0, stream>>>(MIU2, hu1t, headu_b1, H1A);
  k_h2<<<G2 / 16, 256, 0, stream>>>(H1A, hu2t, headu_b2, iiup, 2, WA);
  k_wsum<<<G2 / 8, 256, 0, stream>>>(WA, X, HPRE2);

  k_gemm1<<<M1 / 64, 256, 0, stream>>>(HPRE2, wt_aggi, aggi_b, HOU);
  k_attonly<<<M1 / 64, 256, 0, stream>>>(HOU, item_bf, iip,
                                         sl_attii1, attii_b1, wt_attii2, attii_b2, KAP);

  // kappa head chain: KAP -> WK -> HPREJV
  k_h1<<<G1 / 64, 256, 0, stream>>>(KAP, hii1t, headii_b1, H1K);
  k_h2<<<G1 / 16, 256, 0, stream>>>(H1K, hii2t, headii_b2, iip, 1, WK);
  k_wsum<<<G1 / 8, 256, 0, stream>>>(WK, HOU, HPREJV);

  // part-1 head chain: MIU1 -> WM -> HPRE1
  k_h1<<<G1 / 64, 256, 0, stream>>>(MIU1, hu1t, headu_b1, H1M);
  k_h2<<<G1 / 16, 256, 0, stream>>>(H1M, hu2t, headu_b2, iup, 2, WM);
  k_wsum<<<G1 / 8, 256, 0, stream>>>(WM, FJT, HPRE1);

  k_gemm1<<<2048 / 64, 256, 0, stream>>>(HPRE1, wt_aggi, aggi_b, HJU);
  k_gemm1<<<2048 / 64, 256, 0, stream>>>(HPREJV, wt_aggii, aggii_b, HJV);
  k_comb<<<2048 / 64, 256, 0, stream>>>(HJU, HJV, wt_comb1, comb_b1,
                                        wt_comb2, comb_b2, wt_comb3, comb_b3,
                                        (float*)d_out);
}

// Round 15
// 484.475 us; speedup vs baseline: 1.0840x; 1.0060x over previous
//
#include <hip/hip_runtime.h>
#include <cstdint>
#include <cstddef>

typedef short short8 __attribute__((ext_vector_type(8)));
typedef short short4v __attribute__((ext_vector_type(4)));
typedef float f32x4 __attribute__((ext_vector_type(4)));
typedef __bf16 bf16x8 __attribute__((ext_vector_type(8)));

// native HW RNE f32->bf16 (compiles to v_cvt_pk_bf16_f32 when paired)
__device__ __forceinline__ unsigned short f2bu(float f) {
  return __builtin_bit_cast(unsigned short, (__bf16)f);
}
__device__ __forceinline__ float b2f(unsigned short h) {
  union { unsigned u; float f; } v; v.u = ((unsigned)h) << 16;
  return v.f;
}

__device__ __forceinline__ f32x4 mfma16(short8 a, short8 b, f32x4 c) {
  return __builtin_amdgcn_mfma_f32_16x16x32_bf16(
      __builtin_bit_cast(bf16x8, a), __builtin_bit_cast(bf16x8, b), c, 0, 0, 0);
}

// ---------------- f32 -> bf16 table convert (8/thread) ----------------
__global__ void k_cvt(const float* __restrict__ in, short* __restrict__ o, int ntot) {
  int i = (blockIdx.x * 256 + threadIdx.x) * 8;
  if (i >= ntot) return;
  float4 a = *(const float4*)(in + i);
  float4 b = *(const float4*)(in + i + 4);
  short8 v;
  v[0] = (short)f2bu(a.x); v[1] = (short)f2bu(a.y);
  v[2] = (short)f2bu(a.z); v[3] = (short)f2bu(a.w);
  v[4] = (short)f2bu(b.x); v[5] = (short)f2bu(b.y);
  v[6] = (short)f2bu(b.z); v[7] = (short)f2bu(b.w);
  *(short8*)(o + i) = v;
}

// ---------------- gather + convert referenced rows ------------------------
__global__ void k_cvt_rows(const float* __restrict__ tab, const int* __restrict__ pairs,
                           short* __restrict__ o, int nrows) {
  int t = blockIdx.x * 256 + threadIdx.x;
  if (t >= nrows * 32) return;
  int row = t >> 5;
  int c8 = (t & 31) << 3;
  int id = pairs[2 * row];
  const float* s = tab + (size_t)id * 256 + c8;
  float4 a = *(const float4*)(s);
  float4 b = *(const float4*)(s + 4);
  short8 v;
  v[0] = (short)f2bu(a.x); v[1] = (short)f2bu(a.y);
  v[2] = (short)f2bu(a.z); v[3] = (short)f2bu(a.w);
  v[4] = (short)f2bu(b.x); v[5] = (short)f2bu(b.y);
  v[6] = (short)f2bu(b.z); v[7] = (short)f2bu(b.w);
  *(short8*)(o + (size_t)row * 256 + c8) = v;
}

// ---------------- merged weight prep ------------------------------------
// mode 0 = slab-swizzle (N=256), 1 = transpose->bf16, 2 = cvt
struct Prep {
  const float* src[16];
  short* dst[16];
  int K[16], N[16], mode[16];
  int boff[17];
};
__global__ void k_prep(Prep p) {
  int b = blockIdx.x, e = 0;
#pragma unroll
  for (int i = 1; i < 16; ++i) if (b >= p.boff[i]) e = i;
  int t = (b - p.boff[e]) * 256 + threadIdx.x;
  const int K = p.K[e], N = p.N[e];
  if (t >= K * N) return;
  const float* w = p.src[e];
  const int m = p.mode[e];
  if (m == 2) { p.dst[e][t] = (short)f2bu(w[t]); return; }
  if (m == 0) {
    int ks = t >> 13, rem = t & 8191;
    int P = rem >> 3, j = rem & 7;
    int n = P >> 2;
    int kq = ((P & 3) - (n >> 1)) & 3;
    int k = (ks << 5) + (kq << 3) + j;
    p.dst[e][t] = (short)f2bu(w[(size_t)k * 256 + n]);
    return;
  }
  int n = t / K, k = t - n * K;
  p.dst[e][t] = (short)f2bu(w[(size_t)k * N + n]);
}

// ---------------- RC[6][256]: rate contribution of g_u layer 1 (f32) ------
__global__ void k_rc(const float* __restrict__ rate, const float* __restrict__ w1,
                     float* __restrict__ RC) {
  const int j = blockIdx.x;
  const int n = threadIdx.x;
  float s = 0.f;
  const float* rr = rate + j * 256;
  for (int k = 0; k < 256; ++k)
    s += rr[k] * w1[(size_t)(256 + k) * 256 + n];
  RC[j * 256 + n] = s;
}

// ---------------- QC[G][256]: per-group q contribution of attn layer 1 ----
__global__ __launch_bounds__(256, 4) void k_qc(
    const int* __restrict__ qid, const short* __restrict__ itembf,
    const short* __restrict__ aw1, float* __restrict__ QC)
{
  const int tid = threadIdx.x;
  const int lane = tid & 63;
  const int wave = tid >> 6;
  const int m0 = (int)blockIdx.x << 6;
  const int l15 = lane & 15;
  const int lq = lane >> 4;
  const int nb = wave << 6;

  int pBg[4];
  const short* qp[4];
#pragma unroll
  for (int i = 0; i < 4; ++i) {
    int n = nb + i * 16 + l15;
    pBg[i] = (n * 4 + ((lq + (n >> 1)) & 3)) * 8;
    qp[i] = itembf + (size_t)qid[m0 + i * 16 + l15] * 256 + lq * 8;
  }

  const f32x4 fz = {0.f, 0.f, 0.f, 0.f};
  f32x4 acc[4][4];
#pragma unroll
  for (int ni = 0; ni < 4; ++ni)
#pragma unroll
    for (int mi = 0; mi < 4; ++mi) acc[ni][mi] = fz;

  for (int ks = 0; ks < 8; ++ks) {
    short8 wf[4], qf[4];
#pragma unroll
    for (int i = 0; i < 4; ++i) {
      wf[i] = *(const short8*)(aw1 + (8 + ks) * 8192 + pBg[i]);
      qf[i] = *(const short8*)(qp[i] + ks * 32);
    }
#pragma unroll
    for (int ni = 0; ni < 4; ++ni)
#pragma unroll
      for (int mi = 0; mi < 4; ++mi)
        acc[ni][mi] = mfma16(wf[ni], qf[mi], acc[ni][mi]);
  }
#pragma unroll
  for (int ni = 0; ni < 4; ++ni) {
    const int nbase = nb + ni * 16 + lq * 4;
#pragma unroll
    for (int mi = 0; mi < 4; ++mi) {
      const int m = mi * 16 + l15;
      *(f32x4*)(QC + (size_t)(m0 + m) * 256 + nbase) = acc[ni][mi];
    }
  }
}

// ---------------- fused g_u(item-half) + attu(fjt-half) -------------------
// sH: XOR-swizzled unpadded [64][256] -> LDS 40960 B. X written via
// coalesced copy pass from sH.
template <bool IDENT>
__global__ __launch_bounds__(256, 3) void k_fused(
    const int* __restrict__ idx_pairs,
    const short* __restrict__ tab0,
    const float* __restrict__ RC,
    const float* __restrict__ QC,
    const short* __restrict__ ws1, const float* __restrict__ b1,
    const short* __restrict__ ws2, const float* __restrict__ b2,
    const short* __restrict__ aw1, const float* __restrict__ ab1,
    const short* __restrict__ aw2t, const float* __restrict__ ab2,
    short* __restrict__ Xout, short* __restrict__ miu_out)
{
  __shared__ __align__(16) short smem[20480];   // 40960 B total
  short* sA0 = smem;
  short* sA1 = smem + 2048;
  short* sH  = smem + 4096;                     // 16384 shorts, swizzled

  const int tid = threadIdx.x;
  const int lane = tid & 63;
  const int wave = tid >> 6;
  const int m0 = (int)blockIdx.x << 6;
  const int l15 = lane & 15;
  const int lq = lane >> 4;
  const int nb = wave << 6;
  const int swz = (l15 & 7) << 3;               // per-lane sH swizzle

  const int an = tid >> 2;
  const int kqA = ((tid & 3) - (an >> 1)) & 3;
  const int r = m0 + an;
  const int i0 = idx_pairs[2 * r];
  const short* a0 = (IDENT ? (tab0 + (size_t)r * 256) : (tab0 + (size_t)i0 * 256)) + kqA * 8;

  int pBg[4], pA[4];
#pragma unroll
  for (int i = 0; i < 4; ++i) {
    int n = nb + i * 16 + l15;
    pBg[i] = (n * 4 + ((lq + (n >> 1)) & 3)) * 8;
    int m = i * 16 + l15;
    pA[i] = (m * 4 + ((lq + (m >> 1)) & 3)) * 8;
  }
  const int hOff = lq * 8;

  const f32x4 fz = {0.f, 0.f, 0.f, 0.f};
  f32x4 acc[4][4];
#pragma unroll
  for (int ni = 0; ni < 4; ++ni)
#pragma unroll
    for (int mi = 0; mi < 4; ++mi) acc[ni][mi] = fz;

  short8 wfb[3][4];
  short8 ar0, ar1;

  // per-lane row metadata (4 rows per lane: mi*16+l15)
  int i1v[4], mskv[4], grpv[4];
#pragma unroll
  for (int mi = 0; mi < 4; ++mi) {
    const int row = m0 + mi * 16 + l15;
    i1v[mi]  = idx_pairs[2 * row + 1];
    mskv[mi] = idx_pairs[2 * row];
    grpv[mi] = row / 12;
  }

  // ================= g_u layer 1 (K=256 item half, 8 ksteps) =========
  {
    short8 t = *(const short8*)a0;
    *(short8*)(sA0 + tid * 8) = t;
  }
  ar1 = *(const short8*)(a0 + 32);
#pragma unroll
  for (int i = 0; i < 4; ++i) wfb[0][i] = *(const short8*)(ws1 + pBg[i]);
#pragma unroll
  for (int i = 0; i < 4; ++i) wfb[1][i] = *(const short8*)(ws1 + 8192 + pBg[i]);
  __syncthreads();
#pragma unroll
  for (int ks = 0; ks < 8; ++ks) {
    short* sAc = (ks & 1) ? sA1 : sA0;
    short* sAn = (ks & 1) ? sA0 : sA1;
    if (ks < 6) {
      const int c = ks + 2;
      short8 t = *(const short8*)(a0 + c * 32);
      if ((ks & 1) == 0) ar0 = t; else ar1 = t;
      const short* s = ws1 + c * 8192;
#pragma unroll
      for (int i = 0; i < 4; ++i) wfb[c % 3][i] = *(const short8*)(s + pBg[i]);
    }
    short8 xf[4];
#pragma unroll
    for (int i = 0; i < 4; ++i) xf[i] = *(short8*)(sAc + pA[i]);
#pragma unroll
    for (int ni = 0; ni < 4; ++ni)
#pragma unroll
      for (int mi = 0; mi < 4; ++mi)
        acc[ni][mi] = mfma16(wfb[ks % 3][ni], xf[mi], acc[ni][mi]);
    if (ks < 7) {
      short8 w = (((ks + 1) & 1) == 0) ? ar0 : ar1;
      *(short8*)(sAn + tid * 8) = w;
      __syncthreads();
    }
  }
  // hidden = relu(acc + RC[i1] + b1) -> sH (swizzled)
#pragma unroll
  for (int ni = 0; ni < 4; ++ni) {
    const int nbase = nb + ni * 16 + lq * 4;
    float4 bb = *(const float4*)(b1 + nbase);
#pragma unroll
    for (int mi = 0; mi < 4; ++mi) {
      const int m = mi * 16 + l15;
      float4 rc = *(const float4*)(RC + i1v[mi] * 256 + nbase);
      short4v hv;
      hv[0] = (short)f2bu(fmaxf(acc[ni][mi][0] + rc.x + bb.x, 0.f));
      hv[1] = (short)f2bu(fmaxf(acc[ni][mi][1] + rc.y + bb.y, 0.f));
      hv[2] = (short)f2bu(fmaxf(acc[ni][mi][2] + rc.z + bb.z, 0.f));
      hv[3] = (short)f2bu(fmaxf(acc[ni][mi][3] + rc.w + bb.w, 0.f));
      *(short4v*)(sH + m * 256 + (nbase ^ swz)) = hv;
    }
  }
  __syncthreads();   // publish hidden

  // ================= g_u layer 2 (K=256, barrier-free) =================
#pragma unroll
  for (int ni = 0; ni < 4; ++ni)
#pragma unroll
    for (int mi = 0; mi < 4; ++mi) acc[ni][mi] = fz;
#pragma unroll
  for (int i = 0; i < 4; ++i) wfb[0][i] = *(const short8*)(ws2 + pBg[i]);
#pragma unroll
  for (int i = 0; i < 4; ++i) wfb[1][i] = *(const short8*)(ws2 + 8192 + pBg[i]);
#pragma unroll
  for (int ks = 0; ks < 8; ++ks) {
    if (ks < 6) {
      const short* s = ws2 + (ks + 2) * 8192;
#pragma unroll
      for (int i = 0; i < 4; ++i) wfb[(ks + 2) % 3][i] = *(const short8*)(s + pBg[i]);
    }
    short8 hf[4];
#pragma unroll
    for (int i = 0; i < 4; ++i)
      hf[i] = *(short8*)(sH + (i * 16 + l15) * 256 + ((ks * 32 + hOff) ^ swz));
#pragma unroll
    for (int ni = 0; ni < 4; ++ni)
#pragma unroll
      for (int mi = 0; mi < 4; ++mi)
        acc[ni][mi] = mfma16(wfb[ks % 3][ni], hf[mi], acc[ni][mi]);
  }
  __syncthreads();   // all done reading sH(hidden)

  // f_jt = acc + b2 -> sH (swizzled only; X written by copy pass below)
#pragma unroll
  for (int ni = 0; ni < 4; ++ni) {
    const int nbase = nb + ni * 16 + lq * 4;
    float4 bb = *(const float4*)(b2 + nbase);
#pragma unroll
    for (int mi = 0; mi < 4; ++mi) {
      const int m = mi * 16 + l15;
      short4v hv;
      hv[0] = (short)f2bu(acc[ni][mi][0] + bb.x);
      hv[1] = (short)f2bu(acc[ni][mi][1] + bb.y);
      hv[2] = (short)f2bu(acc[ni][mi][2] + bb.z);
      hv[3] = (short)f2bu(acc[ni][mi][3] + bb.w);
      *(short4v*)(sH + m * 256 + (nbase ^ swz)) = hv;
    }
  }
  __syncthreads();   // publish f_jt

  // coalesced X write: 32 lanes cover one 512B row segment contiguously
#pragma unroll
  for (int p = 0; p < 8; ++p) {
    const int rr = (tid >> 5) + p * 8;
    const int c8 = (tid & 31) * 8;
    short8 v = *(short8*)(sH + rr * 256 + (c8 ^ ((rr & 7) << 3)));
    *(short8*)(Xout + (size_t)(m0 + rr) * 256 + c8) = v;
  }

  // ================= attn layer 1 (K=256 f_jt half, barrier-free) ========
#pragma unroll
  for (int ni = 0; ni < 4; ++ni)
#pragma unroll
    for (int mi = 0; mi < 4; ++mi) acc[ni][mi] = fz;
#pragma unroll
  for (int i = 0; i < 4; ++i) wfb[0][i] = *(const short8*)(aw1 + pBg[i]);
#pragma unroll
  for (int i = 0; i < 4; ++i) wfb[1][i] = *(const short8*)(aw1 + 8192 + pBg[i]);
#pragma unroll
  for (int ks = 0; ks < 8; ++ks) {
    if (ks < 6) {
      const short* s = aw1 + (ks + 2) * 8192;
#pragma unroll
      for (int i = 0; i < 4; ++i) wfb[(ks + 2) % 3][i] = *(const short8*)(s + pBg[i]);
    }
    short8 xf[4];
#pragma unroll
    for (int i = 0; i < 4; ++i)
      xf[i] = *(short8*)(sH + (i * 16 + l15) * 256 + ((ks * 32 + hOff) ^ swz));
#pragma unroll
    for (int ni = 0; ni < 4; ++ni)
#pragma unroll
      for (int mi = 0; mi < 4; ++mi)
        acc[ni][mi] = mfma16(wfb[ks % 3][ni], xf[mi], acc[ni][mi]);
  }
  __syncthreads();   // all done reading sH(f_jt)

  // attn hidden = relu(acc + mask*QC[grp] + ab1) -> sH (overwrite)
#pragma unroll
  for (int ni = 0; ni < 4; ++ni) {
    const int nbase = nb + ni * 16 + lq * 4;
    float4 bb = *(const float4*)(ab1 + nbase);
#pragma unroll
    for (int mi = 0; mi < 4; ++mi) {
      const int m = mi * 16 + l15;
      float4 qv;
      if (mskv[mi] > 0) qv = *(const float4*)(QC + (size_t)grpv[mi] * 256 + nbase);
      else { qv.x = 0.f; qv.y = 0.f; qv.z = 0.f; qv.w = 0.f; }
      short4v hv;
      hv[0] = (short)f2bu(fmaxf(acc[ni][mi][0] + qv.x + bb.x, 0.f));
      hv[1] = (short)f2bu(fmaxf(acc[ni][mi][1] + qv.y + bb.y, 0.f));
      hv[2] = (short)f2bu(fmaxf(acc[ni][mi][2] + qv.z + bb.z, 0.f));
      hv[3] = (short)f2bu(fmaxf(acc[ni][mi][3] + qv.w + bb.w, 0.f));
      *(short4v*)(sH + m * 256 + (nbase ^ swz)) = hv;
    }
  }
  __syncthreads();

  // ================= attn layer 2 (256 -> 16), W2 direct ==========
  f32x4 a2 = fz;
#pragma unroll
  for (int ks = 0; ks < 8; ++ks) {
    short8 af = *(short8*)(sH + (wave * 16 + l15) * 256 + ((ks * 32 + hOff) ^ swz));
    short8 bv = *(const short8*)(aw2t + l15 * 256 + ks * 32 + hOff);
    a2 = mfma16(af, bv, a2);
  }
  const float bias = ab2[l15];
#pragma unroll
  for (int j = 0; j < 4; ++j)
    miu_out[(size_t)(m0 + wave * 16 + lq * 4 + j) * 16 + l15] = (short)f2bu(a2[j] + bias);
}

// ---------------- kappa scores (bf16 out) ---------------------------------
__global__ __launch_bounds__(256, 3) void k_attonly(
    const short* __restrict__ first,
    const short* __restrict__ itembf,
    const int* __restrict__ iidx,
    const short* __restrict__ aw1, const float* __restrict__ ab1,
    const short* __restrict__ aw2t, const float* __restrict__ ab2,
    short* __restrict__ out)
{
  __shared__ __align__(16) short sH[16896];

  const int tid = threadIdx.x;
  const int lane = tid & 63;
  const int wave = tid >> 6;
  const int m0 = (int)blockIdx.x << 6;
  const int l15 = lane & 15;
  const int lq = lane >> 4;
  const int nb = wave << 6;
  const int hOff = lq * 8;

  const short* fp[4];
  const short* qp[4];
  int pBg[4];
#pragma unroll
  for (int i = 0; i < 4; ++i) {
    int mrow = m0 + i * 16 + l15;
    fp[i] = first + (size_t)mrow * 256 + hOff;
    qp[i] = itembf + (size_t)iidx[mrow] * 256 + hOff;
    int n = nb + i * 16 + l15;
    pBg[i] = (n * 4 + ((lq + (n >> 1)) & 3)) * 8;
  }

  const f32x4 fz = {0.f, 0.f, 0.f, 0.f};
  f32x4 acc[4][4];
#pragma unroll
  for (int ni = 0; ni < 4; ++ni)
#pragma unroll
    for (int mi = 0; mi < 4; ++mi) acc[ni][mi] = fz;

  short8 wfc[4], wfn[4], xfc[4], xfn[4];
#pragma unroll
  for (int i = 0; i < 4; ++i) {
    wfc[i] = *(const short8*)(aw1 + pBg[i]);
    xfc[i] = *(const short8*)(fp[i]);
  }
  for (int ks = 0; ks < 16; ++ks) {
    if (ks < 15) {
      const int c = ks + 1;
      const short* s = aw1 + c * 8192;
#pragma unroll
      for (int i = 0; i < 4; ++i) {
        wfn[i] = *(const short8*)(s + pBg[i]);
        xfn[i] = *(const short8*)((c < 8) ? (fp[i] + c * 32) : (qp[i] + (c - 8) * 32));
      }
    }
#pragma unroll
    for (int ni = 0; ni < 4; ++ni)
#pragma unroll
      for (int mi = 0; mi < 4; ++mi)
        acc[ni][mi] = mfma16(wfc[ni], xfc[mi], acc[ni][mi]);
    if (ks < 15) {
#pragma unroll
      for (int i = 0; i < 4; ++i) { wfc[i] = wfn[i]; xfc[i] = xfn[i]; }
    }
  }
#pragma unroll
  for (int ni = 0; ni < 4; ++ni) {
    const int nbase = nb + ni * 16 + lq * 4;
    float4 bb = *(const float4*)(ab1 + nbase);
#pragma unroll
    for (int mi = 0; mi < 4; ++mi) {
      const int m = mi * 16 + l15;
      short4v hv;
      hv[0] = (short)f2bu(fmaxf(acc[ni][mi][0] + bb.x, 0.f));
      hv[1] = (short)f2bu(fmaxf(acc[ni][mi][1] + bb.y, 0.f));
      hv[2] = (short)f2bu(fmaxf(acc[ni][mi][2] + bb.z, 0.f));
      hv[3] = (short)f2bu(fmaxf(acc[ni][mi][3] + bb.w, 0.f));
      *(short4v*)(sH + m * 264 + nbase) = hv;
    }
  }
  __syncthreads();
  f32x4 a2 = fz;
#pragma unroll
  for (int ks = 0; ks < 8; ++ks) {
    short8 af = *(short8*)(sH + (wave * 16 + l15) * 264 + ks * 32 + hOff);
    short8 bv = *(const short8*)(aw2t + l15 * 256 + ks * 32 + hOff);
    a2 = mfma16(af, bv, a2);
  }
  const float bias = ab2[l15];
#pragma unroll
  for (int j = 0; j < 4; ++j)
    out[(size_t)(m0 + wave * 16 + lq * 4 + j) * 16 + l15] = (short)f2bu(a2[j] + bias);
}

// ---------------- single-layer GEMM 256->256 + bias + relu (no LDS) -------
__global__ __launch_bounds__(256, 3) void k_gemm1(
    const short* __restrict__ Abf, const short* __restrict__ wt,
    const float* __restrict__ bias, short* __restrict__ out)
{
  const int tid  = threadIdx.x;
  const int lane = tid & 63;
  const int wave = tid >> 6;
  const int m0   = blockIdx.x << 6;
  const int l15  = lane & 15;
  const int lq   = lane >> 4;
  const int rq   = lq << 2;
  const int nb   = wave << 6;
  const int hOff = lq * 8;

  const f32x4 fz = {0.f, 0.f, 0.f, 0.f};
  f32x4 acc[4][4];
#pragma unroll
  for (int mi = 0; mi < 4; ++mi)
#pragma unroll
    for (int ni = 0; ni < 4; ++ni) acc[mi][ni] = fz;

  for (int ks = 0; ks < 8; ++ks) {
    short8 af[4], bv[4];
#pragma unroll
    for (int i = 0; i < 4; ++i) {
      af[i] = *(const short8*)(Abf + (size_t)(m0 + i * 16 + l15) * 256 + ks * 32 + hOff);
      bv[i] = *(const short8*)(wt + (size_t)(nb + i * 16 + l15) * 256 + ks * 32 + hOff);
    }
#pragma unroll
    for (int mi = 0; mi < 4; ++mi)
#pragma unroll
      for (int ni = 0; ni < 4; ++ni)
        acc[mi][ni] = mfma16(af[mi], bv[ni], acc[mi][ni]);
  }

#pragma unroll
  for (int ni = 0; ni < 4; ++ni) {
    const int col = nb + ni * 16 + l15;
    const float b = bias[col];
#pragma unroll
    for (int mi = 0; mi < 4; ++mi)
#pragma unroll
      for (int j = 0; j < 4; ++j) {
        const int row = mi * 16 + rq + j;
        out[(size_t)(m0 + row) * 256 + col] = (short)f2bu(fmaxf(acc[mi][ni][j] + b, 0.f));
      }
  }
}

// ---------------- fused 3-layer comb MLP --------------------------------
__global__ __launch_bounds__(256, 2) void k_comb(
    const short* __restrict__ hju, const short* __restrict__ hjv,
    const short* __restrict__ w1t, const float* __restrict__ b1,
    const short* __restrict__ w2t, const float* __restrict__ b2,
    const short* __restrict__ w3t, const float* __restrict__ b3,
    float* __restrict__ out)
{
  __shared__ __align__(16) short smem[29696];
  short (*A)[40]   = (short(*)[40])smem;
  short (*Bt)[40]  = (short(*)[40])(smem + 2560);
  short (*Hh)[264] = (short(*)[264])(smem + 12800);

  const int tid  = threadIdx.x;
  const int lane = tid & 63;
  const int wave = tid >> 6;
  const int m0   = blockIdx.x << 6;
  const int arow = tid >> 2;
  const int acol8 = (tid & 3) << 3;
  const int lrow = lane & 15;
  const int lk8  = (lane >> 4) << 3;
  const int rq   = (lane >> 4) << 2;
  const int nb   = wave << 6;
  const int r = m0 + arow;

  const f32x4 fz = {0.f, 0.f, 0.f, 0.f};
  f32x4 acc[4][4];
#pragma unroll
  for (int mi = 0; mi < 4; ++mi)
#pragma unroll
    for (int ni = 0; ni < 4; ++ni) acc[mi][ni] = fz;

  for (int ks = 0; ks < 16; ++ks) {
    const int kg = (ks << 5) + acol8;
    short8 av = (kg < 256) ? *(const short8*)(hju + (size_t)r * 256 + kg)
                           : *(const short8*)(hjv + (size_t)r * 256 + (kg - 256));
    *(short8*)&A[arow][acol8] = av;
    const short* wsrc = w1t + tid * 512 + (ks << 5);
    *(short8*)&Bt[tid][0]  = *(const short8*)(wsrc);
    *(short8*)&Bt[tid][8]  = *(const short8*)(wsrc + 8);
    *(short8*)&Bt[tid][16] = *(const short8*)(wsrc + 16);
    *(short8*)&Bt[tid][24] = *(const short8*)(wsrc + 24);
    __syncthreads();
    short8 af[4], bv[4];
#pragma unroll
    for (int mi = 0; mi < 4; ++mi) af[mi] = *(short8*)&A[mi * 16 + lrow][lk8];
#pragma unroll
    for (int ni = 0; ni < 4; ++ni) bv[ni] = *(short8*)&Bt[nb + ni * 16 + lrow][lk8];
#pragma unroll
    for (int mi = 0; mi < 4; ++mi)
#pragma unroll
      for (int ni = 0; ni < 4; ++ni)
        acc[mi][ni] = mfma16(af[mi], bv[ni], acc[mi][ni]);
    __syncthreads();
  }
#pragma unroll
  for (int ni = 0; ni < 4; ++ni) {
    const int col = nb + ni * 16 + lrow;
    const float bias = b1[col];
#pragma unroll
    for (int mi = 0; mi < 4; ++mi)
#pragma unroll
      for (int j = 0; j < 4; ++j)
        Hh[mi * 16 + rq + j][col] = (short)f2bu(fmaxf(acc[mi][ni][j] + bias, 0.f));
  }

#pragma unroll
  for (int mi = 0; mi < 4; ++mi)
#pragma unroll
    for (int ni = 0; ni < 4; ++ni) acc[mi][ni] = fz;
  for (int ks = 0; ks < 8; ++ks) {
    const short* wsrc = w2t + tid * 256 + (ks << 5);
    *(short8*)&Bt[tid][0]  = *(const short8*)(wsrc);
    *(short8*)&Bt[tid][8]  = *(const short8*)(wsrc + 8);
    *(short8*)&Bt[tid][16] = *(const short8*)(wsrc + 16);
    *(short8*)&Bt[tid][24] = *(const short8*)(wsrc + 24);
    __syncthreads();
    short8 af[4], bv[4];
#pragma unroll
    for (int mi = 0; mi < 4; ++mi) af[mi] = *(short8*)&Hh[mi * 16 + lrow][(ks << 5) + lk8];
#pragma unroll
    for (int ni = 0; ni < 4; ++ni) bv[ni] = *(short8*)&Bt[nb + ni * 16 + lrow][lk8];
#pragma unroll
    for (int mi = 0; mi < 4; ++mi)
#pragma unroll
      for (int ni = 0; ni < 4; ++ni)
        acc[mi][ni] = mfma16(af[mi], bv[ni], acc[mi][ni]);
    __syncthreads();
  }
#pragma unroll
  for (int ni = 0; ni < 4; ++ni) {
    const int col = nb + ni * 16 + lrow;
    const float bias = b2[col];
#pragma unroll
    for (int mi = 0; mi < 4; ++mi)
#pragma unroll
      for (int j = 0; j < 4; ++j)
        Hh[mi * 16 + rq + j][col] = (short)f2bu(fmaxf(acc[mi][ni][j] + bias, 0.f));
  }
  __syncthreads();

#pragma unroll
  for (int mi = 0; mi < 4; ++mi)
#pragma unroll
    for (int ni = 0; ni < 4; ++ni) acc[mi][ni] = fz;
  for (int ks = 0; ks < 8; ++ks) {
    const short* wsrc = w3t + tid * 256 + (ks << 5);
    *(short8*)&Bt[tid][0]  = *(const short8*)(wsrc);
    *(short8*)&Bt[tid][8]  = *(const short8*)(wsrc + 8);
    *(short8*)&Bt[tid][16] = *(const short8*)(wsrc + 16);
    *(short8*)&Bt[tid][24] = *(const short8*)(wsrc + 24);
    __syncthreads();
    short8 af[4], bv[4];
#pragma unroll
    for (int mi = 0; mi < 4; ++mi) af[mi] = *(short8*)&Hh[mi * 16 + lrow][(ks << 5) + lk8];
#pragma unroll
    for (int ni = 0; ni < 4; ++ni) bv[ni] = *(short8*)&Bt[nb + ni * 16 + lrow][lk8];
#pragma unroll
    for (int mi = 0; mi < 4; ++mi)
#pragma unroll
      for (int ni = 0; ni < 4; ++ni)
        acc[mi][ni] = mfma16(af[mi], bv[ni], acc[mi][ni]);
    __syncthreads();
  }
#pragma unroll
  for (int ni = 0; ni < 4; ++ni) {
    const int col = nb + ni * 16 + lrow;
    const float bias = b3[col];
#pragma unroll
    for (int mi = 0; mi < 4; ++mi)
#pragma unroll
      for (int j = 0; j < 4; ++j) {
        const int row = mi * 16 + rq + j;
        out[(size_t)(m0 + row) * 256 + col] = fmaxf(acc[mi][ni][j] + bias, 0.f);
      }
  }
}

// ---------------- head MLP1 as MFMA GEMM: [G][192] -> [G][96], relu ------
__global__ __launch_bounds__(256, 4) void k_h1(
    const short* __restrict__ A, const short* __restrict__ w1t,
    const float* __restrict__ b1, short* __restrict__ h1)
{
  const int tid = threadIdx.x;
  const int lane = tid & 63;
  const int wave = tid >> 6;
  const int m0 = (int)blockIdx.x << 6;
  const int l15 = lane & 15;
  const int lq = lane >> 4;
  const int ntc = (wave < 2) ? 2 : 1;
  const int nta = wave;
  const int ntb = wave + 4;

  const f32x4 fz = {0.f, 0.f, 0.f, 0.f};
  f32x4 acc[4][2];
#pragma unroll
  for (int i = 0; i < 4; ++i) { acc[i][0] = fz; acc[i][1] = fz; }

  for (int ks = 0; ks < 6; ++ks) {
    short8 af[4], bv[2];
#pragma unroll
    for (int i = 0; i < 4; ++i)
      af[i] = *(const short8*)(A + (size_t)(m0 + i * 16 + l15) * 192 + ks * 32 + lq * 8);
    bv[0] = *(const short8*)(w1t + (nta * 16 + l15) * 192 + ks * 32 + lq * 8);
    if (ntc == 2)
      bv[1] = *(const short8*)(w1t + (ntb * 16 + l15) * 192 + ks * 32 + lq * 8);
#pragma unroll
    for (int j = 0; j < 2; ++j)
      if (j < ntc)
#pragma unroll
        for (int i = 0; i < 4; ++i)
          acc[i][j] = mfma16(bv[j], af[i], acc[i][j]);
  }
#pragma unroll
  for (int j = 0; j < 2; ++j) {
    if (j >= ntc) continue;
    const int nbase = (j == 0 ? nta : ntb) * 16 + lq * 4;
    float4 bb = *(const float4*)(b1 + nbase);
#pragma unroll
    for (int i = 0; i < 4; ++i) {
      const int row = m0 + i * 16 + l15;
      short4v hv;
      hv[0] = (short)f2bu(fmaxf(acc[i][j][0] + bb.x, 0.f));
      hv[1] = (short)f2bu(fmaxf(acc[i][j][1] + bb.y, 0.f));
      hv[2] = (short)f2bu(fmaxf(acc[i][j][2] + bb.z, 0.f));
      hv[3] = (short)f2bu(fmaxf(acc[i][j][3] + bb.w, 0.f));
      *(short4v*)(h1 + (size_t)row * 96 + nbase) = hv;
    }
  }
}

// ---------------- head MLP2 + masked softmax -> weights [G][12] f32 -------
__global__ __launch_bounds__(256) void k_h2(
    const short* __restrict__ h1, const short* __restrict__ w2t,
    const float* __restrict__ b2,
    const int* __restrict__ mask_src, const int mstride,
    float* __restrict__ W)
{
  __shared__ float wgt[16][12];
  const int tid = threadIdx.x;
  const int gg = tid >> 4, sl = tid & 15;
  const int g = blockIdx.x * 16 + gg;
  if (sl < 12) {
    float s = b2[sl];
    const short* hr = h1 + (size_t)g * 96;
    const short* wr = w2t + sl * 96;
#pragma unroll
    for (int kk = 0; kk < 12; ++kk) {
      short8 hv = *(const short8*)(hr + kk * 8);
      short8 wv = *(const short8*)(wr + kk * 8);
#pragma unroll
      for (int j = 0; j < 8; ++j)
        s += b2f((unsigned short)hv[j]) * b2f((unsigned short)wv[j]);
    }
    const int mi = mask_src[(g * 12 + sl) * mstride];
    wgt[gg][sl] = (mi > 0) ? expf(s) : 0.f;
  }
  __syncthreads();
  if (sl < 12) {
    float tot = 1e-10f;
#pragma unroll
    for (int m = 0; m < 12; ++m) tot += wgt[gg][m];
    W[(size_t)g * 12 + sl] = wgt[gg][sl] / tot;
  }
}

// ---------------- weighted sum: out[g] = sum_m W[g][m] * X[g*12+m] --------
__global__ __launch_bounds__(256) void k_wsum(
    const float* __restrict__ W, const short* __restrict__ X,
    short* __restrict__ out)
{
  const int tid = threadIdx.x;
  const int g = blockIdx.x * 8 + (tid >> 5);
  const int d0 = (tid & 31) * 8;
  const float* wg = W + (size_t)g * 12;
  float w[12];
#pragma unroll
  for (int m = 0; m < 12; ++m) w[m] = wg[m];
  const short* xp = X + (size_t)g * 12 * 256 + d0;
  float o[8];
#pragma unroll
  for (int j = 0; j < 8; ++j) o[j] = 0.f;
#pragma unroll
  for (int m = 0; m < 12; ++m) {
    short8 x = *(const short8*)(xp + m * 256);
#pragma unroll
    for (int j = 0; j < 8; ++j) o[j] += w[m] * b2f((unsigned short)x[j]);
  }
  short8 v;
#pragma unroll
  for (int j = 0; j < 8; ++j) v[j] = (short)f2bu(o[j]);
  *(short8*)(out + (size_t)g * 256 + d0) = v;
}

// =====================================================================
extern "C" void kernel_launch(void* const* d_in, const int* in_sizes, int n_in,
                              void* d_out, int out_size, void* d_ws, size_t ws_size,
                              hipStream_t stream)
{
  (void)in_sizes; (void)n_in; (void)out_size; (void)ws_size;

  const int*   iids = (const int*)d_in[0];
  const int*   iup  = (const int*)d_in[1];
  const int*   iip  = (const int*)d_in[2];
  const int*   iiup = (const int*)d_in[3];
  const float* user_table = (const float*)d_in[4];
  const float* item_table = (const float*)d_in[5];
  const float* rate_table = (const float*)d_in[6];
  const float* g_u_w1 = (const float*)d_in[7];   const float* g_u_b1 = (const float*)d_in[8];
  const float* g_u_w2 = (const float*)d_in[9];   const float* g_u_b2 = (const float*)d_in[10];
  const float* attu_w1 = (const float*)d_in[11]; const float* attu_b1 = (const float*)d_in[12];
  const float* attu_w2 = (const float*)d_in[13]; const float* attu_b2 = (const float*)d_in[14];
  const float* headu_w1 = (const float*)d_in[15]; const float* headu_b1 = (const float*)d_in[16];
  const float* headu_w2 = (const float*)d_in[17]; const float* headu_b2 = (const float*)d_in[18];
  const float* aggi_w = (const float*)d_in[19];  const float* aggi_b = (const float*)d_in[20];
  const float* attii_w1 = (const float*)d_in[21]; const float* attii_b1 = (const float*)d_in[22];
  const float* attii_w2 = (const float*)d_in[23]; const float* attii_b2 = (const float*)d_in[24];
  const float* headii_w1 = (const float*)d_in[25]; const float* headii_b1 = (const float*)d_in[26];
  const float* headii_w2 = (const float*)d_in[27]; const float* headii_b2 = (const float*)d_in[28];
  const float* aggii_w = (const float*)d_in[29]; const float* aggii_b = (const float*)d_in[30];
  const float* comb_w1 = (const float*)d_in[31]; const float* comb_b1 = (const float*)d_in[32];
  const float* comb_w2 = (const float*)d_in[33]; const float* comb_b2 = (const float*)d_in[34];
  const float* comb_w3 = (const float*)d_in[35]; const float* comb_b3 = (const float*)d_in[36];

  const int NIe = 100000 * 256;
  const int M2 = 2048 * 12 * 12;
  const int M1 = 2048 * 12;
  const int G2 = M1;
  const int G1 = 2048;

  char* wsp = (char*)d_ws;
  size_t off = 0;
  auto alloc = [&](size_t bytes) -> void* {
    void* p = wsp + off;
    off += (bytes + 255) & ~(size_t)255;
    return p;
  };
  short* item_bf = (short*)alloc((size_t)NIe * 2);
  short* urows   = (short*)alloc((size_t)M1 * 256 * 2);
  short* sl_gu1   = (short*)alloc((size_t)512 * 256 * 2);
  short* sl_gu2   = (short*)alloc((size_t)256 * 256 * 2);
  short* sl_attu1 = (short*)alloc((size_t)512 * 256 * 2);
  short* sl_attii1= (short*)alloc((size_t)512 * 256 * 2);
  short* wt_attu2 = (short*)alloc((size_t)256 * 16 * 2);
  short* wt_attii2= (short*)alloc((size_t)256 * 16 * 2);
  short* wt_aggi   = (short*)alloc((size_t)256 * 256 * 2);
  short* wt_aggii  = (short*)alloc((size_t)256 * 256 * 2);
  short* wt_comb1  = (short*)alloc((size_t)512 * 256 * 2);
  short* wt_comb2  = (short*)alloc((size_t)256 * 256 * 2);
  short* wt_comb3  = (short*)alloc((size_t)256 * 256 * 2);
  short* hu1t  = (short*)alloc((size_t)96 * 192 * 2);
  short* hu2t  = (short*)alloc((size_t)12 * 96 * 2);
  short* hii1t = (short*)alloc((size_t)96 * 192 * 2);
  short* hii2t = (short*)alloc((size_t)12 * 96 * 2);
  float* RC    = (float*)alloc((size_t)6 * 256 * 4);
  float* QC2   = (float*)alloc((size_t)G2 * 256 * 4);
  float* QC1   = (float*)alloc((size_t)G1 * 256 * 4);

  short* X      = (short*)alloc((size_t)M2 * 256 * 2);
  short* FJT    = (short*)alloc((size_t)M1 * 256 * 2);
  short* MIU2   = (short*)alloc((size_t)M2 * 16 * 2);
  short* MIU1   = (short*)alloc((size_t)M1 * 16 * 2);
  short* KAP    = (short*)alloc((size_t)M1 * 16 * 2);
  short* H1A    = (short*)alloc((size_t)G2 * 96 * 2);
  short* H1K    = (short*)alloc((size_t)G1 * 96 * 2);
  short* H1M    = (short*)alloc((size_t)G1 * 96 * 2);
  float* WA     = (float*)alloc((size_t)G2 * 12 * 4);
  float* WK     = (float*)alloc((size_t)G1 * 12 * 4);
  float* WM     = (float*)alloc((size_t)G1 * 12 * 4);
  short* HPRE2  = (short*)alloc((size_t)M1 * 256 * 2);
  short* HOU    = (short*)alloc((size_t)M1 * 256 * 2);
  short* HPREJV = (short*)alloc((size_t)2048 * 256 * 2);
  short* HPRE1  = (short*)alloc((size_t)2048 * 256 * 2);
  short* HJU    = (short*)alloc((size_t)2048 * 256 * 2);
  short* HJV    = (short*)alloc((size_t)2048 * 256 * 2);

  k_cvt<<<NIe / 8 / 256, 256, 0, stream>>>(item_table, item_bf, NIe);
  k_cvt_rows<<<(M1 * 32) / 256, 256, 0, stream>>>(user_table, iup, urows, M1);
  k_rc<<<6, 256, 0, stream>>>(rate_table, g_u_w1, RC);

  Prep pp;
  int nbk = 0, ei = 0;
  auto addw = [&](const float* s, short* d, int K, int N, int mode) {
    pp.src[ei] = s; pp.dst[ei] = d; pp.K[ei] = K; pp.N[ei] = N; pp.mode[ei] = mode;
    pp.boff[ei] = nbk; nbk += (K * N + 255) / 256; ++ei;
  };
  addw(g_u_w1,   sl_gu1,    512, 256, 0);
  addw(g_u_w2,   sl_gu2,    256, 256, 0);
  addw(attu_w1,  sl_attu1,  512, 256, 0);
  addw(attii_w1, sl_attii1, 512, 256, 0);
  addw(attu_w2,  wt_attu2,  256, 16, 1);
  addw(attii_w2, wt_attii2, 256, 16, 1);
  addw(aggi_w,   wt_aggi,   256, 256, 1);
  addw(aggii_w,  wt_aggii,  256, 256, 1);
  addw(comb_w1,  wt_comb1,  512, 256, 1);
  addw(comb_w2,  wt_comb2,  256, 256, 1);
  addw(comb_w3,  wt_comb3,  256, 256, 1);
  addw(headu_w1,  hu1t,  192, 96, 1);
  addw(headu_w2,  hu2t,  96, 12, 1);
  addw(headii_w1, hii1t, 192, 96, 1);
  addw(headii_w2, hii2t, 96, 12, 1);
  pp.boff[15] = nbk;
  pp.boff[16] = nbk;
  k_prep<<<nbk, 256, 0, stream>>>(pp);

  // per-group attn q contributions
  k_qc<<<G2 / 64, 256, 0, stream>>>(iip, item_bf, sl_attu1, QC2);
  k_qc<<<G1 / 64, 256, 0, stream>>>(iids, item_bf, sl_attu1, QC1);

  // fused g_u + attu
  k_fused<false><<<M2 / 64, 256, 0, stream>>>(iiup, item_bf, RC, QC2,
                                              sl_gu1, g_u_b1, sl_gu2, g_u_b2,
                                              sl_attu1, attu_b1, wt_attu2, attu_b2,
                                              X, MIU2);
  k_fused<true><<<M1 / 64, 256, 0, stream>>>(iup, urows, RC, QC1,
                                             sl_gu1, g_u_b1, sl_gu2, g_u_b2,
                                             sl_attu1, attu_b1, wt_attu2, attu_b2,
                                             FJT, MIU1);

  // head chain (part-2 inner): MIU2 -> W -> HPRE2
  k_h1<<<G2 / 64, 256, 0, stream>>>(MIU2, hu1t, headu_b1, H1A);
  k_h2<<<G2 / 16, 256, 0, stream>>>(H1A, hu2t, headu_b2, iiup, 2, WA);
  k_wsum<<<G2 / 8, 256, 0, stream>>>(WA, X, HPRE2);

  k_gemm1<<<M1 / 64, 256, 0, stream>>>(HPRE2, wt_aggi, aggi_b, HOU);
  k_attonly<<<M1 / 64, 256, 0, stream>>>(HOU, item_bf, iip,
                                         sl_attii1, attii_b1, wt_attii2, attii_b2, KAP);

  // kappa head chain: KAP -> WK -> HPREJV
  k_h1<<<G1 / 64, 256, 0, stream>>>(KAP, hii1t, headii_b1, H1K);
  k_h2<<<G1 / 16, 256, 0, stream>>>(H1K, hii2t, headii_b2, iip, 1, WK);
  k_wsum<<<G1 / 8, 256, 0, stream>>>(WK, HOU, HPREJV);

  // part-1 head chain: MIU1 -> WM -> HPRE1
  k_h1<<<G1 / 64, 256, 0, stream>>>(MIU1, hu1t, headu_b1, H1M);
  k_h2<<<G1 / 16, 256, 0, stream>>>(H1M, hu2t, headu_b2, iup, 2, WM);
  k_wsum<<<G1 / 8, 256, 0, stream>>>(WM, FJT, HPRE1);

  k_gemm1<<<2048 / 64, 256, 0, stream>>>(HPRE1, wt_aggi, aggi_b, HJU);
  k_gemm1<<<2048 / 64, 256, 0, stream>>>(HPREJV, wt_aggii, aggii_b, HJV);
  k_comb<<<2048 / 64, 256, 0, stream>>>(HJU, HJV, wt_comb1, comb_b1,
                                        wt_comb2, comb_b2, wt_comb3, comb_b3,
                                        (float*)d_out);
}

// Round 16
// 425.433 us; speedup vs baseline: 1.2344x; 1.1388x over previous
//
#include <hip/hip_runtime.h>
#include <cstdint>
#include <cstddef>

typedef short short8 __attribute__((ext_vector_type(8)));
typedef short short4v __attribute__((ext_vector_type(4)));
typedef float f32x4 __attribute__((ext_vector_type(4)));
typedef __bf16 bf16x8 __attribute__((ext_vector_type(8)));

__device__ __forceinline__ unsigned short f2bu(float f) {
  return __builtin_bit_cast(unsigned short, (__bf16)f);
}
__device__ __forceinline__ float b2f(unsigned short h) {
  union { unsigned u; float f; } v; v.u = ((unsigned)h) << 16;
  return v.f;
}

__device__ __forceinline__ f32x4 mfma16(short8 a, short8 b, f32x4 c) {
  return __builtin_amdgcn_mfma_f32_16x16x32_bf16(
      __builtin_bit_cast(bf16x8, a), __builtin_bit_cast(bf16x8, b), c, 0, 0, 0);
}

// ---------------- f32 -> bf16 table convert (8/thread) ----------------
__global__ void k_cvt(const float* __restrict__ in, short* __restrict__ o, int ntot) {
  int i = (blockIdx.x * 256 + threadIdx.x) * 8;
  if (i >= ntot) return;
  float4 a = *(const float4*)(in + i);
  float4 b = *(const float4*)(in + i + 4);
  short8 v;
  v[0] = (short)f2bu(a.x); v[1] = (short)f2bu(a.y);
  v[2] = (short)f2bu(a.z); v[3] = (short)f2bu(a.w);
  v[4] = (short)f2bu(b.x); v[5] = (short)f2bu(b.y);
  v[6] = (short)f2bu(b.z); v[7] = (short)f2bu(b.w);
  *(short8*)(o + i) = v;
}

// ---------------- gather + convert referenced rows ------------------------
__global__ void k_cvt_rows(const float* __restrict__ tab, const int* __restrict__ pairs,
                           short* __restrict__ o, int nrows) {
  int t = blockIdx.x * 256 + threadIdx.x;
  if (t >= nrows * 32) return;
  int row = t >> 5;
  int c8 = (t & 31) << 3;
  int id = pairs[2 * row];
  const float* s = tab + (size_t)id * 256 + c8;
  float4 a = *(const float4*)(s);
  float4 b = *(const float4*)(s + 4);
  short8 v;
  v[0] = (short)f2bu(a.x); v[1] = (short)f2bu(a.y);
  v[2] = (short)f2bu(a.z); v[3] = (short)f2bu(a.w);
  v[4] = (short)f2bu(b.x); v[5] = (short)f2bu(b.y);
  v[6] = (short)f2bu(b.z); v[7] = (short)f2bu(b.w);
  *(short8*)(o + (size_t)row * 256 + c8) = v;
}

// ---------------- merged weight prep ------------------------------------
struct Prep {
  const float* src[16];
  short* dst[16];
  int K[16], N[16], mode[16];
  int boff[17];
};
__global__ void k_prep(Prep p) {
  int b = blockIdx.x, e = 0;
#pragma unroll
  for (int i = 1; i < 16; ++i) if (b >= p.boff[i]) e = i;
  int t = (b - p.boff[e]) * 256 + threadIdx.x;
  const int K = p.K[e], N = p.N[e];
  if (t >= K * N) return;
  const float* w = p.src[e];
  const int m = p.mode[e];
  if (m == 2) { p.dst[e][t] = (short)f2bu(w[t]); return; }
  if (m == 0) {
    int ks = t >> 13, rem = t & 8191;
    int P = rem >> 3, j = rem & 7;
    int n = P >> 2;
    int kq = ((P & 3) - (n >> 1)) & 3;
    int k = (ks << 5) + (kq << 3) + j;
    p.dst[e][t] = (short)f2bu(w[(size_t)k * 256 + n]);
    return;
  }
  int n = t / K, k = t - n * K;
  p.dst[e][t] = (short)f2bu(w[(size_t)k * N + n]);
}

// ---------------- RC[6][256] --------------------------------------------
__global__ void k_rc(const float* __restrict__ rate, const float* __restrict__ w1,
                     float* __restrict__ RC) {
  const int j = blockIdx.x;
  const int n = threadIdx.x;
  float s = 0.f;
  const float* rr = rate + j * 256;
  for (int k = 0; k < 256; ++k)
    s += rr[k] * w1[(size_t)(256 + k) * 256 + n];
  RC[j * 256 + n] = s;
}

// ---------------- QC (merged A/B sets) ------------------------------------
__global__ __launch_bounds__(256, 4) void k_qc(
    int nbA,
    const int* __restrict__ qidA, float* __restrict__ QCA,
    const int* __restrict__ qidB, float* __restrict__ QCB,
    const short* __restrict__ itembf, const short* __restrict__ aw1)
{
  int bid = blockIdx.x;
  const int* qid; float* QC;
  if (bid < nbA) { qid = qidA; QC = QCA; }
  else { bid -= nbA; qid = qidB; QC = QCB; }

  const int tid = threadIdx.x;
  const int lane = tid & 63;
  const int wave = tid >> 6;
  const int m0 = bid << 6;
  const int l15 = lane & 15;
  const int lq = lane >> 4;
  const int nb = wave << 6;

  int pBg[4];
  const short* qp[4];
#pragma unroll
  for (int i = 0; i < 4; ++i) {
    int n = nb + i * 16 + l15;
    pBg[i] = (n * 4 + ((lq + (n >> 1)) & 3)) * 8;
    qp[i] = itembf + (size_t)qid[m0 + i * 16 + l15] * 256 + lq * 8;
  }

  const f32x4 fz = {0.f, 0.f, 0.f, 0.f};
  f32x4 acc[4][4];
#pragma unroll
  for (int ni = 0; ni < 4; ++ni)
#pragma unroll
    for (int mi = 0; mi < 4; ++mi) acc[ni][mi] = fz;

  for (int ks = 0; ks < 8; ++ks) {
    short8 wf[4], qf[4];
#pragma unroll
    for (int i = 0; i < 4; ++i) {
      wf[i] = *(const short8*)(aw1 + (8 + ks) * 8192 + pBg[i]);
      qf[i] = *(const short8*)(qp[i] + ks * 32);
    }
#pragma unroll
    for (int ni = 0; ni < 4; ++ni)
#pragma unroll
      for (int mi = 0; mi < 4; ++mi)
        acc[ni][mi] = mfma16(wf[ni], qf[mi], acc[ni][mi]);
  }
#pragma unroll
  for (int ni = 0; ni < 4; ++ni) {
    const int nbase = nb + ni * 16 + lq * 4;
#pragma unroll
    for (int mi = 0; mi < 4; ++mi) {
      const int m = mi * 16 + l15;
      *(f32x4*)(QC + (size_t)(m0 + m) * 256 + nbase) = acc[ni][mi];
    }
  }
}

// ---------------- fused g_u + attu (merged M2/M1 sets) --------------------
__global__ __launch_bounds__(256, 3) void k_fused(
    int nbA,
    const int* __restrict__ idxA, const short* __restrict__ tabA,
    const float* __restrict__ QCa, short* __restrict__ Xa, short* __restrict__ miuA,
    const int* __restrict__ idxB, const short* __restrict__ tabB,
    const float* __restrict__ QCb, short* __restrict__ Xb, short* __restrict__ miuB,
    const float* __restrict__ RC,
    const short* __restrict__ ws1, const float* __restrict__ b1,
    const short* __restrict__ ws2, const float* __restrict__ b2,
    const short* __restrict__ aw1, const float* __restrict__ ab1,
    const short* __restrict__ aw2t, const float* __restrict__ ab2)
{
  __shared__ __align__(16) short smem[20480];
  short* sA0 = smem;
  short* sA1 = smem + 2048;
  short* sH  = smem + 4096;

  int bid = blockIdx.x;
  const int* idx_pairs; const short* tab0; const float* QC;
  short* Xout; short* miu_out; bool ident;
  if (bid < nbA) {
    idx_pairs = idxA; tab0 = tabA; QC = QCa; Xout = Xa; miu_out = miuA; ident = false;
  } else {
    bid -= nbA;
    idx_pairs = idxB; tab0 = tabB; QC = QCb; Xout = Xb; miu_out = miuB; ident = true;
  }

  const int tid = threadIdx.x;
  const int lane = tid & 63;
  const int wave = tid >> 6;
  const int m0 = bid << 6;
  const int l15 = lane & 15;
  const int lq = lane >> 4;
  const int nb = wave << 6;
  const int swz = (l15 & 7) << 3;

  const int an = tid >> 2;
  const int kqA = ((tid & 3) - (an >> 1)) & 3;
  const int r = m0 + an;
  const int i0 = idx_pairs[2 * r];
  const short* a0 = (ident ? (tab0 + (size_t)r * 256) : (tab0 + (size_t)i0 * 256)) + kqA * 8;

  int pBg[4], pA[4];
#pragma unroll
  for (int i = 0; i < 4; ++i) {
    int n = nb + i * 16 + l15;
    pBg[i] = (n * 4 + ((lq + (n >> 1)) & 3)) * 8;
    int m = i * 16 + l15;
    pA[i] = (m * 4 + ((lq + (m >> 1)) & 3)) * 8;
  }
  const int hOff = lq * 8;

  const f32x4 fz = {0.f, 0.f, 0.f, 0.f};
  f32x4 acc[4][4];
#pragma unroll
  for (int ni = 0; ni < 4; ++ni)
#pragma unroll
    for (int mi = 0; mi < 4; ++mi) acc[ni][mi] = fz;

  short8 wfb[3][4];
  short8 ar0, ar1;

  int i1v[4], mskv[4], grpv[4];
#pragma unroll
  for (int mi = 0; mi < 4; ++mi) {
    const int row = m0 + mi * 16 + l15;
    i1v[mi]  = idx_pairs[2 * row + 1];
    mskv[mi] = idx_pairs[2 * row];
    grpv[mi] = row / 12;
  }

  // ================= g_u layer 1 =================
  {
    short8 t = *(const short8*)a0;
    *(short8*)(sA0 + tid * 8) = t;
  }
  ar1 = *(const short8*)(a0 + 32);
#pragma unroll
  for (int i = 0; i < 4; ++i) wfb[0][i] = *(const short8*)(ws1 + pBg[i]);
#pragma unroll
  for (int i = 0; i < 4; ++i) wfb[1][i] = *(const short8*)(ws1 + 8192 + pBg[i]);
  __syncthreads();
#pragma unroll
  for (int ks = 0; ks < 8; ++ks) {
    short* sAc = (ks & 1) ? sA1 : sA0;
    short* sAn = (ks & 1) ? sA0 : sA1;
    if (ks < 6) {
      const int c = ks + 2;
      short8 t = *(const short8*)(a0 + c * 32);
      if ((ks & 1) == 0) ar0 = t; else ar1 = t;
      const short* s = ws1 + c * 8192;
#pragma unroll
      for (int i = 0; i < 4; ++i) wfb[c % 3][i] = *(const short8*)(s + pBg[i]);
    }
    short8 xf[4];
#pragma unroll
    for (int i = 0; i < 4; ++i) xf[i] = *(short8*)(sAc + pA[i]);
#pragma unroll
    for (int ni = 0; ni < 4; ++ni)
#pragma unroll
      for (int mi = 0; mi < 4; ++mi)
        acc[ni][mi] = mfma16(wfb[ks % 3][ni], xf[mi], acc[ni][mi]);
    if (ks < 7) {
      short8 w = (((ks + 1) & 1) == 0) ? ar0 : ar1;
      *(short8*)(sAn + tid * 8) = w;
      __syncthreads();
    }
  }
#pragma unroll
  for (int ni = 0; ni < 4; ++ni) {
    const int nbase = nb + ni * 16 + lq * 4;
    float4 bb = *(const float4*)(b1 + nbase);
#pragma unroll
    for (int mi = 0; mi < 4; ++mi) {
      const int m = mi * 16 + l15;
      float4 rc = *(const float4*)(RC + i1v[mi] * 256 + nbase);
      short4v hv;
      hv[0] = (short)f2bu(fmaxf(acc[ni][mi][0] + rc.x + bb.x, 0.f));
      hv[1] = (short)f2bu(fmaxf(acc[ni][mi][1] + rc.y + bb.y, 0.f));
      hv[2] = (short)f2bu(fmaxf(acc[ni][mi][2] + rc.z + bb.z, 0.f));
      hv[3] = (short)f2bu(fmaxf(acc[ni][mi][3] + rc.w + bb.w, 0.f));
      *(short4v*)(sH + m * 256 + (nbase ^ swz)) = hv;
    }
  }
  __syncthreads();

  // ================= g_u layer 2 =================
#pragma unroll
  for (int ni = 0; ni < 4; ++ni)
#pragma unroll
    for (int mi = 0; mi < 4; ++mi) acc[ni][mi] = fz;
#pragma unroll
  for (int i = 0; i < 4; ++i) wfb[0][i] = *(const short8*)(ws2 + pBg[i]);
#pragma unroll
  for (int i = 0; i < 4; ++i) wfb[1][i] = *(const short8*)(ws2 + 8192 + pBg[i]);
#pragma unroll
  for (int ks = 0; ks < 8; ++ks) {
    if (ks < 6) {
      const short* s = ws2 + (ks + 2) * 8192;
#pragma unroll
      for (int i = 0; i < 4; ++i) wfb[(ks + 2) % 3][i] = *(const short8*)(s + pBg[i]);
    }
    short8 hf[4];
#pragma unroll
    for (int i = 0; i < 4; ++i)
      hf[i] = *(short8*)(sH + (i * 16 + l15) * 256 + ((ks * 32 + hOff) ^ swz));
#pragma unroll
    for (int ni = 0; ni < 4; ++ni)
#pragma unroll
      for (int mi = 0; mi < 4; ++mi)
        acc[ni][mi] = mfma16(wfb[ks % 3][ni], hf[mi], acc[ni][mi]);
  }
  __syncthreads();

  // f_jt -> sH
#pragma unroll
  for (int ni = 0; ni < 4; ++ni) {
    const int nbase = nb + ni * 16 + lq * 4;
    float4 bb = *(const float4*)(b2 + nbase);
#pragma unroll
    for (int mi = 0; mi < 4; ++mi) {
      const int m = mi * 16 + l15;
      short4v hv;
      hv[0] = (short)f2bu(acc[ni][mi][0] + bb.x);
      hv[1] = (short)f2bu(acc[ni][mi][1] + bb.y);
      hv[2] = (short)f2bu(acc[ni][mi][2] + bb.z);
      hv[3] = (short)f2bu(acc[ni][mi][3] + bb.w);
      *(short4v*)(sH + m * 256 + (nbase ^ swz)) = hv;
    }
  }
  __syncthreads();

  // coalesced X write
#pragma unroll
  for (int p = 0; p < 8; ++p) {
    const int rr = (tid >> 5) + p * 8;
    const int c8 = (tid & 31) * 8;
    short8 v = *(short8*)(sH + rr * 256 + (c8 ^ ((rr & 7) << 3)));
    *(short8*)(Xout + (size_t)(m0 + rr) * 256 + c8) = v;
  }

  // ================= attn layer 1 =================
#pragma unroll
  for (int ni = 0; ni < 4; ++ni)
#pragma unroll
    for (int mi = 0; mi < 4; ++mi) acc[ni][mi] = fz;
#pragma unroll
  for (int i = 0; i < 4; ++i) wfb[0][i] = *(const short8*)(aw1 + pBg[i]);
#pragma unroll
  for (int i = 0; i < 4; ++i) wfb[1][i] = *(const short8*)(aw1 + 8192 + pBg[i]);
#pragma unroll
  for (int ks = 0; ks < 8; ++ks) {
    if (ks < 6) {
      const short* s = aw1 + (ks + 2) * 8192;
#pragma unroll
      for (int i = 0; i < 4; ++i) wfb[(ks + 2) % 3][i] = *(const short8*)(s + pBg[i]);
    }
    short8 xf[4];
#pragma unroll
    for (int i = 0; i < 4; ++i)
      xf[i] = *(short8*)(sH + (i * 16 + l15) * 256 + ((ks * 32 + hOff) ^ swz));
#pragma unroll
    for (int ni = 0; ni < 4; ++ni)
#pragma unroll
      for (int mi = 0; mi < 4; ++mi)
        acc[ni][mi] = mfma16(wfb[ks % 3][ni], xf[mi], acc[ni][mi]);
  }
  __syncthreads();

  // attn hidden -> sH
#pragma unroll
  for (int ni = 0; ni < 4; ++ni) {
    const int nbase = nb + ni * 16 + lq * 4;
    float4 bb = *(const float4*)(ab1 + nbase);
#pragma unroll
    for (int mi = 0; mi < 4; ++mi) {
      const int m = mi * 16 + l15;
      float4 qv;
      if (mskv[mi] > 0) qv = *(const float4*)(QC + (size_t)grpv[mi] * 256 + nbase);
      else { qv.x = 0.f; qv.y = 0.f; qv.z = 0.f; qv.w = 0.f; }
      short4v hv;
      hv[0] = (short)f2bu(fmaxf(acc[ni][mi][0] + qv.x + bb.x, 0.f));
      hv[1] = (short)f2bu(fmaxf(acc[ni][mi][1] + qv.y + bb.y, 0.f));
      hv[2] = (short)f2bu(fmaxf(acc[ni][mi][2] + qv.z + bb.z, 0.f));
      hv[3] = (short)f2bu(fmaxf(acc[ni][mi][3] + qv.w + bb.w, 0.f));
      *(short4v*)(sH + m * 256 + (nbase ^ swz)) = hv;
    }
  }
  __syncthreads();

  // ================= attn layer 2 =================
  f32x4 a2 = fz;
#pragma unroll
  for (int ks = 0; ks < 8; ++ks) {
    short8 af = *(short8*)(sH + (wave * 16 + l15) * 256 + ((ks * 32 + hOff) ^ swz));
    short8 bv = *(const short8*)(aw2t + l15 * 256 + ks * 32 + hOff);
    a2 = mfma16(af, bv, a2);
  }
  const float bias = ab2[l15];
#pragma unroll
  for (int j = 0; j < 4; ++j)
    miu_out[(size_t)(m0 + wave * 16 + lq * 4 + j) * 16 + l15] = (short)f2bu(a2[j] + bias);
}

// ---------------- kappa scores (bf16 out) ---------------------------------
__global__ __launch_bounds__(256, 3) void k_attonly(
    const short* __restrict__ first,
    const short* __restrict__ itembf,
    const int* __restrict__ iidx,
    const short* __restrict__ aw1, const float* __restrict__ ab1,
    const short* __restrict__ aw2t, const float* __restrict__ ab2,
    short* __restrict__ out)
{
  __shared__ __align__(16) short sH[16896];

  const int tid = threadIdx.x;
  const int lane = tid & 63;
  const int wave = tid >> 6;
  const int m0 = (int)blockIdx.x << 6;
  const int l15 = lane & 15;
  const int lq = lane >> 4;
  const int nb = wave << 6;
  const int hOff = lq * 8;

  const short* fp[4];
  const short* qp[4];
  int pBg[4];
#pragma unroll
  for (int i = 0; i < 4; ++i) {
    int mrow = m0 + i * 16 + l15;
    fp[i] = first + (size_t)mrow * 256 + hOff;
    qp[i] = itembf + (size_t)iidx[mrow] * 256 + hOff;
    int n = nb + i * 16 + l15;
    pBg[i] = (n * 4 + ((lq + (n >> 1)) & 3)) * 8;
  }

  const f32x4 fz = {0.f, 0.f, 0.f, 0.f};
  f32x4 acc[4][4];
#pragma unroll
  for (int ni = 0; ni < 4; ++ni)
#pragma unroll
    for (int mi = 0; mi < 4; ++mi) acc[ni][mi] = fz;

  short8 wfc[4], wfn[4], xfc[4], xfn[4];
#pragma unroll
  for (int i = 0; i < 4; ++i) {
    wfc[i] = *(const short8*)(aw1 + pBg[i]);
    xfc[i] = *(const short8*)(fp[i]);
  }
  for (int ks = 0; ks < 16; ++ks) {
    if (ks < 15) {
      const int c = ks + 1;
      const short* s = aw1 + c * 8192;
#pragma unroll
      for (int i = 0; i < 4; ++i) {
        wfn[i] = *(const short8*)(s + pBg[i]);
        xfn[i] = *(const short8*)((c < 8) ? (fp[i] + c * 32) : (qp[i] + (c - 8) * 32));
      }
    }
#pragma unroll
    for (int ni = 0; ni < 4; ++ni)
#pragma unroll
      for (int mi = 0; mi < 4; ++mi)
        acc[ni][mi] = mfma16(wfc[ni], xfc[mi], acc[ni][mi]);
    if (ks < 15) {
#pragma unroll
      for (int i = 0; i < 4; ++i) { wfc[i] = wfn[i]; xfc[i] = xfn[i]; }
    }
  }
#pragma unroll
  for (int ni = 0; ni < 4; ++ni) {
    const int nbase = nb + ni * 16 + lq * 4;
    float4 bb = *(const float4*)(ab1 + nbase);
#pragma unroll
    for (int mi = 0; mi < 4; ++mi) {
      const int m = mi * 16 + l15;
      short4v hv;
      hv[0] = (short)f2bu(fmaxf(acc[ni][mi][0] + bb.x, 0.f));
      hv[1] = (short)f2bu(fmaxf(acc[ni][mi][1] + bb.y, 0.f));
      hv[2] = (short)f2bu(fmaxf(acc[ni][mi][2] + bb.z, 0.f));
      hv[3] = (short)f2bu(fmaxf(acc[ni][mi][3] + bb.w, 0.f));
      *(short4v*)(sH + m * 264 + nbase) = hv;
    }
  }
  __syncthreads();
  f32x4 a2 = fz;
#pragma unroll
  for (int ks = 0; ks < 8; ++ks) {
    short8 af = *(short8*)(sH + (wave * 16 + l15) * 264 + ks * 32 + hOff);
    short8 bv = *(const short8*)(aw2t + l15 * 256 + ks * 32 + hOff);
    a2 = mfma16(af, bv, a2);
  }
  const float bias = ab2[l15];
#pragma unroll
  for (int j = 0; j < 4; ++j)
    out[(size_t)(m0 + wave * 16 + lq * 4 + j) * 16 + l15] = (short)f2bu(a2[j] + bias);
}

// ---------------- single-layer GEMM (merged A/B sets) ---------------------
__global__ __launch_bounds__(256, 3) void k_gemm1(
    int nbA,
    const short* __restrict__ Aa, short* __restrict__ outA,
    const short* __restrict__ Ab, short* __restrict__ outB,
    const short* __restrict__ wt, const float* __restrict__ bias)
{
  int bid = blockIdx.x;
  const short* Abf; short* out;
  if (bid < nbA) { Abf = Aa; out = outA; }
  else { bid -= nbA; Abf = Ab; out = outB; }

  const int tid  = threadIdx.x;
  const int lane = tid & 63;
  const int wave = tid >> 6;
  const int m0   = bid << 6;
  const int l15  = lane & 15;
  const int lq   = lane >> 4;
  const int rq   = lq << 2;
  const int nb   = wave << 6;
  const int hOff = lq * 8;

  const f32x4 fz = {0.f, 0.f, 0.f, 0.f};
  f32x4 acc[4][4];
#pragma unroll
  for (int mi = 0; mi < 4; ++mi)
#pragma unroll
    for (int ni = 0; ni < 4; ++ni) acc[mi][ni] = fz;

  for (int ks = 0; ks < 8; ++ks) {
    short8 af[4], bv[4];
#pragma unroll
    for (int i = 0; i < 4; ++i) {
      af[i] = *(const short8*)(Abf + (size_t)(m0 + i * 16 + l15) * 256 + ks * 32 + hOff);
      bv[i] = *(const short8*)(wt + (size_t)(nb + i * 16 + l15) * 256 + ks * 32 + hOff);
    }
#pragma unroll
    for (int mi = 0; mi < 4; ++mi)
#pragma unroll
      for (int ni = 0; ni < 4; ++ni)
        acc[mi][ni] = mfma16(af[mi], bv[ni], acc[mi][ni]);
  }

#pragma unroll
  for (int ni = 0; ni < 4; ++ni) {
    const int col = nb + ni * 16 + l15;
    const float b = bias[col];
#pragma unroll
    for (int mi = 0; mi < 4; ++mi)
#pragma unroll
      for (int j = 0; j < 4; ++j) {
        const int row = mi * 16 + rq + j;
        out[(size_t)(m0 + row) * 256 + col] = (short)f2bu(fmaxf(acc[mi][ni][j] + b, 0.f));
      }
  }
}

// ---------------- fused 3-layer comb MLP --------------------------------
__global__ __launch_bounds__(256, 2) void k_comb(
    const short* __restrict__ hju, const short* __restrict__ hjv,
    const short* __restrict__ w1t, const float* __restrict__ b1,
    const short* __restrict__ w2t, const float* __restrict__ b2,
    const short* __restrict__ w3t, const float* __restrict__ b3,
    float* __restrict__ out)
{
  __shared__ __align__(16) short smem[29696];
  short (*A)[40]   = (short(*)[40])smem;
  short (*Bt)[40]  = (short(*)[40])(smem + 2560);
  short (*Hh)[264] = (short(*)[264])(smem + 12800);

  const int tid  = threadIdx.x;
  const int lane = tid & 63;
  const int wave = tid >> 6;
  const int m0   = blockIdx.x << 6;
  const int arow = tid >> 2;
  const int acol8 = (tid & 3) << 3;
  const int lrow = lane & 15;
  const int lk8  = (lane >> 4) << 3;
  const int rq   = (lane >> 4) << 2;
  const int nb   = wave << 6;
  const int r = m0 + arow;

  const f32x4 fz = {0.f, 0.f, 0.f, 0.f};
  f32x4 acc[4][4];
#pragma unroll
  for (int mi = 0; mi < 4; ++mi)
#pragma unroll
    for (int ni = 0; ni < 4; ++ni) acc[mi][ni] = fz;

  for (int ks = 0; ks < 16; ++ks) {
    const int kg = (ks << 5) + acol8;
    short8 av = (kg < 256) ? *(const short8*)(hju + (size_t)r * 256 + kg)
                           : *(const short8*)(hjv + (size_t)r * 256 + (kg - 256));
    *(short8*)&A[arow][acol8] = av;
    const short* wsrc = w1t + tid * 512 + (ks << 5);
    *(short8*)&Bt[tid][0]  = *(const short8*)(wsrc);
    *(short8*)&Bt[tid][8]  = *(const short8*)(wsrc + 8);
    *(short8*)&Bt[tid][16] = *(const short8*)(wsrc + 16);
    *(short8*)&Bt[tid][24] = *(const short8*)(wsrc + 24);
    __syncthreads();
    short8 af[4], bv[4];
#pragma unroll
    for (int mi = 0; mi < 4; ++mi) af[mi] = *(short8*)&A[mi * 16 + lrow][lk8];
#pragma unroll
    for (int ni = 0; ni < 4; ++ni) bv[ni] = *(short8*)&Bt[nb + ni * 16 + lrow][lk8];
#pragma unroll
    for (int mi = 0; mi < 4; ++mi)
#pragma unroll
      for (int ni = 0; ni < 4; ++ni)
        acc[mi][ni] = mfma16(af[mi], bv[ni], acc[mi][ni]);
    __syncthreads();
  }
#pragma unroll
  for (int ni = 0; ni < 4; ++ni) {
    const int col = nb + ni * 16 + lrow;
    const float bias = b1[col];
#pragma unroll
    for (int mi = 0; mi < 4; ++mi)
#pragma unroll
      for (int j = 0; j < 4; ++j)
        Hh[mi * 16 + rq + j][col] = (short)f2bu(fmaxf(acc[mi][ni][j] + bias, 0.f));
  }

#pragma unroll
  for (int mi = 0; mi < 4; ++mi)
#pragma unroll
    for (int ni = 0; ni < 4; ++ni) acc[mi][ni] = fz;
  for (int ks = 0; ks < 8; ++ks) {
    const short* wsrc = w2t + tid * 256 + (ks << 5);
    *(short8*)&Bt[tid][0]  = *(const short8*)(wsrc);
    *(short8*)&Bt[tid][8]  = *(const short8*)(wsrc + 8);
    *(short8*)&Bt[tid][16] = *(const short8*)(wsrc + 16);
    *(short8*)&Bt[tid][24] = *(const short8*)(wsrc + 24);
    __syncthreads();
    short8 af[4], bv[4];
#pragma unroll
    for (int mi = 0; mi < 4; ++mi) af[mi] = *(short8*)&Hh[mi * 16 + lrow][(ks << 5) + lk8];
#pragma unroll
    for (int ni = 0; ni < 4; ++ni) bv[ni] = *(short8*)&Bt[nb + ni * 16 + lrow][lk8];
#pragma unroll
    for (int mi = 0; mi < 4; ++mi)
#pragma unroll
      for (int ni = 0; ni < 4; ++ni)
        acc[mi][ni] = mfma16(af[mi], bv[ni], acc[mi][ni]);
    __syncthreads();
  }
#pragma unroll
  for (int ni = 0; ni < 4; ++ni) {
    const int col = nb + ni * 16 + lrow;
    const float bias = b2[col];
#pragma unroll
    for (int mi = 0; mi < 4; ++mi)
#pragma unroll
      for (int j = 0; j < 4; ++j)
        Hh[mi * 16 + rq + j][col] = (short)f2bu(fmaxf(acc[mi][ni][j] + bias, 0.f));
  }
  __syncthreads();

#pragma unroll
  for (int mi = 0; mi < 4; ++mi)
#pragma unroll
    for (int ni = 0; ni < 4; ++ni) acc[mi][ni] = fz;
  for (int ks = 0; ks < 8; ++ks) {
    const short* wsrc = w3t + tid * 256 + (ks << 5);
    *(short8*)&Bt[tid][0]  = *(const short8*)(wsrc);
    *(short8*)&Bt[tid][8]  = *(const short8*)(wsrc + 8);
    *(short8*)&Bt[tid][16] = *(const short8*)(wsrc + 16);
    *(short8*)&Bt[tid][24] = *(const short8*)(wsrc + 24);
    __syncthreads();
    short8 af[4], bv[4];
#pragma unroll
    for (int mi = 0; mi < 4; ++mi) af[mi] = *(short8*)&Hh[mi * 16 + lrow][(ks << 5) + lk8];
#pragma unroll
    for (int ni = 0; ni < 4; ++ni) bv[ni] = *(short8*)&Bt[nb + ni * 16 + lrow][lk8];
#pragma unroll
    for (int mi = 0; mi < 4; ++mi)
#pragma unroll
      for (int ni = 0; ni < 4; ++ni)
        acc[mi][ni] = mfma16(af[mi], bv[ni], acc[mi][ni]);
    __syncthreads();
  }
#pragma unroll
  for (int ni = 0; ni < 4; ++ni) {
    const int col = nb + ni * 16 + lrow;
    const float bias = b3[col];
#pragma unroll
    for (int mi = 0; mi < 4; ++mi)
#pragma unroll
      for (int j = 0; j < 4; ++j) {
        const int row = mi * 16 + rq + j;
        out[(size_t)(m0 + row) * 256 + col] = fmaxf(acc[mi][ni][j] + bias, 0.f);
      }
  }
}

// ---------------- head MLP1 (merged A/B sets) -----------------------------
__global__ __launch_bounds__(256, 4) void k_h1(
    int nbA,
    const short* __restrict__ Aa, short* __restrict__ h1a,
    const short* __restrict__ Ab, short* __restrict__ h1b,
    const short* __restrict__ w1t, const float* __restrict__ b1)
{
  int bid = blockIdx.x;
  const short* A; short* h1;
  if (bid < nbA) { A = Aa; h1 = h1a; }
  else { bid -= nbA; A = Ab; h1 = h1b; }

  const int tid = threadIdx.x;
  const int lane = tid & 63;
  const int wave = tid >> 6;
  const int m0 = bid << 6;
  const int l15 = lane & 15;
  const int lq = lane >> 4;
  const int ntc = (wave < 2) ? 2 : 1;
  const int nta = wave;
  const int ntb = wave + 4;

  const f32x4 fz = {0.f, 0.f, 0.f, 0.f};
  f32x4 acc[4][2];
#pragma unroll
  for (int i = 0; i < 4; ++i) { acc[i][0] = fz; acc[i][1] = fz; }

  for (int ks = 0; ks < 6; ++ks) {
    short8 af[4], bv[2];
#pragma unroll
    for (int i = 0; i < 4; ++i)
      af[i] = *(const short8*)(A + (size_t)(m0 + i * 16 + l15) * 192 + ks * 32 + lq * 8);
    bv[0] = *(const short8*)(w1t + (nta * 16 + l15) * 192 + ks * 32 + lq * 8);
    if (ntc == 2)
      bv[1] = *(const short8*)(w1t + (ntb * 16 + l15) * 192 + ks * 32 + lq * 8);
#pragma unroll
    for (int j = 0; j < 2; ++j)
      if (j < ntc)
#pragma unroll
        for (int i = 0; i < 4; ++i)
          acc[i][j] = mfma16(bv[j], af[i], acc[i][j]);
  }
#pragma unroll
  for (int j = 0; j < 2; ++j) {
    if (j >= ntc) continue;
    const int nbase = (j == 0 ? nta : ntb) * 16 + lq * 4;
    float4 bb = *(const float4*)(b1 + nbase);
#pragma unroll
    for (int i = 0; i < 4; ++i) {
      const int row = m0 + i * 16 + l15;
      short4v hv;
      hv[0] = (short)f2bu(fmaxf(acc[i][j][0] + bb.x, 0.f));
      hv[1] = (short)f2bu(fmaxf(acc[i][j][1] + bb.y, 0.f));
      hv[2] = (short)f2bu(fmaxf(acc[i][j][2] + bb.z, 0.f));
      hv[3] = (short)f2bu(fmaxf(acc[i][j][3] + bb.w, 0.f));
      *(short4v*)(h1 + (size_t)row * 96 + nbase) = hv;
    }
  }
}

// ---------------- head MLP2 + softmax (merged A/B sets) -------------------
__global__ __launch_bounds__(256) void k_h2(
    int nbA,
    const short* __restrict__ h1a, const int* __restrict__ maskA, int strideA,
    float* __restrict__ Wa,
    const short* __restrict__ h1b, const int* __restrict__ maskB, int strideB,
    float* __restrict__ Wb,
    const short* __restrict__ w2t, const float* __restrict__ b2)
{
  __shared__ float wgt[16][12];
  int bid = blockIdx.x;
  const short* h1; const int* mask_src; int mstride; float* W;
  if (bid < nbA) { h1 = h1a; mask_src = maskA; mstride = strideA; W = Wa; }
  else { bid -= nbA; h1 = h1b; mask_src = maskB; mstride = strideB; W = Wb; }

  const int tid = threadIdx.x;
  const int gg = tid >> 4, sl = tid & 15;
  const int g = bid * 16 + gg;
  if (sl < 12) {
    float s = b2[sl];
    const short* hr = h1 + (size_t)g * 96;
    const short* wr = w2t + sl * 96;
#pragma unroll
    for (int kk = 0; kk < 12; ++kk) {
      short8 hv = *(const short8*)(hr + kk * 8);
      short8 wv = *(const short8*)(wr + kk * 8);
#pragma unroll
      for (int j = 0; j < 8; ++j)
        s += b2f((unsigned short)hv[j]) * b2f((unsigned short)wv[j]);
    }
    const int mi = mask_src[(g * 12 + sl) * mstride];
    wgt[gg][sl] = (mi > 0) ? expf(s) : 0.f;
  }
  __syncthreads();
  if (sl < 12) {
    float tot = 1e-10f;
#pragma unroll
    for (int m = 0; m < 12; ++m) tot += wgt[gg][m];
    W[(size_t)g * 12 + sl] = wgt[gg][sl] / tot;
  }
}

// ---------------- weighted sum (merged A/B sets) --------------------------
__global__ __launch_bounds__(256) void k_wsum(
    int nbA,
    const float* __restrict__ Wa, const short* __restrict__ Xa, short* __restrict__ outA,
    const float* __restrict__ Wb, const short* __restrict__ Xb, short* __restrict__ outB)
{
  int bid = blockIdx.x;
  const float* W; const short* X; short* out;
  if (bid < nbA) { W = Wa; X = Xa; out = outA; }
  else { bid -= nbA; W = Wb; X = Xb; out = outB; }

  const int tid = threadIdx.x;
  const int g = bid * 8 + (tid >> 5);
  const int d0 = (tid & 31) * 8;
  const float* wg = W + (size_t)g * 12;
  float w[12];
#pragma unroll
  for (int m = 0; m < 12; ++m) w[m] = wg[m];
  const short* xp = X + (size_t)g * 12 * 256 + d0;
  float o[8];
#pragma unroll
  for (int j = 0; j < 8; ++j) o[j] = 0.f;
#pragma unroll
  for (int m = 0; m < 12; ++m) {
    short8 x = *(const short8*)(xp + m * 256);
#pragma unroll
    for (int j = 0; j < 8; ++j) o[j] += w[m] * b2f((unsigned short)x[j]);
  }
  short8 v;
#pragma unroll
  for (int j = 0; j < 8; ++j) v[j] = (short)f2bu(o[j]);
  *(short8*)(out + (size_t)g * 256 + d0) = v;
}

// =====================================================================
extern "C" void kernel_launch(void* const* d_in, const int* in_sizes, int n_in,
                              void* d_out, int out_size, void* d_ws, size_t ws_size,
                              hipStream_t stream)
{
  (void)in_sizes; (void)n_in; (void)out_size; (void)ws_size;

  const int*   iids = (const int*)d_in[0];
  const int*   iup  = (const int*)d_in[1];
  const int*   iip  = (const int*)d_in[2];
  const int*   iiup = (const int*)d_in[3];
  const float* user_table = (const float*)d_in[4];
  const float* item_table = (const float*)d_in[5];
  const float* rate_table = (const float*)d_in[6];
  const float* g_u_w1 = (const float*)d_in[7];   const float* g_u_b1 = (const float*)d_in[8];
  const float* g_u_w2 = (const float*)d_in[9];   const float* g_u_b2 = (const float*)d_in[10];
  const float* attu_w1 = (const float*)d_in[11]; const float* attu_b1 = (const float*)d_in[12];
  const float* attu_w2 = (const float*)d_in[13]; const float* attu_b2 = (const float*)d_in[14];
  const float* headu_w1 = (const float*)d_in[15]; const float* headu_b1 = (const float*)d_in[16];
  const float* headu_w2 = (const float*)d_in[17]; const float* headu_b2 = (const float*)d_in[18];
  const float* aggi_w = (const float*)d_in[19];  const float* aggi_b = (const float*)d_in[20];
  const float* attii_w1 = (const float*)d_in[21]; const float* attii_b1 = (const float*)d_in[22];
  const float* attii_w2 = (const float*)d_in[23]; const float* attii_b2 = (const float*)d_in[24];
  const float* headii_w1 = (const float*)d_in[25]; const float* headii_b1 = (const float*)d_in[26];
  const float* headii_w2 = (const float*)d_in[27]; const float* headii_b2 = (const float*)d_in[28];
  const float* aggii_w = (const float*)d_in[29]; const float* aggii_b = (const float*)d_in[30];
  const float* comb_w1 = (const float*)d_in[31]; const float* comb_b1 = (const float*)d_in[32];
  const float* comb_w2 = (const float*)d_in[33]; const float* comb_b2 = (const float*)d_in[34];
  const float* comb_w3 = (const float*)d_in[35]; const float* comb_b3 = (const float*)d_in[36];

  const int NIe = 100000 * 256;
  const int M2 = 2048 * 12 * 12;
  const int M1 = 2048 * 12;
  const int G2 = M1;
  const int G1 = 2048;

  char* wsp = (char*)d_ws;
  size_t off = 0;
  auto alloc = [&](size_t bytes) -> void* {
    void* p = wsp + off;
    off += (bytes + 255) & ~(size_t)255;
    return p;
  };
  short* item_bf = (short*)alloc((size_t)NIe * 2);
  short* urows   = (short*)alloc((size_t)M1 * 256 * 2);
  short* sl_gu1   = (short*)alloc((size_t)512 * 256 * 2);
  short* sl_gu2   = (short*)alloc((size_t)256 * 256 * 2);
  short* sl_attu1 = (short*)alloc((size_t)512 * 256 * 2);
  short* sl_attii1= (short*)alloc((size_t)512 * 256 * 2);
  short* wt_attu2 = (short*)alloc((size_t)256 * 16 * 2);
  short* wt_attii2= (short*)alloc((size_t)256 * 16 * 2);
  short* wt_aggi   = (short*)alloc((size_t)256 * 256 * 2);
  short* wt_aggii  = (short*)alloc((size_t)256 * 256 * 2);
  short* wt_comb1  = (short*)alloc((size_t)512 * 256 * 2);
  short* wt_comb2  = (short*)alloc((size_t)256 * 256 * 2);
  short* wt_comb3  = (short*)alloc((size_t)256 * 256 * 2);
  short* hu1t  = (short*)alloc((size_t)96 * 192 * 2);
  short* hu2t  = (short*)alloc((size_t)12 * 96 * 2);
  short* hii1t = (short*)alloc((size_t)96 * 192 * 2);
  short* hii2t = (short*)alloc((size_t)12 * 96 * 2);
  float* RC    = (float*)alloc((size_t)6 * 256 * 4);
  float* QC2   = (float*)alloc((size_t)G2 * 256 * 4);
  float* QC1   = (float*)alloc((size_t)G1 * 256 * 4);

  short* X      = (short*)alloc((size_t)M2 * 256 * 2);
  short* FJT    = (short*)alloc((size_t)M1 * 256 * 2);
  short* MIU2   = (short*)alloc((size_t)M2 * 16 * 2);
  short* MIU1   = (short*)alloc((size_t)M1 * 16 * 2);
  short* KAP    = (short*)alloc((size_t)M1 * 16 * 2);
  short* H1A    = (short*)alloc((size_t)G2 * 96 * 2);
  short* H1K    = (short*)alloc((size_t)G1 * 96 * 2);
  short* H1M    = (short*)alloc((size_t)G1 * 96 * 2);
  float* WA     = (float*)alloc((size_t)G2 * 12 * 4);
  float* WK     = (float*)alloc((size_t)G1 * 12 * 4);
  float* WM     = (float*)alloc((size_t)G1 * 12 * 4);
  short* HPRE2  = (short*)alloc((size_t)M1 * 256 * 2);
  short* HOU    = (short*)alloc((size_t)M1 * 256 * 2);
  short* HPREJV = (short*)alloc((size_t)2048 * 256 * 2);
  short* HPRE1  = (short*)alloc((size_t)2048 * 256 * 2);
  short* HJU    = (short*)alloc((size_t)2048 * 256 * 2);
  short* HJV    = (short*)alloc((size_t)2048 * 256 * 2);

  k_cvt<<<NIe / 8 / 256, 256, 0, stream>>>(item_table, item_bf, NIe);
  k_cvt_rows<<<(M1 * 32) / 256, 256, 0, stream>>>(user_table, iup, urows, M1);
  k_rc<<<6, 256, 0, stream>>>(rate_table, g_u_w1, RC);

  Prep pp;
  int nbk = 0, ei = 0;
  auto addw = [&](const float* s, short* d, int K, int N, int mode) {
    pp.src[ei] = s; pp.dst[ei] = d; pp.K[ei] = K; pp.N[ei] = N; pp.mode[ei] = mode;
    pp.boff[ei] = nbk; nbk += (K * N + 255) / 256; ++ei;
  };
  addw(g_u_w1,   sl_gu1,    512, 256, 0);
  addw(g_u_w2,   sl_gu2,    256, 256, 0);
  addw(attu_w1,  sl_attu1,  512, 256, 0);
  addw(attii_w1, sl_attii1, 512, 256, 0);
  addw(attu_w2,  wt_attu2,  256, 16, 1);
  addw(attii_w2, wt_attii2, 256, 16, 1);
  addw(aggi_w,   wt_aggi,   256, 256, 1);
  addw(aggii_w,  wt_aggii,  256, 256, 1);
  addw(comb_w1,  wt_comb1,  512, 256, 1);
  addw(comb_w2,  wt_comb2,  256, 256, 1);
  addw(comb_w3,  wt_comb3,  256, 256, 1);
  addw(headu_w1,  hu1t,  192, 96, 1);
  addw(headu_w2,  hu2t,  96, 12, 1);
  addw(headii_w1, hii1t, 192, 96, 1);
  addw(headii_w2, hii2t, 96, 12, 1);
  pp.boff[15] = nbk;
  pp.boff[16] = nbk;
  k_prep<<<nbk, 256, 0, stream>>>(pp);

  // QC merged (part-2 + part-1)
  k_qc<<<G2 / 64 + G1 / 64, 256, 0, stream>>>(G2 / 64, iip, QC2, iids, QC1,
                                              item_bf, sl_attu1);

  // fused g_u + attu merged (M2 + M1)
  k_fused<<<M2 / 64 + M1 / 64, 256, 0, stream>>>(
      M2 / 64,
      iiup, item_bf, QC2, X, MIU2,
      iup, urows, QC1, FJT, MIU1,
      RC, sl_gu1, g_u_b1, sl_gu2, g_u_b2,
      sl_attu1, attu_b1, wt_attu2, attu_b2);

  // head chain merged (part-2 + part-1)
  k_h1<<<G2 / 64 + G1 / 64, 256, 0, stream>>>(G2 / 64, MIU2, H1A, MIU1, H1M,
                                              hu1t, headu_b1);
  k_h2<<<G2 / 16 + G1 / 16, 256, 0, stream>>>(G2 / 16, H1A, iiup, 2, WA,
                                              H1M, iup, 2, WM, hu2t, headu_b2);
  k_wsum<<<G2 / 8 + G1 / 8, 256, 0, stream>>>(G2 / 8, WA, X, HPRE2,
                                              WM, FJT, HPRE1);

  // agg GEMMs merged (HOU + HJU, same weight)
  k_gemm1<<<M1 / 64 + G1 / 64, 256, 0, stream>>>(M1 / 64, HPRE2, HOU,
                                                 HPRE1, HJU, wt_aggi, aggi_b);

  // kappa chain
  k_attonly<<<M1 / 64, 256, 0, stream>>>(HOU, item_bf, iip,
                                         sl_attii1, attii_b1, wt_attii2, attii_b2, KAP);
  k_h1<<<G1 / 64, 256, 0, stream>>>(G1 / 64, KAP, H1K, KAP, H1K, hii1t, headii_b1);
  k_h2<<<G1 / 16, 256, 0, stream>>>(G1 / 16, H1K, iip, 1, WK,
                                    H1K, iip, 1, WK, hii2t, headii_b2);
  k_wsum<<<G1 / 8, 256, 0, stream>>>(G1 / 8, WK, HOU, HPREJV, WK, HOU, HPREJV);
  k_gemm1<<<G1 / 64, 256, 0, stream>>>(G1 / 64, HPREJV, HJV, HPREJV, HJV,
                                       wt_aggii, aggii_b);

  k_comb<<<2048 / 64, 256, 0, stream>>>(HJU, HJV, wt_comb1, comb_b1,
                                        wt_comb2, comb_b2, wt_comb3, comb_b3,
                                        (float*)d_out);
}

// Round 17
// 407.477 us; speedup vs baseline: 1.2888x; 1.0441x over previous
//
#include <hip/hip_runtime.h>
#include <cstdint>
#include <cstddef>

typedef short short8 __attribute__((ext_vector_type(8)));
typedef short short4v __attribute__((ext_vector_type(4)));
typedef float f32x4 __attribute__((ext_vector_type(4)));
typedef __bf16 bf16x8 __attribute__((ext_vector_type(8)));

__device__ __forceinline__ unsigned short f2bu(float f) {
  return __builtin_bit_cast(unsigned short, (__bf16)f);
}
__device__ __forceinline__ float b2f(unsigned short h) {
  union { unsigned u; float f; } v; v.u = ((unsigned)h) << 16;
  return v.f;
}

__device__ __forceinline__ f32x4 mfma16(short8 a, short8 b, f32x4 c) {
  return __builtin_amdgcn_mfma_f32_16x16x32_bf16(
      __builtin_bit_cast(bf16x8, a), __builtin_bit_cast(bf16x8, b), c, 0, 0, 0);
}

// ---------------- weight prep descriptor ---------------------------------
struct Prep {
  const float* src[16];
  short* dst[16];
  int K[16], N[16], mode[16];
  int boff[17];
};

// ---------------- merged pre-pass: cvt + cvt_rows + rc + prep -------------
__global__ void k_pre(
    const float* __restrict__ item_table, short* __restrict__ item_bf, int nCvtBlk,
    const float* __restrict__ user_table, const int* __restrict__ iup,
    short* __restrict__ urows, int nRowsBlk,
    const float* __restrict__ rate, const float* __restrict__ guw1,
    float* __restrict__ RC,
    Prep p)
{
  int b = blockIdx.x;
  const int tid = threadIdx.x;

  if (b < nCvtBlk) {                       // item table f32 -> bf16
    int i = (b * 256 + tid) * 8;
    float4 a = *(const float4*)(item_table + i);
    float4 c = *(const float4*)(item_table + i + 4);
    short8 v;
    v[0] = (short)f2bu(a.x); v[1] = (short)f2bu(a.y);
    v[2] = (short)f2bu(a.z); v[3] = (short)f2bu(a.w);
    v[4] = (short)f2bu(c.x); v[5] = (short)f2bu(c.y);
    v[6] = (short)f2bu(c.z); v[7] = (short)f2bu(c.w);
    *(short8*)(item_bf + i) = v;
    return;
  }
  b -= nCvtBlk;
  if (b < nRowsBlk) {                      // gather user rows -> bf16
    int t = b * 256 + tid;
    int row = t >> 5;
    int c8 = (t & 31) << 3;
    int id = iup[2 * row];
    const float* s = user_table + (size_t)id * 256 + c8;
    float4 a = *(const float4*)(s);
    float4 c = *(const float4*)(s + 4);
    short8 v;
    v[0] = (short)f2bu(a.x); v[1] = (short)f2bu(a.y);
    v[2] = (short)f2bu(a.z); v[3] = (short)f2bu(a.w);
    v[4] = (short)f2bu(c.x); v[5] = (short)f2bu(c.y);
    v[6] = (short)f2bu(c.z); v[7] = (short)f2bu(c.w);
    *(short8*)(urows + (size_t)row * 256 + c8) = v;
    return;
  }
  b -= nRowsBlk;
  if (b < 6) {                             // RC[6][256]
    float s = 0.f;
    const float* rr = rate + b * 256;
    for (int k = 0; k < 256; ++k)
      s += rr[k] * guw1[(size_t)(256 + k) * 256 + tid];
    RC[b * 256 + tid] = s;
    return;
  }
  b -= 6;
  // weight prep
  int e = 0;
#pragma unroll
  for (int i = 1; i < 16; ++i) if (b >= p.boff[i]) e = i;
  int t = (b - p.boff[e]) * 256 + tid;
  const int K = p.K[e], N = p.N[e];
  if (t >= K * N) return;
  const float* w = p.src[e];
  const int m = p.mode[e];
  if (m == 2) { p.dst[e][t] = (short)f2bu(w[t]); return; }
  if (m == 0) {
    int ks = t >> 13, rem = t & 8191;
    int P = rem >> 3, j = rem & 7;
    int n = P >> 2;
    int kq = ((P & 3) - (n >> 1)) & 3;
    int k = (ks << 5) + (kq << 3) + j;
    p.dst[e][t] = (short)f2bu(w[(size_t)k * 256 + n]);
    return;
  }
  int n = t / K, k = t - n * K;
  p.dst[e][t] = (short)f2bu(w[(size_t)k * N + n]);
}

// ---------------- QC (merged A/B sets) ------------------------------------
__global__ __launch_bounds__(256, 4) void k_qc(
    int nbA,
    const int* __restrict__ qidA, float* __restrict__ QCA,
    const int* __restrict__ qidB, float* __restrict__ QCB,
    const short* __restrict__ itembf, const short* __restrict__ aw1)
{
  int bid = blockIdx.x;
  const int* qid; float* QC;
  if (bid < nbA) { qid = qidA; QC = QCA; }
  else { bid -= nbA; qid = qidB; QC = QCB; }

  const int tid = threadIdx.x;
  const int lane = tid & 63;
  const int wave = tid >> 6;
  const int m0 = bid << 6;
  const int l15 = lane & 15;
  const int lq = lane >> 4;
  const int nb = wave << 6;

  int pBg[4];
  const short* qp[4];
#pragma unroll
  for (int i = 0; i < 4; ++i) {
    int n = nb + i * 16 + l15;
    pBg[i] = (n * 4 + ((lq + (n >> 1)) & 3)) * 8;
    qp[i] = itembf + (size_t)qid[m0 + i * 16 + l15] * 256 + lq * 8;
  }

  const f32x4 fz = {0.f, 0.f, 0.f, 0.f};
  f32x4 acc[4][4];
#pragma unroll
  for (int ni = 0; ni < 4; ++ni)
#pragma unroll
    for (int mi = 0; mi < 4; ++mi) acc[ni][mi] = fz;

  for (int ks = 0; ks < 8; ++ks) {
    short8 wf[4], qf[4];
#pragma unroll
    for (int i = 0; i < 4; ++i) {
      wf[i] = *(const short8*)(aw1 + (8 + ks) * 8192 + pBg[i]);
      qf[i] = *(const short8*)(qp[i] + ks * 32);
    }
#pragma unroll
    for (int ni = 0; ni < 4; ++ni)
#pragma unroll
      for (int mi = 0; mi < 4; ++mi)
        acc[ni][mi] = mfma16(wf[ni], qf[mi], acc[ni][mi]);
  }
#pragma unroll
  for (int ni = 0; ni < 4; ++ni) {
    const int nbase = nb + ni * 16 + lq * 4;
#pragma unroll
    for (int mi = 0; mi < 4; ++mi) {
      const int m = mi * 16 + l15;
      *(f32x4*)(QC + (size_t)(m0 + m) * 256 + nbase) = acc[ni][mi];
    }
  }
}

// ---------------- fused g_u + attu (merged M2/M1 sets) --------------------
__global__ __launch_bounds__(256, 3) void k_fused(
    int nbA,
    const int* __restrict__ idxA, const short* __restrict__ tabA,
    const float* __restrict__ QCa, short* __restrict__ Xa, short* __restrict__ miuA,
    const int* __restrict__ idxB, const short* __restrict__ tabB,
    const float* __restrict__ QCb, short* __restrict__ Xb, short* __restrict__ miuB,
    const float* __restrict__ RC,
    const short* __restrict__ ws1, const float* __restrict__ b1,
    const short* __restrict__ ws2, const float* __restrict__ b2,
    const short* __restrict__ aw1, const float* __restrict__ ab1,
    const short* __restrict__ aw2t, const float* __restrict__ ab2)
{
  __shared__ __align__(16) short smem[20480];
  short* sA0 = smem;
  short* sA1 = smem + 2048;
  short* sH  = smem + 4096;

  int bid = blockIdx.x;
  const int* idx_pairs; const short* tab0; const float* QC;
  short* Xout; short* miu_out; bool ident;
  if (bid < nbA) {
    idx_pairs = idxA; tab0 = tabA; QC = QCa; Xout = Xa; miu_out = miuA; ident = false;
  } else {
    bid -= nbA;
    idx_pairs = idxB; tab0 = tabB; QC = QCb; Xout = Xb; miu_out = miuB; ident = true;
  }

  const int tid = threadIdx.x;
  const int lane = tid & 63;
  const int wave = tid >> 6;
  const int m0 = bid << 6;
  const int l15 = lane & 15;
  const int lq = lane >> 4;
  const int nb = wave << 6;
  const int swz = (l15 & 7) << 3;

  const int an = tid >> 2;
  const int kqA = ((tid & 3) - (an >> 1)) & 3;
  const int r = m0 + an;
  const int i0 = idx_pairs[2 * r];
  const short* a0 = (ident ? (tab0 + (size_t)r * 256) : (tab0 + (size_t)i0 * 256)) + kqA * 8;

  int pBg[4], pA[4];
#pragma unroll
  for (int i = 0; i < 4; ++i) {
    int n = nb + i * 16 + l15;
    pBg[i] = (n * 4 + ((lq + (n >> 1)) & 3)) * 8;
    int m = i * 16 + l15;
    pA[i] = (m * 4 + ((lq + (m >> 1)) & 3)) * 8;
  }
  const int hOff = lq * 8;

  const f32x4 fz = {0.f, 0.f, 0.f, 0.f};
  f32x4 acc[4][4];
#pragma unroll
  for (int ni = 0; ni < 4; ++ni)
#pragma unroll
    for (int mi = 0; mi < 4; ++mi) acc[ni][mi] = fz;

  short8 wfb[3][4];
  short8 ar0, ar1;

  int i1v[4], mskv[4], grpv[4];
#pragma unroll
  for (int mi = 0; mi < 4; ++mi) {
    const int row = m0 + mi * 16 + l15;
    i1v[mi]  = idx_pairs[2 * row + 1];
    mskv[mi] = idx_pairs[2 * row];
    grpv[mi] = row / 12;
  }

  // ================= g_u layer 1 =================
  {
    short8 t = *(const short8*)a0;
    *(short8*)(sA0 + tid * 8) = t;
  }
  ar1 = *(const short8*)(a0 + 32);
#pragma unroll
  for (int i = 0; i < 4; ++i) wfb[0][i] = *(const short8*)(ws1 + pBg[i]);
#pragma unroll
  for (int i = 0; i < 4; ++i) wfb[1][i] = *(const short8*)(ws1 + 8192 + pBg[i]);
  __syncthreads();
#pragma unroll
  for (int ks = 0; ks < 8; ++ks) {
    short* sAc = (ks & 1) ? sA1 : sA0;
    short* sAn = (ks & 1) ? sA0 : sA1;
    if (ks < 6) {
      const int c = ks + 2;
      short8 t = *(const short8*)(a0 + c * 32);
      if ((ks & 1) == 0) ar0 = t; else ar1 = t;
      const short* s = ws1 + c * 8192;
#pragma unroll
      for (int i = 0; i < 4; ++i) wfb[c % 3][i] = *(const short8*)(s + pBg[i]);
    }
    short8 xf[4];
#pragma unroll
    for (int i = 0; i < 4; ++i) xf[i] = *(short8*)(sAc + pA[i]);
#pragma unroll
    for (int ni = 0; ni < 4; ++ni)
#pragma unroll
      for (int mi = 0; mi < 4; ++mi)
        acc[ni][mi] = mfma16(wfb[ks % 3][ni], xf[mi], acc[ni][mi]);
    if (ks < 7) {
      short8 w = (((ks + 1) & 1) == 0) ? ar0 : ar1;
      *(short8*)(sAn + tid * 8) = w;
      __syncthreads();
    }
  }
#pragma unroll
  for (int ni = 0; ni < 4; ++ni) {
    const int nbase = nb + ni * 16 + lq * 4;
    float4 bb = *(const float4*)(b1 + nbase);
#pragma unroll
    for (int mi = 0; mi < 4; ++mi) {
      const int m = mi * 16 + l15;
      float4 rc = *(const float4*)(RC + i1v[mi] * 256 + nbase);
      short4v hv;
      hv[0] = (short)f2bu(fmaxf(acc[ni][mi][0] + rc.x + bb.x, 0.f));
      hv[1] = (short)f2bu(fmaxf(acc[ni][mi][1] + rc.y + bb.y, 0.f));
      hv[2] = (short)f2bu(fmaxf(acc[ni][mi][2] + rc.z + bb.z, 0.f));
      hv[3] = (short)f2bu(fmaxf(acc[ni][mi][3] + rc.w + bb.w, 0.f));
      *(short4v*)(sH + m * 256 + (nbase ^ swz)) = hv;
    }
  }
  __syncthreads();

  // ================= g_u layer 2 =================
#pragma unroll
  for (int ni = 0; ni < 4; ++ni)
#pragma unroll
    for (int mi = 0; mi < 4; ++mi) acc[ni][mi] = fz;
#pragma unroll
  for (int i = 0; i < 4; ++i) wfb[0][i] = *(const short8*)(ws2 + pBg[i]);
#pragma unroll
  for (int i = 0; i < 4; ++i) wfb[1][i] = *(const short8*)(ws2 + 8192 + pBg[i]);
#pragma unroll
  for (int ks = 0; ks < 8; ++ks) {
    if (ks < 6) {
      const short* s = ws2 + (ks + 2) * 8192;
#pragma unroll
      for (int i = 0; i < 4; ++i) wfb[(ks + 2) % 3][i] = *(const short8*)(s + pBg[i]);
    }
    short8 hf[4];
#pragma unroll
    for (int i = 0; i < 4; ++i)
      hf[i] = *(short8*)(sH + (i * 16 + l15) * 256 + ((ks * 32 + hOff) ^ swz));
#pragma unroll
    for (int ni = 0; ni < 4; ++ni)
#pragma unroll
      for (int mi = 0; mi < 4; ++mi)
        acc[ni][mi] = mfma16(wfb[ks % 3][ni], hf[mi], acc[ni][mi]);
  }
  __syncthreads();

  // f_jt -> sH
#pragma unroll
  for (int ni = 0; ni < 4; ++ni) {
    const int nbase = nb + ni * 16 + lq * 4;
    float4 bb = *(const float4*)(b2 + nbase);
#pragma unroll
    for (int mi = 0; mi < 4; ++mi) {
      const int m = mi * 16 + l15;
      short4v hv;
      hv[0] = (short)f2bu(acc[ni][mi][0] + bb.x);
      hv[1] = (short)f2bu(acc[ni][mi][1] + bb.y);
      hv[2] = (short)f2bu(acc[ni][mi][2] + bb.z);
      hv[3] = (short)f2bu(acc[ni][mi][3] + bb.w);
      *(short4v*)(sH + m * 256 + (nbase ^ swz)) = hv;
    }
  }
  __syncthreads();

  // coalesced X write
#pragma unroll
  for (int p = 0; p < 8; ++p) {
    const int rr = (tid >> 5) + p * 8;
    const int c8 = (tid & 31) * 8;
    short8 v = *(short8*)(sH + rr * 256 + (c8 ^ ((rr & 7) << 3)));
    *(short8*)(Xout + (size_t)(m0 + rr) * 256 + c8) = v;
  }

  // ================= attn layer 1 =================
#pragma unroll
  for (int ni = 0; ni < 4; ++ni)
#pragma unroll
    for (int mi = 0; mi < 4; ++mi) acc[ni][mi] = fz;
#pragma unroll
  for (int i = 0; i < 4; ++i) wfb[0][i] = *(const short8*)(aw1 + pBg[i]);
#pragma unroll
  for (int i = 0; i < 4; ++i) wfb[1][i] = *(const short8*)(aw1 + 8192 + pBg[i]);
#pragma unroll
  for (int ks = 0; ks < 8; ++ks) {
    if (ks < 6) {
      const short* s = aw1 + (ks + 2) * 8192;
#pragma unroll
      for (int i = 0; i < 4; ++i) wfb[(ks + 2) % 3][i] = *(const short8*)(s + pBg[i]);
    }
    short8 xf[4];
#pragma unroll
    for (int i = 0; i < 4; ++i)
      xf[i] = *(short8*)(sH + (i * 16 + l15) * 256 + ((ks * 32 + hOff) ^ swz));
#pragma unroll
    for (int ni = 0; ni < 4; ++ni)
#pragma unroll
      for (int mi = 0; mi < 4; ++mi)
        acc[ni][mi] = mfma16(wfb[ks % 3][ni], xf[mi], acc[ni][mi]);
  }
  __syncthreads();

  // attn hidden -> sH
#pragma unroll
  for (int ni = 0; ni < 4; ++ni) {
    const int nbase = nb + ni * 16 + lq * 4;
    float4 bb = *(const float4*)(ab1 + nbase);
#pragma unroll
    for (int mi = 0; mi < 4; ++mi) {
      const int m = mi * 16 + l15;
      float4 qv;
      if (mskv[mi] > 0) qv = *(const float4*)(QC + (size_t)grpv[mi] * 256 + nbase);
      else { qv.x = 0.f; qv.y = 0.f; qv.z = 0.f; qv.w = 0.f; }
      short4v hv;
      hv[0] = (short)f2bu(fmaxf(acc[ni][mi][0] + qv.x + bb.x, 0.f));
      hv[1] = (short)f2bu(fmaxf(acc[ni][mi][1] + qv.y + bb.y, 0.f));
      hv[2] = (short)f2bu(fmaxf(acc[ni][mi][2] + qv.z + bb.z, 0.f));
      hv[3] = (short)f2bu(fmaxf(acc[ni][mi][3] + qv.w + bb.w, 0.f));
      *(short4v*)(sH + m * 256 + (nbase ^ swz)) = hv;
    }
  }
  __syncthreads();

  // ================= attn layer 2 =================
  f32x4 a2 = fz;
#pragma unroll
  for (int ks = 0; ks < 8; ++ks) {
    short8 af = *(short8*)(sH + (wave * 16 + l15) * 256 + ((ks * 32 + hOff) ^ swz));
    short8 bv = *(const short8*)(aw2t + l15 * 256 + ks * 32 + hOff);
    a2 = mfma16(af, bv, a2);
  }
  const float bias = ab2[l15];
#pragma unroll
  for (int j = 0; j < 4; ++j)
    miu_out[(size_t)(m0 + wave * 16 + lq * 4 + j) * 16 + l15] = (short)f2bu(a2[j] + bias);
}

// ---------------- kappa scores (bf16 out) ---------------------------------
__global__ __launch_bounds__(256, 3) void k_attonly(
    const short* __restrict__ first,
    const short* __restrict__ itembf,
    const int* __restrict__ iidx,
    const short* __restrict__ aw1, const float* __restrict__ ab1,
    const short* __restrict__ aw2t, const float* __restrict__ ab2,
    short* __restrict__ out)
{
  __shared__ __align__(16) short sH[16896];

  const int tid = threadIdx.x;
  const int lane = tid & 63;
  const int wave = tid >> 6;
  const int m0 = (int)blockIdx.x << 6;
  const int l15 = lane & 15;
  const int lq = lane >> 4;
  const int nb = wave << 6;
  const int hOff = lq * 8;

  const short* fp[4];
  const short* qp[4];
  int pBg[4];
#pragma unroll
  for (int i = 0; i < 4; ++i) {
    int mrow = m0 + i * 16 + l15;
    fp[i] = first + (size_t)mrow * 256 + hOff;
    qp[i] = itembf + (size_t)iidx[mrow] * 256 + hOff;
    int n = nb + i * 16 + l15;
    pBg[i] = (n * 4 + ((lq + (n >> 1)) & 3)) * 8;
  }

  const f32x4 fz = {0.f, 0.f, 0.f, 0.f};
  f32x4 acc[4][4];
#pragma unroll
  for (int ni = 0; ni < 4; ++ni)
#pragma unroll
    for (int mi = 0; mi < 4; ++mi) acc[ni][mi] = fz;

  short8 wfc[4], wfn[4], xfc[4], xfn[4];
#pragma unroll
  for (int i = 0; i < 4; ++i) {
    wfc[i] = *(const short8*)(aw1 + pBg[i]);
    xfc[i] = *(const short8*)(fp[i]);
  }
  for (int ks = 0; ks < 16; ++ks) {
    if (ks < 15) {
      const int c = ks + 1;
      const short* s = aw1 + c * 8192;
#pragma unroll
      for (int i = 0; i < 4; ++i) {
        wfn[i] = *(const short8*)(s + pBg[i]);
        xfn[i] = *(const short8*)((c < 8) ? (fp[i] + c * 32) : (qp[i] + (c - 8) * 32));
      }
    }
#pragma unroll
    for (int ni = 0; ni < 4; ++ni)
#pragma unroll
      for (int mi = 0; mi < 4; ++mi)
        acc[ni][mi] = mfma16(wfc[ni], xfc[mi], acc[ni][mi]);
    if (ks < 15) {
#pragma unroll
      for (int i = 0; i < 4; ++i) { wfc[i] = wfn[i]; xfc[i] = xfn[i]; }
    }
  }
#pragma unroll
  for (int ni = 0; ni < 4; ++ni) {
    const int nbase = nb + ni * 16 + lq * 4;
    float4 bb = *(const float4*)(ab1 + nbase);
#pragma unroll
    for (int mi = 0; mi < 4; ++mi) {
      const int m = mi * 16 + l15;
      short4v hv;
      hv[0] = (short)f2bu(fmaxf(acc[ni][mi][0] + bb.x, 0.f));
      hv[1] = (short)f2bu(fmaxf(acc[ni][mi][1] + bb.y, 0.f));
      hv[2] = (short)f2bu(fmaxf(acc[ni][mi][2] + bb.z, 0.f));
      hv[3] = (short)f2bu(fmaxf(acc[ni][mi][3] + bb.w, 0.f));
      *(short4v*)(sH + m * 264 + nbase) = hv;
    }
  }
  __syncthreads();
  f32x4 a2 = fz;
#pragma unroll
  for (int ks = 0; ks < 8; ++ks) {
    short8 af = *(short8*)(sH + (wave * 16 + l15) * 264 + ks * 32 + hOff);
    short8 bv = *(const short8*)(aw2t + l15 * 256 + ks * 32 + hOff);
    a2 = mfma16(af, bv, a2);
  }
  const float bias = ab2[l15];
#pragma unroll
  for (int j = 0; j < 4; ++j)
    out[(size_t)(m0 + wave * 16 + lq * 4 + j) * 16 + l15] = (short)f2bu(a2[j] + bias);
}

// ---------------- single-layer GEMM (merged A/B sets) ---------------------
__global__ __launch_bounds__(256, 3) void k_gemm1(
    int nbA,
    const short* __restrict__ Aa, short* __restrict__ outA,
    const short* __restrict__ Ab, short* __restrict__ outB,
    const short* __restrict__ wt, const float* __restrict__ bias)
{
  int bid = blockIdx.x;
  const short* Abf; short* out;
  if (bid < nbA) { Abf = Aa; out = outA; }
  else { bid -= nbA; Abf = Ab; out = outB; }

  const int tid  = threadIdx.x;
  const int lane = tid & 63;
  const int wave = tid >> 6;
  const int m0   = bid << 6;
  const int l15  = lane & 15;
  const int lq   = lane >> 4;
  const int rq   = lq << 2;
  const int nb   = wave << 6;
  const int hOff = lq * 8;

  const f32x4 fz = {0.f, 0.f, 0.f, 0.f};
  f32x4 acc[4][4];
#pragma unroll
  for (int mi = 0; mi < 4; ++mi)
#pragma unroll
    for (int ni = 0; ni < 4; ++ni) acc[mi][ni] = fz;

  for (int ks = 0; ks < 8; ++ks) {
    short8 af[4], bv[4];
#pragma unroll
    for (int i = 0; i < 4; ++i) {
      af[i] = *(const short8*)(Abf + (size_t)(m0 + i * 16 + l15) * 256 + ks * 32 + hOff);
      bv[i] = *(const short8*)(wt + (size_t)(nb + i * 16 + l15) * 256 + ks * 32 + hOff);
    }
#pragma unroll
    for (int mi = 0; mi < 4; ++mi)
#pragma unroll
      for (int ni = 0; ni < 4; ++ni)
        acc[mi][ni] = mfma16(af[mi], bv[ni], acc[mi][ni]);
  }

#pragma unroll
  for (int ni = 0; ni < 4; ++ni) {
    const int col = nb + ni * 16 + l15;
    const float b = bias[col];
#pragma unroll
    for (int mi = 0; mi < 4; ++mi)
#pragma unroll
      for (int j = 0; j < 4; ++j) {
        const int row = mi * 16 + rq + j;
        out[(size_t)(m0 + row) * 256 + col] = (short)f2bu(fmaxf(acc[mi][ni][j] + b, 0.f));
      }
  }
}

// ---------------- fused 3-layer comb MLP --------------------------------
__global__ __launch_bounds__(256, 2) void k_comb(
    const short* __restrict__ hju, const short* __restrict__ hjv,
    const short* __restrict__ w1t, const float* __restrict__ b1,
    const short* __restrict__ w2t, const float* __restrict__ b2,
    const short* __restrict__ w3t, const float* __restrict__ b3,
    float* __restrict__ out)
{
  __shared__ __align__(16) short smem[29696];
  short (*A)[40]   = (short(*)[40])smem;
  short (*Bt)[40]  = (short(*)[40])(smem + 2560);
  short (*Hh)[264] = (short(*)[264])(smem + 12800);

  const int tid  = threadIdx.x;
  const int lane = tid & 63;
  const int wave = tid >> 6;
  const int m0   = blockIdx.x << 6;
  const int arow = tid >> 2;
  const int acol8 = (tid & 3) << 3;
  const int lrow = lane & 15;
  const int lk8  = (lane >> 4) << 3;
  const int rq   = (lane >> 4) << 2;
  const int nb   = wave << 6;
  const int r = m0 + arow;

  const f32x4 fz = {0.f, 0.f, 0.f, 0.f};
  f32x4 acc[4][4];
#pragma unroll
  for (int mi = 0; mi < 4; ++mi)
#pragma unroll
    for (int ni = 0; ni < 4; ++ni) acc[mi][ni] = fz;

  for (int ks = 0; ks < 16; ++ks) {
    const int kg = (ks << 5) + acol8;
    short8 av = (kg < 256) ? *(const short8*)(hju + (size_t)r * 256 + kg)
                           : *(const short8*)(hjv + (size_t)r * 256 + (kg - 256));
    *(short8*)&A[arow][acol8] = av;
    const short* wsrc = w1t + tid * 512 + (ks << 5);
    *(short8*)&Bt[tid][0]  = *(const short8*)(wsrc);
    *(short8*)&Bt[tid][8]  = *(const short8*)(wsrc + 8);
    *(short8*)&Bt[tid][16] = *(const short8*)(wsrc + 16);
    *(short8*)&Bt[tid][24] = *(const short8*)(wsrc + 24);
    __syncthreads();
    short8 af[4], bv[4];
#pragma unroll
    for (int mi = 0; mi < 4; ++mi) af[mi] = *(short8*)&A[mi * 16 + lrow][lk8];
#pragma unroll
    for (int ni = 0; ni < 4; ++ni) bv[ni] = *(short8*)&Bt[nb + ni * 16 + lrow][lk8];
#pragma unroll
    for (int mi = 0; mi < 4; ++mi)
#pragma unroll
      for (int ni = 0; ni < 4; ++ni)
        acc[mi][ni] = mfma16(af[mi], bv[ni], acc[mi][ni]);
    __syncthreads();
  }
#pragma unroll
  for (int ni = 0; ni < 4; ++ni) {
    const int col = nb + ni * 16 + lrow;
    const float bias = b1[col];
#pragma unroll
    for (int mi = 0; mi < 4; ++mi)
#pragma unroll
      for (int j = 0; j < 4; ++j)
        Hh[mi * 16 + rq + j][col] = (short)f2bu(fmaxf(acc[mi][ni][j] + bias, 0.f));
  }

#pragma unroll
  for (int mi = 0; mi < 4; ++mi)
#pragma unroll
    for (int ni = 0; ni < 4; ++ni) acc[mi][ni] = fz;
  for (int ks = 0; ks < 8; ++ks) {
    const short* wsrc = w2t + tid * 256 + (ks << 5);
    *(short8*)&Bt[tid][0]  = *(const short8*)(wsrc);
    *(short8*)&Bt[tid][8]  = *(const short8*)(wsrc + 8);
    *(short8*)&Bt[tid][16] = *(const short8*)(wsrc + 16);
    *(short8*)&Bt[tid][24] = *(const short8*)(wsrc + 24);
    __syncthreads();
    short8 af[4], bv[4];
#pragma unroll
    for (int mi = 0; mi < 4; ++mi) af[mi] = *(short8*)&Hh[mi * 16 + lrow][(ks << 5) + lk8];
#pragma unroll
    for (int ni = 0; ni < 4; ++ni) bv[ni] = *(short8*)&Bt[nb + ni * 16 + lrow][lk8];
#pragma unroll
    for (int mi = 0; mi < 4; ++mi)
#pragma unroll
      for (int ni = 0; ni < 4; ++ni)
        acc[mi][ni] = mfma16(af[mi], bv[ni], acc[mi][ni]);
    __syncthreads();
  }
#pragma unroll
  for (int ni = 0; ni < 4; ++ni) {
    const int col = nb + ni * 16 + lrow;
    const float bias = b2[col];
#pragma unroll
    for (int mi = 0; mi < 4; ++mi)
#pragma unroll
      for (int j = 0; j < 4; ++j)
        Hh[mi * 16 + rq + j][col] = (short)f2bu(fmaxf(acc[mi][ni][j] + bias, 0.f));
  }
  __syncthreads();

#pragma unroll
  for (int mi = 0; mi < 4; ++mi)
#pragma unroll
    for (int ni = 0; ni < 4; ++ni) acc[mi][ni] = fz;
  for (int ks = 0; ks < 8; ++ks) {
    const short* wsrc = w3t + tid * 256 + (ks << 5);
    *(short8*)&Bt[tid][0]  = *(const short8*)(wsrc);
    *(short8*)&Bt[tid][8]  = *(const short8*)(wsrc + 8);
    *(short8*)&Bt[tid][16] = *(const short8*)(wsrc + 16);
    *(short8*)&Bt[tid][24] = *(const short8*)(wsrc + 24);
    __syncthreads();
    short8 af[4], bv[4];
#pragma unroll
    for (int mi = 0; mi < 4; ++mi) af[mi] = *(short8*)&Hh[mi * 16 + lrow][(ks << 5) + lk8];
#pragma unroll
    for (int ni = 0; ni < 4; ++ni) bv[ni] = *(short8*)&Bt[nb + ni * 16 + lrow][lk8];
#pragma unroll
    for (int mi = 0; mi < 4; ++mi)
#pragma unroll
      for (int ni = 0; ni < 4; ++ni)
        acc[mi][ni] = mfma16(af[mi], bv[ni], acc[mi][ni]);
    __syncthreads();
  }
#pragma unroll
  for (int ni = 0; ni < 4; ++ni) {
    const int col = nb + ni * 16 + lrow;
    const float bias = b3[col];
#pragma unroll
    for (int mi = 0; mi < 4; ++mi)
#pragma unroll
      for (int j = 0; j < 4; ++j) {
        const int row = mi * 16 + rq + j;
        out[(size_t)(m0 + row) * 256 + col] = fmaxf(acc[mi][ni][j] + bias, 0.f);
      }
  }
}

// ---------------- head MLP1 (merged A/B sets) -----------------------------
__global__ __launch_bounds__(256, 4) void k_h1(
    int nbA,
    const short* __restrict__ Aa, short* __restrict__ h1a,
    const short* __restrict__ Ab, short* __restrict__ h1b,
    const short* __restrict__ w1t, const float* __restrict__ b1)
{
  int bid = blockIdx.x;
  const short* A; short* h1;
  if (bid < nbA) { A = Aa; h1 = h1a; }
  else { bid -= nbA; A = Ab; h1 = h1b; }

  const int tid = threadIdx.x;
  const int lane = tid & 63;
  const int wave = tid >> 6;
  const int m0 = bid << 6;
  const int l15 = lane & 15;
  const int lq = lane >> 4;
  const int ntc = (wave < 2) ? 2 : 1;
  const int nta = wave;
  const int ntb = wave + 4;

  const f32x4 fz = {0.f, 0.f, 0.f, 0.f};
  f32x4 acc[4][2];
#pragma unroll
  for (int i = 0; i < 4; ++i) { acc[i][0] = fz; acc[i][1] = fz; }

  for (int ks = 0; ks < 6; ++ks) {
    short8 af[4], bv[2];
#pragma unroll
    for (int i = 0; i < 4; ++i)
      af[i] = *(const short8*)(A + (size_t)(m0 + i * 16 + l15) * 192 + ks * 32 + lq * 8);
    bv[0] = *(const short8*)(w1t + (nta * 16 + l15) * 192 + ks * 32 + lq * 8);
    if (ntc == 2)
      bv[1] = *(const short8*)(w1t + (ntb * 16 + l15) * 192 + ks * 32 + lq * 8);
#pragma unroll
    for (int j = 0; j < 2; ++j)
      if (j < ntc)
#pragma unroll
        for (int i = 0; i < 4; ++i)
          acc[i][j] = mfma16(bv[j], af[i], acc[i][j]);
  }
#pragma unroll
  for (int j = 0; j < 2; ++j) {
    if (j >= ntc) continue;
    const int nbase = (j == 0 ? nta : ntb) * 16 + lq * 4;
    float4 bb = *(const float4*)(b1 + nbase);
#pragma unroll
    for (int i = 0; i < 4; ++i) {
      const int row = m0 + i * 16 + l15;
      short4v hv;
      hv[0] = (short)f2bu(fmaxf(acc[i][j][0] + bb.x, 0.f));
      hv[1] = (short)f2bu(fmaxf(acc[i][j][1] + bb.y, 0.f));
      hv[2] = (short)f2bu(fmaxf(acc[i][j][2] + bb.z, 0.f));
      hv[3] = (short)f2bu(fmaxf(acc[i][j][3] + bb.w, 0.f));
      *(short4v*)(h1 + (size_t)row * 96 + nbase) = hv;
    }
  }
}

// ---------------- head MLP2 + softmax + weighted sum (merged A/B sets) ----
// block = 8 groups; phase A: 96 threads compute the 8x12 masked scores;
// phase B: weighted sum over the group's 12 source rows.
__global__ __launch_bounds__(256) void k_h2w(
    int nbA,
    const short* __restrict__ h1a, const int* __restrict__ maskA, int strideA,
    const short* __restrict__ Xa, short* __restrict__ outA,
    const short* __restrict__ h1b, const int* __restrict__ maskB, int strideB,
    const short* __restrict__ Xb, short* __restrict__ outB,
    const short* __restrict__ w2t, const float* __restrict__ b2)
{
  __shared__ float wgt[8][12];
  int bid = blockIdx.x;
  const short* h1; const int* mask_src; int mstride;
  const short* X; short* out;
  if (bid < nbA) { h1 = h1a; mask_src = maskA; mstride = strideA; X = Xa; out = outA; }
  else { bid -= nbA; h1 = h1b; mask_src = maskB; mstride = strideB; X = Xb; out = outB; }

  const int tid = threadIdx.x;
  if (tid < 96) {
    const int gg = tid / 12, sl = tid - gg * 12;
    const int g = bid * 8 + gg;
    float s = b2[sl];
    const short* hr = h1 + (size_t)g * 96;
    const short* wr = w2t + sl * 96;
#pragma unroll
    for (int kk = 0; kk < 12; ++kk) {
      short8 hv = *(const short8*)(hr + kk * 8);
      short8 wv = *(const short8*)(wr + kk * 8);
#pragma unroll
      for (int j = 0; j < 8; ++j)
        s += b2f((unsigned short)hv[j]) * b2f((unsigned short)wv[j]);
    }
    const int mi = mask_src[(g * 12 + sl) * mstride];
    wgt[gg][sl] = (mi > 0) ? expf(s) : 0.f;
  }
  __syncthreads();

  const int gg = tid >> 5;
  const int g = bid * 8 + gg;
  const int d0 = (tid & 31) * 8;
  float tot = 1e-10f;
#pragma unroll
  for (int m = 0; m < 12; ++m) tot += wgt[gg][m];
  float w[12];
#pragma unroll
  for (int m = 0; m < 12; ++m) w[m] = wgt[gg][m] / tot;

  const short* xp = X + (size_t)g * 12 * 256 + d0;
  float o[8];
#pragma unroll
  for (int j = 0; j < 8; ++j) o[j] = 0.f;
#pragma unroll
  for (int m = 0; m < 12; ++m) {
    short8 x = *(const short8*)(xp + m * 256);
#pragma unroll
    for (int j = 0; j < 8; ++j) o[j] += w[m] * b2f((unsigned short)x[j]);
  }
  short8 v;
#pragma unroll
  for (int j = 0; j < 8; ++j) v[j] = (short)f2bu(o[j]);
  *(short8*)(out + (size_t)g * 256 + d0) = v;
}

// =====================================================================
extern "C" void kernel_launch(void* const* d_in, const int* in_sizes, int n_in,
                              void* d_out, int out_size, void* d_ws, size_t ws_size,
                              hipStream_t stream)
{
  (void)in_sizes; (void)n_in; (void)out_size; (void)ws_size;

  const int*   iids = (const int*)d_in[0];
  const int*   iup  = (const int*)d_in[1];
  const int*   iip  = (const int*)d_in[2];
  const int*   iiup = (const int*)d_in[3];
  const float* user_table = (const float*)d_in[4];
  const float* item_table = (const float*)d_in[5];
  const float* rate_table = (const float*)d_in[6];
  const float* g_u_w1 = (const float*)d_in[7];   const float* g_u_b1 = (const float*)d_in[8];
  const float* g_u_w2 = (const float*)d_in[9];   const float* g_u_b2 = (const float*)d_in[10];
  const float* attu_w1 = (const float*)d_in[11]; const float* attu_b1 = (const float*)d_in[12];
  const float* attu_w2 = (const float*)d_in[13]; const float* attu_b2 = (const float*)d_in[14];
  const float* headu_w1 = (const float*)d_in[15]; const float* headu_b1 = (const float*)d_in[16];
  const float* headu_w2 = (const float*)d_in[17]; const float* headu_b2 = (const float*)d_in[18];
  const float* aggi_w = (const float*)d_in[19];  const float* aggi_b = (const float*)d_in[20];
  const float* attii_w1 = (const float*)d_in[21]; const float* attii_b1 = (const float*)d_in[22];
  const float* attii_w2 = (const float*)d_in[23]; const float* attii_b2 = (const float*)d_in[24];
  const float* headii_w1 = (const float*)d_in[25]; const float* headii_b1 = (const float*)d_in[26];
  const float* headii_w2 = (const float*)d_in[27]; const float* headii_b2 = (const float*)d_in[28];
  const float* aggii_w = (const float*)d_in[29]; const float* aggii_b = (const float*)d_in[30];
  const float* comb_w1 = (const float*)d_in[31]; const float* comb_b1 = (const float*)d_in[32];
  const float* comb_w2 = (const float*)d_in[33]; const float* comb_b2 = (const float*)d_in[34];
  const float* comb_w3 = (const float*)d_in[35]; const float* comb_b3 = (const float*)d_in[36];

  const int NIe = 100000 * 256;
  const int M2 = 2048 * 12 * 12;
  const int M1 = 2048 * 12;
  const int G2 = M1;
  const int G1 = 2048;

  char* wsp = (char*)d_ws;
  size_t off = 0;
  auto alloc = [&](size_t bytes) -> void* {
    void* p = wsp + off;
    off += (bytes + 255) & ~(size_t)255;
    return p;
  };
  short* item_bf = (short*)alloc((size_t)NIe * 2);
  short* urows   = (short*)alloc((size_t)M1 * 256 * 2);
  short* sl_gu1   = (short*)alloc((size_t)512 * 256 * 2);
  short* sl_gu2   = (short*)alloc((size_t)256 * 256 * 2);
  short* sl_attu1 = (short*)alloc((size_t)512 * 256 * 2);
  short* sl_attii1= (short*)alloc((size_t)512 * 256 * 2);
  short* wt_attu2 = (short*)alloc((size_t)256 * 16 * 2);
  short* wt_attii2= (short*)alloc((size_t)256 * 16 * 2);
  short* wt_aggi   = (short*)alloc((size_t)256 * 256 * 2);
  short* wt_aggii  = (short*)alloc((size_t)256 * 256 * 2);
  short* wt_comb1  = (short*)alloc((size_t)512 * 256 * 2);
  short* wt_comb2  = (short*)alloc((size_t)256 * 256 * 2);
  short* wt_comb3  = (short*)alloc((size_t)256 * 256 * 2);
  short* hu1t  = (short*)alloc((size_t)96 * 192 * 2);
  short* hu2t  = (short*)alloc((size_t)12 * 96 * 2);
  short* hii1t = (short*)alloc((size_t)96 * 192 * 2);
  short* hii2t = (short*)alloc((size_t)12 * 96 * 2);
  float* RC    = (float*)alloc((size_t)6 * 256 * 4);
  float* QC2   = (float*)alloc((size_t)G2 * 256 * 4);
  float* QC1   = (float*)alloc((size_t)G1 * 256 * 4);

  short* X      = (short*)alloc((size_t)M2 * 256 * 2);
  short* FJT    = (short*)alloc((size_t)M1 * 256 * 2);
  short* MIU2   = (short*)alloc((size_t)M2 * 16 * 2);
  short* MIU1   = (short*)alloc((size_t)M1 * 16 * 2);
  short* KAP    = (short*)alloc((size_t)M1 * 16 * 2);
  short* H1A    = (short*)alloc((size_t)G2 * 96 * 2);
  short* H1K    = (short*)alloc((size_t)G1 * 96 * 2);
  short* H1M    = (short*)alloc((size_t)G1 * 96 * 2);
  short* HPRE2  = (short*)alloc((size_t)M1 * 256 * 2);
  short* HOU    = (short*)alloc((size_t)M1 * 256 * 2);
  short* HPREJV = (short*)alloc((size_t)2048 * 256 * 2);
  short* HPRE1  = (short*)alloc((size_t)2048 * 256 * 2);
  short* HJU    = (short*)alloc((size_t)2048 * 256 * 2);
  short* HJV    = (short*)alloc((size_t)2048 * 256 * 2);

  Prep pp;
  int nbk = 0, ei = 0;
  auto addw = [&](const float* s, short* d, int K, int N, int mode) {
    pp.src[ei] = s; pp.dst[ei] = d; pp.K[ei] = K; pp.N[ei] = N; pp.mode[ei] = mode;
    pp.boff[ei] = nbk; nbk += (K * N + 255) / 256; ++ei;
  };
  addw(g_u_w1,   sl_gu1,    512, 256, 0);
  addw(g_u_w2,   sl_gu2,    256, 256, 0);
  addw(attu_w1,  sl_attu1,  512, 256, 0);
  addw(attii_w1, sl_attii1, 512, 256, 0);
  addw(attu_w2,  wt_attu2,  256, 16, 1);
  addw(attii_w2, wt_attii2, 256, 16, 1);
  addw(aggi_w,   wt_aggi,   256, 256, 1);
  addw(aggii_w,  wt_aggii,  256, 256, 1);
  addw(comb_w1,  wt_comb1,  512, 256, 1);
  addw(comb_w2,  wt_comb2,  256, 256, 1);
  addw(comb_w3,  wt_comb3,  256, 256, 1);
  addw(headu_w1,  hu1t,  192, 96, 1);
  addw(headu_w2,  hu2t,  96, 12, 1);
  addw(headii_w1, hii1t, 192, 96, 1);
  addw(headii_w2, hii2t, 96, 12, 1);
  pp.boff[15] = nbk;
  pp.boff[16] = nbk;

  const int nCvtBlk = NIe / 8 / 256;       // 12500
  const int nRowsBlk = (M1 * 32) / 256;    // 3072
  k_pre<<<nCvtBlk + nRowsBlk + 6 + nbk, 256, 0, stream>>>(
      item_table, item_bf, nCvtBlk,
      user_table, iup, urows, nRowsBlk,
      rate_table, g_u_w1, RC, pp);

  // QC merged (part-2 + part-1)
  k_qc<<<G2 / 64 + G1 / 64, 256, 0, stream>>>(G2 / 64, iip, QC2, iids, QC1,
                                              item_bf, sl_attu1);

  // fused g_u + attu merged (M2 + M1)
  k_fused<<<M2 / 64 + M1 / 64, 256, 0, stream>>>(
      M2 / 64,
      iiup, item_bf, QC2, X, MIU2,
      iup, urows, QC1, FJT, MIU1,
      RC, sl_gu1, g_u_b1, sl_gu2, g_u_b2,
      sl_attu1, attu_b1, wt_attu2, attu_b2);

  // head chain merged (part-2 + part-1)
  k_h1<<<G2 / 64 + G1 / 64, 256, 0, stream>>>(G2 / 64, MIU2, H1A, MIU1, H1M,
                                              hu1t, headu_b1);
  k_h2w<<<G2 / 8 + G1 / 8, 256, 0, stream>>>(G2 / 8,
                                             H1A, iiup, 2, X, HPRE2,
                                             H1M, iup, 2, FJT, HPRE1,
                                             hu2t, headu_b2);

  // agg GEMMs merged (HOU + HJU, same weight)
  k_gemm1<<<M1 / 64 + G1 / 64, 256, 0, stream>>>(M1 / 64, HPRE2, HOU,
                                                 HPRE1, HJU, wt_aggi, aggi_b);

  // kappa chain
  k_attonly<<<M1 / 64, 256, 0, stream>>>(HOU, item_bf, iip,
                                         sl_attii1, attii_b1, wt_attii2, attii_b2, KAP);
  k_h1<<<G1 / 64, 256, 0, stream>>>(G1 / 64, KAP, H1K, KAP, H1K, hii1t, headii_b1);
  k_h2w<<<G1 / 8, 256, 0, stream>>>(G1 / 8,
                                    H1K, iip, 1, HOU, HPREJV,
                                    H1K, iip, 1, HOU, HPREJV,
                                    hii2t, headii_b2);
  k_gemm1<<<G1 / 64, 256, 0, stream>>>(G1 / 64, HPREJV, HJV, HPREJV, HJV,
                                       wt_aggii, aggii_b);

  k_comb<<<2048 / 64, 256, 0, stream>>>(HJU, HJV, wt_comb1, comb_b1,
                                        wt_comb2, comb_b2, wt_comb3, comb_b3,
                                        (float*)d_out);
}